// Round 1
// baseline (896.896 us; speedup 1.0000x reference)
//
#include <hip/hip_runtime.h>

// ---------------------------------------------------------------------------
// GraphSAGE 3-layer forward, fp32.
//   h = x[:,4:10]
//   per layer: mean_agg(h) @ Wl + bl + h @ Wr, relu
// Strategy:
//   - build reverse-CSR (edges grouped by dst) once per call (counting sort)
//   - aggregation = per-node wave sum over CSR edge list (sequential writes)
//   - layer 2: pre-multiply h1 @ Wl2 (128->64) BEFORE aggregating (halves
//     scatter traffic; 1/cnt scaling commutes with the matmul)
//   - dense layers: LDS-tiled fp32 GEMM, 64xN block tile, 8x{4,2} micro-tile
// ---------------------------------------------------------------------------

static __device__ __forceinline__ int imax(int a, int b) { return a > b ? a : b; }

// ---- graph build -----------------------------------------------------------

__global__ __launch_bounds__(256) void k_degree(const int* __restrict__ dst,
                                                int* __restrict__ cnt, int nE) {
    int i = blockIdx.x * blockDim.x + threadIdx.x;
    if (i < nE) atomicAdd(&cnt[dst[i]], 1);
}

// single-block exclusive scan over nN counts (nN = 100000, chunk ~98/thread)
__global__ __launch_bounds__(1024) void k_scan(const int* __restrict__ cnt,
                                               int* __restrict__ offs, int n) {
    __shared__ int sums[1024];
    int t = threadIdx.x;
    int chunk = (n + 1023) >> 10;
    int lo = min(t * chunk, n);
    int hi = min(t * chunk + chunk, n);
    int s = 0;
    for (int i = lo; i < hi; ++i) s += cnt[i];
    sums[t] = s;
    __syncthreads();
    for (int off = 1; off < 1024; off <<= 1) {
        int v = (t >= off) ? sums[t - off] : 0;
        __syncthreads();
        sums[t] += v;
        __syncthreads();
    }
    int run = (t == 0) ? 0 : sums[t - 1];
    for (int i = lo; i < hi; ++i) { offs[i] = run; run += cnt[i]; }
    if (hi == n) offs[n] = run;   // threads with empty tail chunks write same total
}

__global__ __launch_bounds__(256) void k_fill(const int* __restrict__ src,
                                              const int* __restrict__ dst,
                                              const int* __restrict__ offs,
                                              int* __restrict__ next,
                                              int* __restrict__ csr, int nE) {
    int i = blockIdx.x * blockDim.x + threadIdx.x;
    if (i >= nE) return;
    int d = dst[i];
    int p = offs[d] + atomicAdd(&next[d], 1);
    csr[p] = src[i];
}

// ---- aggregation -----------------------------------------------------------

// 6-dim mean of x[:,4:10] over incoming edges; one thread per node
__global__ __launch_bounds__(256) void k_agg0(const float* __restrict__ x,
                                              const int* __restrict__ offs,
                                              const int* __restrict__ csr,
                                              float* __restrict__ mean0, int nN) {
    int i = blockIdx.x * blockDim.x + threadIdx.x;
    if (i >= nN) return;
    int lo = offs[i], hi = offs[i + 1];
    float a0 = 0, a1 = 0, a2 = 0, a3 = 0, a4 = 0, a5 = 0;
    for (int e = lo; e < hi; ++e) {
        int s = csr[e];
        const float* r = x + (size_t)s * 10 + 4;
        float2 v0 = *(const float2*)(r);
        float2 v1 = *(const float2*)(r + 2);
        float2 v2 = *(const float2*)(r + 4);
        a0 += v0.x; a1 += v0.y; a2 += v1.x; a3 += v1.y; a4 += v2.x; a5 += v2.y;
    }
    float inv = 1.0f / (float)imax(hi - lo, 1);
    float* o = mean0 + (size_t)i * 6;
    o[0] = a0 * inv; o[1] = a1 * inv; o[2] = a2 * inv;
    o[3] = a3 * inv; o[4] = a4 * inv; o[5] = a5 * inv;
}

// 128-dim mean: one wave per node, lane holds float2
__global__ __launch_bounds__(256) void k_agg128(const float* __restrict__ X,
                                                const int* __restrict__ offs,
                                                const int* __restrict__ csr,
                                                float* __restrict__ M, int nN) {
    int w = (blockIdx.x * 256 + threadIdx.x) >> 6;
    int lane = threadIdx.x & 63;
    if (w >= nN) return;
    int lo = offs[w], hi = offs[w + 1];
    float2 acc = make_float2(0.f, 0.f);
    for (int e = lo; e < hi; ++e) {
        int s = csr[e];
        float2 v = *(const float2*)(X + (size_t)s * 128 + lane * 2);
        acc.x += v.x; acc.y += v.y;
    }
    float inv = 1.0f / (float)imax(hi - lo, 1);
    *(float2*)(M + (size_t)w * 128 + lane * 2) = make_float2(acc.x * inv, acc.y * inv);
}

// 64-dim mean: one wave per node, lane holds 1 float
__global__ __launch_bounds__(256) void k_agg64(const float* __restrict__ X,
                                               const int* __restrict__ offs,
                                               const int* __restrict__ csr,
                                               float* __restrict__ M, int nN) {
    int w = (blockIdx.x * 256 + threadIdx.x) >> 6;
    int lane = threadIdx.x & 63;
    if (w >= nN) return;
    int lo = offs[w], hi = offs[w + 1];
    float acc = 0.f;
    for (int e = lo; e < hi; ++e) {
        int s = csr[e];
        acc += X[(size_t)s * 64 + lane];
    }
    M[(size_t)w * 64 + lane] = acc / (float)imax(hi - lo, 1);
}

// ---- dense layers -----------------------------------------------------------

// layer 0: out[i][j] = relu(sum_k mean0[i][k]*Wl[k][j] + bl[j] + sum_k h[i][k]*Wr[k][j])
// K=6, so one thread per (node, out-feature); weights are L1-resident (6 KB)
__global__ __launch_bounds__(256) void k_l0(const float* __restrict__ x,
                                            const float* __restrict__ mean0,
                                            const float* __restrict__ Wl,
                                            const float* __restrict__ bl,
                                            const float* __restrict__ Wr,
                                            float* __restrict__ out, int nN) {
    int j = threadIdx.x & 127;
    int node = blockIdx.x * 2 + (threadIdx.x >> 7);
    if (node >= nN) return;
    const float* m = mean0 + (size_t)node * 6;
    const float* h = x + (size_t)node * 10 + 4;
    float v = bl[j];
#pragma unroll
    for (int k = 0; k < 6; ++k) v = fmaf(m[k], Wl[k * 128 + j], v);
#pragma unroll
    for (int k = 0; k < 6; ++k) v = fmaf(h[k], Wr[k * 128 + j], v);
    out[(size_t)node * 128 + j] = fmaxf(v, 0.f);
}

// generic tall-skinny GEMM: C[i][:] = act( A[i][:KA]@WA + B[i][:KB]@WB + bias + add[i][:] )
// block = 64 rows x N cols, 256 threads, 8x(N/32) micro-tile per thread
template <int KA, int KB, int N, bool RELU>
__global__ __launch_bounds__(256) void k_gemm(const float* __restrict__ A,
                                              const float* __restrict__ WA,
                                              const float* __restrict__ B,
                                              const float* __restrict__ WB,
                                              const float* __restrict__ bias,
                                              const float* __restrict__ add,
                                              float* __restrict__ C, int nN) {
    constexpr int BM = 64, BK = 32;
    constexpr int K = KA + KB;
    constexpr int NC = N / 32;
    __shared__ __align__(16) float As[BK][BM];
    __shared__ __align__(16) float Ws[BK][N];
    const int tid = threadIdx.x;
    const int m0 = blockIdx.x * BM;
    const int ty = tid >> 5;   // 0..7
    const int tx = tid & 31;   // 0..31

    float acc[8][NC];
#pragma unroll
    for (int r = 0; r < 8; ++r)
#pragma unroll
        for (int c = 0; c < NC; ++c) acc[r][c] = 0.f;

    for (int kk = 0; kk < K; kk += BK) {
        const float* Ap; const float* Wp; int krel, lda;
        if (kk < KA) { Ap = A; Wp = WA + (size_t)kk * N;        krel = kk;      lda = KA; }
        else         { Ap = B; Wp = WB + (size_t)(kk - KA) * N; krel = kk - KA; lda = KB; }
        // A tile: 64 rows x 32 cols
        {
            int r = tid >> 3;
            int c = (tid & 7) << 2;
#pragma unroll
            for (int h = 0; h < 2; ++h) {
                int row = r + 32 * h;
                int gm = m0 + row;
                float4 v = make_float4(0.f, 0.f, 0.f, 0.f);
                if (gm < nN) v = *(const float4*)(Ap + (size_t)gm * lda + krel + c);
                As[c + 0][row] = v.x; As[c + 1][row] = v.y;
                As[c + 2][row] = v.z; As[c + 3][row] = v.w;
            }
        }
        // W tile: 32 x N
        {
            constexpr int NV = N / 4;
#pragma unroll
            for (int q = 0; q < (BK * NV) / 256; ++q) {
                int idx = tid + q * 256;
                int r = idx / NV;
                int c = (idx % NV) << 2;
                *(float4*)&Ws[r][c] = *(const float4*)(Wp + r * N + c);
            }
        }
        __syncthreads();
#pragma unroll
        for (int k = 0; k < BK; ++k) {
            float4 a0 = *(const float4*)&As[k][ty << 3];
            float4 a1 = *(const float4*)&As[k][(ty << 3) + 4];
            float a[8] = {a0.x, a0.y, a0.z, a0.w, a1.x, a1.y, a1.z, a1.w};
            float b[NC];
#pragma unroll
            for (int c = 0; c < NC; ++c) b[c] = Ws[k][tx + 32 * c];
#pragma unroll
            for (int r = 0; r < 8; ++r)
#pragma unroll
                for (int c = 0; c < NC; ++c) acc[r][c] = fmaf(a[r], b[c], acc[r][c]);
        }
        __syncthreads();
    }
#pragma unroll
    for (int r = 0; r < 8; ++r) {
        int gm = m0 + (ty << 3) + r;
        if (gm >= nN) continue;
#pragma unroll
        for (int c = 0; c < NC; ++c) {
            int n = tx + 32 * c;
            float v = acc[r][c];
            if (bias) v += bias[n];
            if (add) v += add[(size_t)gm * N + n];
            if (RELU) v = fmaxf(v, 0.f);
            C[(size_t)gm * N + n] = v;
        }
    }
}

// ---------------------------------------------------------------------------

extern "C" void kernel_launch(void* const* d_in, const int* in_sizes, int n_in,
                              void* d_out, int out_size, void* d_ws, size_t ws_size,
                              hipStream_t stream) {
    const float* x   = (const float*)d_in[0];
    const int*   ei  = (const int*)d_in[1];
    const float* Wl0 = (const float*)d_in[2];
    const float* bl0 = (const float*)d_in[3];
    const float* Wr0 = (const float*)d_in[4];
    const float* Wl1 = (const float*)d_in[5];
    const float* bl1 = (const float*)d_in[6];
    const float* Wr1 = (const float*)d_in[7];
    const float* Wl2 = (const float*)d_in[8];
    const float* bl2 = (const float*)d_in[9];
    const float* Wr2 = (const float*)d_in[10];

    const int nN = in_sizes[0] / 10;
    const int nE = in_sizes[1] / 2;
    const int* src = ei;
    const int* dst = ei + nE;

    // workspace layout (big, 16B-aligned buffers first)
    char* ws = (char*)d_ws;
    size_t off = 0;
    auto alloc = [&](size_t bytes) -> char* {
        char* p = ws + off;
        off = (off + bytes + 255) & ~(size_t)255;
        return p;
    };
    float* bufA  = (float*)alloc((size_t)nN * 128 * 4);  // out0 / z2
    float* bufB  = (float*)alloc((size_t)nN * 128 * 4);  // mean1 / mean(z2)
    float* bufC  = (float*)alloc((size_t)nN * 128 * 4);  // out1
    float* mean0 = (float*)alloc((size_t)nN * 6 * 4);
    int* cnt  = (int*)alloc((size_t)nN * 4);
    int* next = (int*)alloc((size_t)nN * 4);
    int* offs = (int*)alloc(((size_t)nN + 1) * 4);
    int* csr  = (int*)alloc((size_t)nE * 4);

    hipMemsetAsync(cnt, 0, (size_t)nN * 4, stream);
    hipMemsetAsync(next, 0, (size_t)nN * 4, stream);

    // build reverse CSR
    k_degree<<<(nE + 255) / 256, 256, 0, stream>>>(dst, cnt, nE);
    k_scan<<<1, 1024, 0, stream>>>(cnt, offs, nN);
    k_fill<<<(nE + 255) / 256, 256, 0, stream>>>(src, dst, offs, next, csr, nE);

    // layer 0 (K=6)
    k_agg0<<<(nN + 255) / 256, 256, 0, stream>>>(x, offs, csr, mean0, nN);
    k_l0<<<(nN + 1) / 2, 256, 0, stream>>>(x, mean0, Wl0, bl0, Wr0, bufA, nN);

    // layer 1: mean1 = agg(out0); out1 = relu(mean1@Wl1 + bl1 + out0@Wr1)
    k_agg128<<<(nN + 3) / 4, 256, 0, stream>>>(bufA, offs, csr, bufB, nN);
    k_gemm<128, 128, 128, true><<<(nN + 63) / 64, 256, 0, stream>>>(
        bufB, Wl1, bufA, Wr1, bl1, nullptr, bufC, nN);

    // layer 2 (reordered): z2 = out1@Wl2; out = relu(agg(z2) + bl2 + out1@Wr2)
    k_gemm<128, 0, 64, false><<<(nN + 63) / 64, 256, 0, stream>>>(
        bufC, Wl2, nullptr, nullptr, nullptr, nullptr, bufA, nN);
    k_agg64<<<(nN + 3) / 4, 256, 0, stream>>>(bufA, offs, csr, bufB, nN);
    k_gemm<128, 0, 64, true><<<(nN + 63) / 64, 256, 0, stream>>>(
        bufC, Wr2, nullptr, nullptr, bl2, bufB, (float*)d_out, nN);
}

// Round 2
// 619.109 us; speedup vs baseline: 1.4487x; 1.4487x over previous
//
#include <hip/hip_runtime.h>

// ---------------------------------------------------------------------------
// GraphSAGE 3-layer forward.
//   h = x[:,4:10]; per layer: mean_agg(h) @ Wl + bl + h @ Wr, relu
// Round-2 changes:
//   - hierarchical 2-kernel scan (was: single-block, 162us @ 0.16% occupancy)
//   - out0 / z2 stored bf16 -> halves the random-gather bytes in agg kernels
//   - agg128: 2 edges/iter (half-wave per edge), agg64: 4 edges/iter
// ---------------------------------------------------------------------------

static __device__ __forceinline__ int imax(int a, int b) { return a > b ? a : b; }

static __device__ __forceinline__ float bfbits_lo(unsigned u) {
    union { unsigned i; float f; } v; v.i = u << 16; return v.f;
}
static __device__ __forceinline__ float bfbits_hi(unsigned u) {
    union { unsigned i; float f; } v; v.i = u & 0xffff0000u; return v.f;
}
static __device__ __forceinline__ unsigned short f2bf(float f) {
    unsigned u = __float_as_uint(f);
    u = (u + 0x7fffu + ((u >> 16) & 1u)) >> 16;
    return (unsigned short)u;
}

// load 4 contiguous elements as float4 (fp32 or bf16 source)
static __device__ __forceinline__ float4 ld4(const float* p) { return *(const float4*)p; }
static __device__ __forceinline__ float4 ld4(const unsigned short* p) {
    uint2 v = *(const uint2*)p;
    return make_float4(bfbits_lo(v.x), bfbits_hi(v.x), bfbits_lo(v.y), bfbits_hi(v.y));
}
static __device__ __forceinline__ void st1(float* p, float v) { *p = v; }
static __device__ __forceinline__ void st1(unsigned short* p, float v) { *p = f2bf(v); }

// ---- graph build -----------------------------------------------------------

__global__ __launch_bounds__(256) void k_degree(const int* __restrict__ dst,
                                                int* __restrict__ cnt, int nE) {
    int i = blockIdx.x * blockDim.x + threadIdx.x;
    if (i < nE) atomicAdd(&cnt[dst[i]], 1);
}

// hierarchical scan, pass A: per-block (1024 elems) exclusive scan + block sum
__global__ __launch_bounds__(256) void k_scan_a(const int* __restrict__ cnt,
                                                int* __restrict__ offs,
                                                int* __restrict__ bsum, int n) {
    __shared__ int sm[256];
    int t = threadIdx.x;
    int base = blockIdx.x * 1024 + t * 4;
    int v0 = 0, v1 = 0, v2 = 0, v3 = 0;
    if (base + 3 < n) {
        int4 q = *(const int4*)(cnt + base);
        v0 = q.x; v1 = q.y; v2 = q.z; v3 = q.w;
    } else {
        if (base < n)     v0 = cnt[base];
        if (base + 1 < n) v1 = cnt[base + 1];
        if (base + 2 < n) v2 = cnt[base + 2];
    }
    int s = v0 + v1 + v2 + v3;
    sm[t] = s;
    __syncthreads();
    for (int o = 1; o < 256; o <<= 1) {
        int u = (t >= o) ? sm[t - o] : 0;
        __syncthreads();
        sm[t] += u;
        __syncthreads();
    }
    int excl = sm[t] - s;
    if (base < n)     offs[base]     = excl;
    if (base + 1 < n) offs[base + 1] = excl + v0;
    if (base + 2 < n) offs[base + 2] = excl + v0 + v1;
    if (base + 3 < n) offs[base + 3] = excl + v0 + v1 + v2;
    if (t == 255) bsum[blockIdx.x] = sm[255];
}

// pass B: add block prefix; write grand total at offs[n]
__global__ __launch_bounds__(256) void k_scan_b(int* __restrict__ offs,
                                                const int* __restrict__ bsum,
                                                int n, int nb) {
    __shared__ int pfx;
    int t = threadIdx.x, b = blockIdx.x;
    if (t == 0) {
        int s = 0;
        for (int i = 0; i < b; ++i) s += bsum[i];
        pfx = s;
        if (b == nb - 1) offs[n] = s + bsum[b];
    }
    __syncthreads();
    if (b == 0) return;           // prefix 0, nothing to add
    int base = b * 1024 + t * 4;
    int p = pfx;
    if (base < n)     offs[base]     += p;
    if (base + 1 < n) offs[base + 1] += p;
    if (base + 2 < n) offs[base + 2] += p;
    if (base + 3 < n) offs[base + 3] += p;
}

__global__ __launch_bounds__(256) void k_fill(const int* __restrict__ src,
                                              const int* __restrict__ dst,
                                              const int* __restrict__ offs,
                                              int* __restrict__ next,
                                              int* __restrict__ csr, int nE) {
    int i = blockIdx.x * blockDim.x + threadIdx.x;
    if (i >= nE) return;
    int d = dst[i];
    int p = offs[d] + atomicAdd(&next[d], 1);
    csr[p] = src[i];
}

// ---- aggregation -----------------------------------------------------------

// 6-dim mean of x[:,4:10]; one thread per node (x is 4MB -> L2-resident)
__global__ __launch_bounds__(256) void k_agg0(const float* __restrict__ x,
                                              const int* __restrict__ offs,
                                              const int* __restrict__ csr,
                                              float* __restrict__ mean0, int nN) {
    int i = blockIdx.x * blockDim.x + threadIdx.x;
    if (i >= nN) return;
    int lo = offs[i], hi = offs[i + 1];
    float a0 = 0, a1 = 0, a2 = 0, a3 = 0, a4 = 0, a5 = 0;
    for (int e = lo; e < hi; ++e) {
        int s = csr[e];
        const float* r = x + (size_t)s * 10 + 4;
        float2 v0 = *(const float2*)(r);
        float2 v1 = *(const float2*)(r + 2);
        float2 v2 = *(const float2*)(r + 4);
        a0 += v0.x; a1 += v0.y; a2 += v1.x; a3 += v1.y; a4 += v2.x; a5 += v2.y;
    }
    float inv = 1.0f / (float)imax(hi - lo, 1);
    float* o = mean0 + (size_t)i * 6;
    o[0] = a0 * inv; o[1] = a1 * inv; o[2] = a2 * inv;
    o[3] = a3 * inv; o[4] = a4 * inv; o[5] = a5 * inv;
}

// 128-dim bf16 mean: wave per node, 2 edges/iter (half-wave each, 4 feats/lane)
__global__ __launch_bounds__(256) void k_agg128(const unsigned short* __restrict__ X,
                                                const int* __restrict__ offs,
                                                const int* __restrict__ csr,
                                                float* __restrict__ M, int nN) {
    int w = (blockIdx.x * 256 + threadIdx.x) >> 6;
    int lane = threadIdx.x & 63;
    if (w >= nN) return;
    int lo = offs[w], hi = offs[w + 1];
    int half = lane >> 5;     // which edge of the pair
    int fl = lane & 31;       // feature group: bf16[fl*4 .. fl*4+3]
    float a0 = 0, a1 = 0, a2 = 0, a3 = 0;
    for (int e = lo + half; e < hi; e += 2) {
        int s = csr[e];
        uint2 v = *(const uint2*)(X + (size_t)s * 128 + fl * 4);
        a0 += bfbits_lo(v.x); a1 += bfbits_hi(v.x);
        a2 += bfbits_lo(v.y); a3 += bfbits_hi(v.y);
    }
    a0 += __shfl_xor(a0, 32); a1 += __shfl_xor(a1, 32);
    a2 += __shfl_xor(a2, 32); a3 += __shfl_xor(a3, 32);
    if (lane < 32) {
        float inv = 1.0f / (float)imax(hi - lo, 1);
        *(float4*)(M + (size_t)w * 128 + fl * 4) =
            make_float4(a0 * inv, a1 * inv, a2 * inv, a3 * inv);
    }
}

// 64-dim bf16 mean: wave per node, 4 edges/iter (16-lane groups, 4 feats/lane)
__global__ __launch_bounds__(256) void k_agg64(const unsigned short* __restrict__ X,
                                               const int* __restrict__ offs,
                                               const int* __restrict__ csr,
                                               float* __restrict__ M, int nN) {
    int w = (blockIdx.x * 256 + threadIdx.x) >> 6;
    int lane = threadIdx.x & 63;
    if (w >= nN) return;
    int lo = offs[w], hi = offs[w + 1];
    int quad = lane >> 4;     // which edge of the quad
    int fl = lane & 15;       // feature group: bf16[fl*4 .. fl*4+3]
    float a0 = 0, a1 = 0, a2 = 0, a3 = 0;
    for (int e = lo + quad; e < hi; e += 4) {
        int s = csr[e];
        uint2 v = *(const uint2*)(X + (size_t)s * 64 + fl * 4);
        a0 += bfbits_lo(v.x); a1 += bfbits_hi(v.x);
        a2 += bfbits_lo(v.y); a3 += bfbits_hi(v.y);
    }
    a0 += __shfl_xor(a0, 32); a1 += __shfl_xor(a1, 32);
    a2 += __shfl_xor(a2, 32); a3 += __shfl_xor(a3, 32);
    a0 += __shfl_xor(a0, 16); a1 += __shfl_xor(a1, 16);
    a2 += __shfl_xor(a2, 16); a3 += __shfl_xor(a3, 16);
    if (lane < 16) {
        float inv = 1.0f / (float)imax(hi - lo, 1);
        *(float4*)(M + (size_t)w * 64 + fl * 4) =
            make_float4(a0 * inv, a1 * inv, a2 * inv, a3 * inv);
    }
}

// ---- dense layers -----------------------------------------------------------

// layer 0 (K=6): one thread per (node, out-feature); weights L1-resident
__global__ __launch_bounds__(256) void k_l0(const float* __restrict__ x,
                                            const float* __restrict__ mean0,
                                            const float* __restrict__ Wl,
                                            const float* __restrict__ bl,
                                            const float* __restrict__ Wr,
                                            unsigned short* __restrict__ out, int nN) {
    int j = threadIdx.x & 127;
    int node = blockIdx.x * 2 + (threadIdx.x >> 7);
    if (node >= nN) return;
    const float* m = mean0 + (size_t)node * 6;
    const float* h = x + (size_t)node * 10 + 4;
    float v = bl[j];
#pragma unroll
    for (int k = 0; k < 6; ++k) v = fmaf(m[k], Wl[k * 128 + j], v);
#pragma unroll
    for (int k = 0; k < 6; ++k) v = fmaf(h[k], Wr[k * 128 + j], v);
    out[(size_t)node * 128 + j] = f2bf(fmaxf(v, 0.f));
}

// stage one 64x32 A-tile (convert to fp32) + 32xN W-tile into LDS
template <typename T, int N>
static __device__ __forceinline__ void stage_tiles(const T* __restrict__ Ap, int lda,
                                                   int krel, const float* __restrict__ Wp,
                                                   int m0, int nN, int tid,
                                                   float (*As)[64], float (*Ws)[N]) {
    int r = tid >> 3;
    int c = (tid & 7) << 2;
#pragma unroll
    for (int h = 0; h < 2; ++h) {
        int row = r + 32 * h;
        int gm = m0 + row;
        float4 v = make_float4(0.f, 0.f, 0.f, 0.f);
        if (gm < nN) v = ld4(Ap + (size_t)gm * lda + krel + c);
        As[c + 0][row] = v.x; As[c + 1][row] = v.y;
        As[c + 2][row] = v.z; As[c + 3][row] = v.w;
    }
    constexpr int NV = N / 4;
#pragma unroll
    for (int q = 0; q < (32 * NV) / 256; ++q) {
        int idx = tid + q * 256;
        int rr = idx / NV;
        int cc = (idx % NV) << 2;
        *(float4*)&Ws[rr][cc] = *(const float4*)(Wp + rr * N + cc);
    }
}

// C[i][:] = act( A[i][:KA]@WA + B[i][:KB]@WB (+bias) (+add[i][:]) )
template <typename TA, typename TB, typename TC, int KA, int KB, int N, bool RELU>
__global__ __launch_bounds__(256) void k_gemm(const TA* __restrict__ A,
                                              const float* __restrict__ WA,
                                              const TB* __restrict__ B,
                                              const float* __restrict__ WB,
                                              const float* __restrict__ bias,
                                              const float* __restrict__ add,
                                              TC* __restrict__ C, int nN) {
    constexpr int BM = 64, BK = 32;
    constexpr int NC = N / 32;
    __shared__ __align__(16) float As[BK][BM];
    __shared__ __align__(16) float Ws[BK][N];
    const int tid = threadIdx.x;
    const int m0 = blockIdx.x * BM;
    const int ty = tid >> 5;
    const int tx = tid & 31;

    float acc[8][NC];
#pragma unroll
    for (int r = 0; r < 8; ++r)
#pragma unroll
        for (int c = 0; c < NC; ++c) acc[r][c] = 0.f;

    auto compute = [&]() {
#pragma unroll
        for (int k = 0; k < BK; ++k) {
            float4 a0 = *(const float4*)&As[k][ty << 3];
            float4 a1 = *(const float4*)&As[k][(ty << 3) + 4];
            float a[8] = {a0.x, a0.y, a0.z, a0.w, a1.x, a1.y, a1.z, a1.w};
            float b[NC];
#pragma unroll
            for (int c = 0; c < NC; ++c) b[c] = Ws[k][tx + 32 * c];
#pragma unroll
            for (int r = 0; r < 8; ++r)
#pragma unroll
                for (int c = 0; c < NC; ++c) acc[r][c] = fmaf(a[r], b[c], acc[r][c]);
        }
    };

    for (int kk = 0; kk < KA; kk += BK) {
        stage_tiles<TA, N>(A, KA, kk, WA + (size_t)kk * N, m0, nN, tid, As, Ws);
        __syncthreads();
        compute();
        __syncthreads();
    }
    if constexpr (KB > 0) {
        for (int kk = 0; kk < KB; kk += BK) {
            stage_tiles<TB, N>(B, KB, kk, WB + (size_t)kk * N, m0, nN, tid, As, Ws);
            __syncthreads();
            compute();
            __syncthreads();
        }
    }

#pragma unroll
    for (int r = 0; r < 8; ++r) {
        int gm = m0 + (ty << 3) + r;
        if (gm >= nN) continue;
#pragma unroll
        for (int c = 0; c < NC; ++c) {
            int n = tx + 32 * c;
            float v = acc[r][c];
            if (bias) v += bias[n];
            if (add) v += add[(size_t)gm * N + n];
            if (RELU) v = fmaxf(v, 0.f);
            st1(&C[(size_t)gm * N + n], v);
        }
    }
}

// ---------------------------------------------------------------------------

extern "C" void kernel_launch(void* const* d_in, const int* in_sizes, int n_in,
                              void* d_out, int out_size, void* d_ws, size_t ws_size,
                              hipStream_t stream) {
    const float* x   = (const float*)d_in[0];
    const int*   ei  = (const int*)d_in[1];
    const float* Wl0 = (const float*)d_in[2];
    const float* bl0 = (const float*)d_in[3];
    const float* Wr0 = (const float*)d_in[4];
    const float* Wl1 = (const float*)d_in[5];
    const float* bl1 = (const float*)d_in[6];
    const float* Wr1 = (const float*)d_in[7];
    const float* Wl2 = (const float*)d_in[8];
    const float* bl2 = (const float*)d_in[9];
    const float* Wr2 = (const float*)d_in[10];

    const int nN = in_sizes[0] / 10;
    const int nE = in_sizes[1] / 2;
    const int* src = ei;
    const int* dst = ei + nE;
    const int nb = (nN + 1023) / 1024;

    char* ws = (char*)d_ws;
    size_t off = 0;
    auto alloc = [&](size_t bytes) -> char* {
        char* p = ws + off;
        off = (off + bytes + 255) & ~(size_t)255;
        return p;
    };
    unsigned short* out0  = (unsigned short*)alloc((size_t)nN * 128 * 2); // bf16; reused as z2
    float* mean1 = (float*)alloc((size_t)nN * 128 * 4);                   // fp32; reused as mean_z2
    float* out1  = (float*)alloc((size_t)nN * 128 * 4);                   // fp32
    float* mean0 = (float*)alloc((size_t)nN * 6 * 4);
    int* cnt  = (int*)alloc((size_t)nN * 4);
    int* next = (int*)alloc((size_t)nN * 4);
    int* offs = (int*)alloc(((size_t)nN + 1) * 4);
    int* csr  = (int*)alloc((size_t)nE * 4);
    int* bsum = (int*)alloc((size_t)nb * 4);

    unsigned short* z2     = out0;   // out0 dead after layer-1 GEMM
    float*          meanz2 = mean1;  // mean1 dead after layer-1 GEMM

    hipMemsetAsync(cnt, 0, (size_t)nN * 4, stream);
    hipMemsetAsync(next, 0, (size_t)nN * 4, stream);

    // build reverse CSR
    k_degree<<<(nE + 255) / 256, 256, 0, stream>>>(dst, cnt, nE);
    k_scan_a<<<nb, 256, 0, stream>>>(cnt, offs, bsum, nN);
    k_scan_b<<<nb, 256, 0, stream>>>(offs, bsum, nN, nb);
    k_fill<<<(nE + 255) / 256, 256, 0, stream>>>(src, dst, offs, next, csr, nE);

    // layer 0 (K=6) -> out0 (bf16)
    k_agg0<<<(nN + 255) / 256, 256, 0, stream>>>(x, offs, csr, mean0, nN);
    k_l0<<<(nN + 1) / 2, 256, 0, stream>>>(x, mean0, Wl0, bl0, Wr0, out0, nN);

    // layer 1: mean1 = agg(out0); out1 = relu(mean1@Wl1 + bl1 + out0@Wr1)
    k_agg128<<<(nN + 3) / 4, 256, 0, stream>>>(out0, offs, csr, mean1, nN);
    k_gemm<float, unsigned short, float, 128, 128, 128, true>
        <<<(nN + 63) / 64, 256, 0, stream>>>(mean1, Wl1, out0, Wr1, bl1, nullptr, out1, nN);

    // layer 2 (reordered): z2 = out1@Wl2 (bf16); out = relu(agg(z2) + bl2 + out1@Wr2)
    k_gemm<float, float, unsigned short, 128, 0, 64, false>
        <<<(nN + 63) / 64, 256, 0, stream>>>(out1, Wl2, nullptr, nullptr, nullptr, nullptr, z2, nN);
    k_agg64<<<(nN + 3) / 4, 256, 0, stream>>>(z2, offs, csr, meanz2, nN);
    k_gemm<float, float, float, 128, 0, 64, true>
        <<<(nN + 63) / 64, 256, 0, stream>>>(out1, Wr2, nullptr, nullptr, bl2, meanz2, (float*)d_out, nN);
}

// Round 3
// 507.397 us; speedup vs baseline: 1.7676x; 1.2202x over previous
//
#include <hip/hip_runtime.h>

// ---------------------------------------------------------------------------
// GraphSAGE 3-layer forward.
//   h = x[:,4:10]; per layer: mean_agg(h) @ Wl + bl + h @ Wr, relu
// Round-3 changes:
//   - all dense GEMMs -> LDS-free bf16 MFMA (mfma_f32_16x16x32_bf16), fp32 acc
//     (was: fp32 vector GEMM, 155us @ VALUBusy 48%, 5.6M LDS bank conflicts)
//   - weights transposed+converted to bf16 Wt[N][K] per call (L2-resident,
//     16B-contiguous B-fragments per lane)
//   - mean1 stored bf16 directly by k_agg128
// ---------------------------------------------------------------------------

typedef __attribute__((ext_vector_type(8))) short bf16x8;   // 8 bf16 = 4 VGPR
typedef __attribute__((ext_vector_type(4))) float f32x4;

static __device__ __forceinline__ int imax(int a, int b) { return a > b ? a : b; }

static __device__ __forceinline__ float bfbits_lo(unsigned u) {
    union { unsigned i; float f; } v; v.i = u << 16; return v.f;
}
static __device__ __forceinline__ float bfbits_hi(unsigned u) {
    union { unsigned i; float f; } v; v.i = u & 0xffff0000u; return v.f;
}
static __device__ __forceinline__ unsigned short f2bf(float f) {
    unsigned u = __float_as_uint(f);
    u = (u + 0x7fffu + ((u >> 16) & 1u)) >> 16;
    return (unsigned short)u;
}

// ---- graph build -----------------------------------------------------------

__global__ __launch_bounds__(256) void k_degree(const int* __restrict__ dst,
                                                int* __restrict__ cnt, int nE) {
    int i = blockIdx.x * blockDim.x + threadIdx.x;
    if (i < nE) atomicAdd(&cnt[dst[i]], 1);
}

__global__ __launch_bounds__(256) void k_scan_a(const int* __restrict__ cnt,
                                                int* __restrict__ offs,
                                                int* __restrict__ bsum, int n) {
    __shared__ int sm[256];
    int t = threadIdx.x;
    int base = blockIdx.x * 1024 + t * 4;
    int v0 = 0, v1 = 0, v2 = 0, v3 = 0;
    if (base + 3 < n) {
        int4 q = *(const int4*)(cnt + base);
        v0 = q.x; v1 = q.y; v2 = q.z; v3 = q.w;
    } else {
        if (base < n)     v0 = cnt[base];
        if (base + 1 < n) v1 = cnt[base + 1];
        if (base + 2 < n) v2 = cnt[base + 2];
    }
    int s = v0 + v1 + v2 + v3;
    sm[t] = s;
    __syncthreads();
    for (int o = 1; o < 256; o <<= 1) {
        int u = (t >= o) ? sm[t - o] : 0;
        __syncthreads();
        sm[t] += u;
        __syncthreads();
    }
    int excl = sm[t] - s;
    if (base < n)     offs[base]     = excl;
    if (base + 1 < n) offs[base + 1] = excl + v0;
    if (base + 2 < n) offs[base + 2] = excl + v0 + v1;
    if (base + 3 < n) offs[base + 3] = excl + v0 + v1 + v2;
    if (t == 255) bsum[blockIdx.x] = sm[255];
}

__global__ __launch_bounds__(256) void k_scan_b(int* __restrict__ offs,
                                                const int* __restrict__ bsum,
                                                int n, int nb) {
    __shared__ int pfx;
    int t = threadIdx.x, b = blockIdx.x;
    if (t == 0) {
        int s = 0;
        for (int i = 0; i < b; ++i) s += bsum[i];
        pfx = s;
        if (b == nb - 1) offs[n] = s + bsum[b];
    }
    __syncthreads();
    if (b == 0) return;
    int base = b * 1024 + t * 4;
    int p = pfx;
    if (base < n)     offs[base]     += p;
    if (base + 1 < n) offs[base + 1] += p;
    if (base + 2 < n) offs[base + 2] += p;
    if (base + 3 < n) offs[base + 3] += p;
}

__global__ __launch_bounds__(256) void k_fill(const int* __restrict__ src,
                                              const int* __restrict__ dst,
                                              const int* __restrict__ offs,
                                              int* __restrict__ next,
                                              int* __restrict__ csr, int nE) {
    int i = blockIdx.x * blockDim.x + threadIdx.x;
    if (i >= nE) return;
    int d = dst[i];
    int p = offs[d] + atomicAdd(&next[d], 1);
    csr[p] = src[i];
}

// ---- weight prep: Wt[n][k] = bf16( k<K1 ? W1[k][n] : W2[k-K1][n] ) ----------

__global__ __launch_bounds__(256) void k_wtcat(const float* __restrict__ W1,
                                               const float* __restrict__ W2,
                                               unsigned short* __restrict__ Wt,
                                               int K1, int K, int N) {
    int idx = blockIdx.x * 256 + threadIdx.x;
    if (idx >= N * K) return;
    int n = idx / K, k = idx % K;
    float v = (k < K1) ? W1[k * N + n] : W2[(k - K1) * N + n];
    Wt[idx] = f2bf(v);
}

// ---- aggregation -----------------------------------------------------------

__global__ __launch_bounds__(256) void k_agg0(const float* __restrict__ x,
                                              const int* __restrict__ offs,
                                              const int* __restrict__ csr,
                                              float* __restrict__ mean0, int nN) {
    int i = blockIdx.x * blockDim.x + threadIdx.x;
    if (i >= nN) return;
    int lo = offs[i], hi = offs[i + 1];
    float a0 = 0, a1 = 0, a2 = 0, a3 = 0, a4 = 0, a5 = 0;
    for (int e = lo; e < hi; ++e) {
        int s = csr[e];
        const float* r = x + (size_t)s * 10 + 4;
        float2 v0 = *(const float2*)(r);
        float2 v1 = *(const float2*)(r + 2);
        float2 v2 = *(const float2*)(r + 4);
        a0 += v0.x; a1 += v0.y; a2 += v1.x; a3 += v1.y; a4 += v2.x; a5 += v2.y;
    }
    float inv = 1.0f / (float)imax(hi - lo, 1);
    float* o = mean0 + (size_t)i * 6;
    o[0] = a0 * inv; o[1] = a1 * inv; o[2] = a2 * inv;
    o[3] = a3 * inv; o[4] = a4 * inv; o[5] = a5 * inv;
}

// 128-dim bf16 mean -> bf16: wave per node, 2 edges/iter
__global__ __launch_bounds__(256) void k_agg128(const unsigned short* __restrict__ X,
                                                const int* __restrict__ offs,
                                                const int* __restrict__ csr,
                                                unsigned short* __restrict__ M, int nN) {
    int w = (blockIdx.x * 256 + threadIdx.x) >> 6;
    int lane = threadIdx.x & 63;
    if (w >= nN) return;
    int lo = offs[w], hi = offs[w + 1];
    int half = lane >> 5;
    int fl = lane & 31;
    float a0 = 0, a1 = 0, a2 = 0, a3 = 0;
    for (int e = lo + half; e < hi; e += 2) {
        int s = csr[e];
        uint2 v = *(const uint2*)(X + (size_t)s * 128 + fl * 4);
        a0 += bfbits_lo(v.x); a1 += bfbits_hi(v.x);
        a2 += bfbits_lo(v.y); a3 += bfbits_hi(v.y);
    }
    a0 += __shfl_xor(a0, 32); a1 += __shfl_xor(a1, 32);
    a2 += __shfl_xor(a2, 32); a3 += __shfl_xor(a3, 32);
    if (lane < 32) {
        float inv = 1.0f / (float)imax(hi - lo, 1);
        ushort4 o;
        o.x = f2bf(a0 * inv); o.y = f2bf(a1 * inv);
        o.z = f2bf(a2 * inv); o.w = f2bf(a3 * inv);
        *(ushort4*)(M + (size_t)w * 128 + fl * 4) = o;
    }
}

// 64-dim bf16 mean -> fp32: wave per node, 4 edges/iter
__global__ __launch_bounds__(256) void k_agg64(const unsigned short* __restrict__ X,
                                               const int* __restrict__ offs,
                                               const int* __restrict__ csr,
                                               float* __restrict__ M, int nN) {
    int w = (blockIdx.x * 256 + threadIdx.x) >> 6;
    int lane = threadIdx.x & 63;
    if (w >= nN) return;
    int lo = offs[w], hi = offs[w + 1];
    int quad = lane >> 4;
    int fl = lane & 15;
    float a0 = 0, a1 = 0, a2 = 0, a3 = 0;
    for (int e = lo + quad; e < hi; e += 4) {
        int s = csr[e];
        uint2 v = *(const uint2*)(X + (size_t)s * 64 + fl * 4);
        a0 += bfbits_lo(v.x); a1 += bfbits_hi(v.x);
        a2 += bfbits_lo(v.y); a3 += bfbits_hi(v.y);
    }
    a0 += __shfl_xor(a0, 32); a1 += __shfl_xor(a1, 32);
    a2 += __shfl_xor(a2, 32); a3 += __shfl_xor(a3, 32);
    a0 += __shfl_xor(a0, 16); a1 += __shfl_xor(a1, 16);
    a2 += __shfl_xor(a2, 16); a3 += __shfl_xor(a3, 16);
    if (lane < 16) {
        float inv = 1.0f / (float)imax(hi - lo, 1);
        *(float4*)(M + (size_t)w * 64 + fl * 4) =
            make_float4(a0 * inv, a1 * inv, a2 * inv, a3 * inv);
    }
}

// ---- layer 0 (K=6): one thread per (node, out-feature) ----------------------

__global__ __launch_bounds__(256) void k_l0(const float* __restrict__ x,
                                            const float* __restrict__ mean0,
                                            const float* __restrict__ Wl,
                                            const float* __restrict__ bl,
                                            const float* __restrict__ Wr,
                                            unsigned short* __restrict__ out, int nN) {
    int j = threadIdx.x & 127;
    int node = blockIdx.x * 2 + (threadIdx.x >> 7);
    if (node >= nN) return;
    const float* m = mean0 + (size_t)node * 6;
    const float* h = x + (size_t)node * 10 + 4;
    float v = bl[j];
#pragma unroll
    for (int k = 0; k < 6; ++k) v = fmaf(m[k], Wl[k * 128 + j], v);
#pragma unroll
    for (int k = 0; k < 6; ++k) v = fmaf(h[k], Wr[k * 128 + j], v);
    out[(size_t)node * 128 + j] = f2bf(fmaxf(v, 0.f));
}

// ---- MFMA GEMM: C = act( [A0|A1] @ Wt^T (+bias) (+add) ) --------------------
// A0: [nN][KA] bf16, A1: [nN][KB] bf16 (KB may be 0), Wt: [N][KA+KB] bf16.
// One wave per 32 rows x N cols; no LDS, no barriers.
// mfma_f32_16x16x32_bf16 lane mapping: A row = lane&15, k = (lane>>4)*8 + e;
// B col = lane&15, same k; C/D col = lane&15, row = (lane>>4)*4 + r.
template <int KA, int KB, int N, bool RELU, bool BF16OUT, bool HASBIAS, bool HASADD>
__global__ __launch_bounds__(256) void k_mfma(const unsigned short* __restrict__ A0,
                                              const unsigned short* __restrict__ A1,
                                              const unsigned short* __restrict__ Wt,
                                              const float* __restrict__ bias,
                                              const float* __restrict__ add,
                                              void* __restrict__ Cout, int nN) {
    constexpr int K = KA + KB;
    constexpr int NB = N / 16;
    const int tid = threadIdx.x;
    const int wave = (blockIdx.x * 256 + tid) >> 6;
    const int m0 = wave * 32;
    if (m0 >= nN) return;          // 32 | nN-tile boundary: waves fully in or out
    const int lane = tid & 63;
    const int lr = lane & 15;      // A-row / B-col / C-col within fragment
    const int lk = lane >> 4;      // k-group (0..3)

    f32x4 acc[2][NB];
#pragma unroll
    for (int g = 0; g < 2; ++g)
#pragma unroll
        for (int n = 0; n < NB; ++n) acc[g][n] = (f32x4){0.f, 0.f, 0.f, 0.f};

#pragma unroll
    for (int kk = 0; kk < K; kk += 32) {
        const unsigned short* Ap;
        int lda, krel;
        if (KB > 0 && kk >= KA) { Ap = A1; lda = KB; krel = kk - KA; }
        else                    { Ap = A0; lda = KA; krel = kk; }
        bf16x8 a0 = *(const bf16x8*)(Ap + (size_t)(m0 + lr) * lda + krel + lk * 8);
        bf16x8 a1 = *(const bf16x8*)(Ap + (size_t)(m0 + 16 + lr) * lda + krel + lk * 8);
#pragma unroll
        for (int n = 0; n < NB; ++n) {
            bf16x8 b = *(const bf16x8*)(Wt + (size_t)(n * 16 + lr) * K + kk + lk * 8);
            acc[0][n] = __builtin_amdgcn_mfma_f32_16x16x32_bf16(a0, b, acc[0][n], 0, 0, 0);
            acc[1][n] = __builtin_amdgcn_mfma_f32_16x16x32_bf16(a1, b, acc[1][n], 0, 0, 0);
        }
    }

#pragma unroll
    for (int g = 0; g < 2; ++g) {
#pragma unroll
        for (int r = 0; r < 4; ++r) {
            int gm = m0 + g * 16 + lk * 4 + r;
#pragma unroll
            for (int n = 0; n < NB; ++n) {
                float v = acc[g][n][r];
                if (HASBIAS) v += bias[n * 16 + lr];
                if (HASADD)  v += add[(size_t)gm * N + n * 16 + lr];
                if (RELU)    v = fmaxf(v, 0.f);
                if (BF16OUT) ((unsigned short*)Cout)[(size_t)gm * N + n * 16 + lr] = f2bf(v);
                else         ((float*)Cout)[(size_t)gm * N + n * 16 + lr] = v;
            }
        }
    }
}

// ---------------------------------------------------------------------------

extern "C" void kernel_launch(void* const* d_in, const int* in_sizes, int n_in,
                              void* d_out, int out_size, void* d_ws, size_t ws_size,
                              hipStream_t stream) {
    const float* x   = (const float*)d_in[0];
    const int*   ei  = (const int*)d_in[1];
    const float* Wl0 = (const float*)d_in[2];
    const float* bl0 = (const float*)d_in[3];
    const float* Wr0 = (const float*)d_in[4];
    const float* Wl1 = (const float*)d_in[5];
    const float* bl1 = (const float*)d_in[6];
    const float* Wr1 = (const float*)d_in[7];
    const float* Wl2 = (const float*)d_in[8];
    const float* bl2 = (const float*)d_in[9];
    const float* Wr2 = (const float*)d_in[10];

    const int nN = in_sizes[0] / 10;
    const int nE = in_sizes[1] / 2;
    const int* src = ei;
    const int* dst = ei + nE;
    const int nb = (nN + 1023) / 1024;

    char* ws = (char*)d_ws;
    size_t off = 0;
    auto alloc = [&](size_t bytes) -> char* {
        char* p = ws + off;
        off = (off + bytes + 255) & ~(size_t)255;
        return p;
    };
    unsigned short* out0  = (unsigned short*)alloc((size_t)nN * 128 * 2); // reused as z2
    unsigned short* mean1 = (unsigned short*)alloc((size_t)nN * 128 * 2); // reused as meanz2 (fp32 x64)
    unsigned short* out1  = (unsigned short*)alloc((size_t)nN * 128 * 2);
    float* mean0 = (float*)alloc((size_t)nN * 6 * 4);
    unsigned short* Wt1  = (unsigned short*)alloc((size_t)128 * 256 * 2);
    unsigned short* Wt2l = (unsigned short*)alloc((size_t)64 * 128 * 2);
    unsigned short* Wt2r = (unsigned short*)alloc((size_t)64 * 128 * 2);
    int* cnt  = (int*)alloc((size_t)nN * 4);
    int* next = (int*)alloc((size_t)nN * 4);
    int* offs = (int*)alloc(((size_t)nN + 1) * 4);
    int* csr  = (int*)alloc((size_t)nE * 4);
    int* bsum = (int*)alloc((size_t)nb * 4);

    unsigned short* z2     = out0;            // out0 dead after layer-1 GEMM
    float*          meanz2 = (float*)mean1;   // mean1 dead after layer-1 GEMM

    hipMemsetAsync(cnt, 0, (size_t)nN * 4, stream);
    hipMemsetAsync(next, 0, (size_t)nN * 4, stream);

    // weight prep (independent of graph build)
    k_wtcat<<<(128 * 256 + 255) / 256, 256, 0, stream>>>(Wl1, Wr1, Wt1, 128, 256, 128);
    k_wtcat<<<(64 * 128 + 255) / 256, 256, 0, stream>>>(Wl2, Wl2, Wt2l, 128, 128, 64);
    k_wtcat<<<(64 * 128 + 255) / 256, 256, 0, stream>>>(Wr2, Wr2, Wt2r, 128, 128, 64);

    // build reverse CSR
    k_degree<<<(nE + 255) / 256, 256, 0, stream>>>(dst, cnt, nE);
    k_scan_a<<<nb, 256, 0, stream>>>(cnt, offs, bsum, nN);
    k_scan_b<<<nb, 256, 0, stream>>>(offs, bsum, nN, nb);
    k_fill<<<(nE + 255) / 256, 256, 0, stream>>>(src, dst, offs, next, csr, nE);

    // layer 0 (K=6) -> out0 (bf16)
    k_agg0<<<(nN + 255) / 256, 256, 0, stream>>>(x, offs, csr, mean0, nN);
    k_l0<<<(nN + 1) / 2, 256, 0, stream>>>(x, mean0, Wl0, bl0, Wr0, out0, nN);

    const int gemm_grid = (nN / 32 + 3) / 4 + 1;   // 4 waves/block, 32 rows/wave

    // layer 1: mean1 = agg(out0); out1 = relu([mean1|out0] @ Wt1^T + bl1)
    k_agg128<<<(nN + 3) / 4, 256, 0, stream>>>(out0, offs, csr, mean1, nN);
    k_mfma<128, 128, 128, true, true, true, false><<<gemm_grid, 256, 0, stream>>>(
        mean1, out0, Wt1, bl1, nullptr, out1, nN);

    // layer 2 (reordered): z2 = out1@Wl2 (bf16); out = relu(out1@Wr2 + bl2 + agg(z2))
    k_mfma<128, 0, 64, false, true, false, false><<<gemm_grid, 256, 0, stream>>>(
        out1, nullptr, Wt2l, nullptr, nullptr, z2, nN);
    k_agg64<<<(nN + 3) / 4, 256, 0, stream>>>(z2, offs, csr, meanz2, nN);
    k_mfma<128, 0, 64, true, false, true, true><<<gemm_grid, 256, 0, stream>>>(
        out1, nullptr, Wt2r, bl2, meanz2, (float*)d_out, nN);
}

// Round 4
// 332.686 us; speedup vs baseline: 2.6959x; 1.5252x over previous
//
#include <hip/hip_runtime.h>

// ---------------------------------------------------------------------------
// GraphSAGE 3-layer forward.
//   h = x[:,4:10]; per layer: mean_agg(h) @ Wl + bl + h @ Wr, relu
// Round-4 changes:
//   - CSR build: bucket partition (dst>>8) -> per-bucket counting sort.
//     Replaces k_fill (105us, WRITE_SIZE 107MB: 4B scatters = full-line
//     writebacks split across XCDs) + k_degree (1.6M global atomics) + scans.
//     All writes are now block-private dense regions.
//   - offs[] computed for free in k_p2fill's per-bucket LDS histogram+scan.
//   - agg128/agg64: uint4 16B loads, 4/8 edges in flight per wave.
// ---------------------------------------------------------------------------

typedef __attribute__((ext_vector_type(8))) short bf16x8;   // 8 bf16 = 4 VGPR
typedef __attribute__((ext_vector_type(4))) float f32x4;

constexpr int PB = 256;   // partition pass blocks (== colscan threads, fixed)

static __device__ __forceinline__ int imax(int a, int b) { return a > b ? a : b; }

static __device__ __forceinline__ float bfbits_lo(unsigned u) {
    union { unsigned i; float f; } v; v.i = u << 16; return v.f;
}
static __device__ __forceinline__ float bfbits_hi(unsigned u) {
    union { unsigned i; float f; } v; v.i = u & 0xffff0000u; return v.f;
}
static __device__ __forceinline__ unsigned short f2bf(float f) {
    unsigned u = __float_as_uint(f);
    u = (u + 0x7fffu + ((u >> 16) & 1u)) >> 16;
    return (unsigned short)u;
}
static __device__ __forceinline__ unsigned pack2bf(float a, float b) {
    return (unsigned)f2bf(a) | ((unsigned)f2bf(b) << 16);
}

// ---- graph build: bucket partition + per-bucket counting sort ---------------

// pass 1a: per-(block,bucket) edge counts. C[PB][nbk].
__global__ __launch_bounds__(256) void k_p1count(const int* __restrict__ dst,
                                                 int* __restrict__ C,
                                                 int nE, int nbk, int epb) {
    __shared__ int h[512];
    for (int i = threadIdx.x; i < nbk; i += 256) h[i] = 0;
    __syncthreads();
    int e0 = blockIdx.x * epb;
    int e1 = min(e0 + epb, nE);
    for (int i = e0 + threadIdx.x; i < e1; i += 256)
        atomicAdd(&h[dst[i] >> 8], 1);
    __syncthreads();
    for (int i = threadIdx.x; i < nbk; i += 256)
        C[blockIdx.x * nbk + i] = h[i];
}

// pass 1b: exclusive scan down each bucket column (over the PB=256 blocks);
// emit per-bucket totals.
__global__ __launch_bounds__(256) void k_colscan(int* __restrict__ C,
                                                 int* __restrict__ tot, int nbk) {
    __shared__ int sm[256];
    int k = blockIdx.x, t = threadIdx.x;
    int v = C[t * nbk + k];
    sm[t] = v;
    __syncthreads();
    for (int o = 1; o < 256; o <<= 1) {
        int u = (t >= o) ? sm[t - o] : 0;
        __syncthreads();
        sm[t] += u;
        __syncthreads();
    }
    C[t * nbk + k] = sm[t] - v;
    if (t == 255) tot[k] = sm[255];
}

// small scan (n <= 1024, one block) for bucket starts
__global__ __launch_bounds__(256) void k_scan_a(const int* __restrict__ cnt,
                                                int* __restrict__ offs,
                                                int* __restrict__ bsum, int n) {
    __shared__ int sm[256];
    int t = threadIdx.x;
    int base = blockIdx.x * 1024 + t * 4;
    int v0 = 0, v1 = 0, v2 = 0, v3 = 0;
    if (base + 3 < n) {
        int4 q = *(const int4*)(cnt + base);
        v0 = q.x; v1 = q.y; v2 = q.z; v3 = q.w;
    } else {
        if (base < n)     v0 = cnt[base];
        if (base + 1 < n) v1 = cnt[base + 1];
        if (base + 2 < n) v2 = cnt[base + 2];
    }
    int s = v0 + v1 + v2 + v3;
    sm[t] = s;
    __syncthreads();
    for (int o = 1; o < 256; o <<= 1) {
        int u = (t >= o) ? sm[t - o] : 0;
        __syncthreads();
        sm[t] += u;
        __syncthreads();
    }
    int excl = sm[t] - s;
    if (base < n)     offs[base]     = excl;
    if (base + 1 < n) offs[base + 1] = excl + v0;
    if (base + 2 < n) offs[base + 2] = excl + v0 + v1;
    if (base + 3 < n) offs[base + 3] = excl + v0 + v1 + v2;
    if (t == 255) bsum[blockIdx.x] = sm[255];
}

__global__ __launch_bounds__(256) void k_scan_b(int* __restrict__ offs,
                                                const int* __restrict__ bsum,
                                                int n, int nb) {
    __shared__ int pfx;
    int t = threadIdx.x, b = blockIdx.x;
    if (t == 0) {
        int s = 0;
        for (int i = 0; i < b; ++i) s += bsum[i];
        pfx = s;
        if (b == nb - 1) offs[n] = s + bsum[b];
    }
    __syncthreads();
    if (b == 0) return;
    int base = b * 1024 + t * 4;
    int p = pfx;
    if (base < n)     offs[base]     += p;
    if (base + 1 < n) offs[base + 1] += p;
    if (base + 2 < n) offs[base + 2] += p;
    if (base + 3 < n) offs[base + 3] += p;
}

// pass 2: scatter packed (src<<8 | dst&255) into bucket-partitioned ebuf.
// Each (block,bucket) writes a private contiguous run.
__global__ __launch_bounds__(256) void k_p1fill(const int* __restrict__ src,
                                                const int* __restrict__ dst,
                                                const int* __restrict__ bstart,
                                                const int* __restrict__ C,
                                                unsigned* __restrict__ ebuf,
                                                int nE, int nbk, int epb) {
    __shared__ int cur[512];
    int b = blockIdx.x;
    for (int i = threadIdx.x; i < nbk; i += 256)
        cur[i] = bstart[i] + C[b * nbk + i];
    __syncthreads();
    int e0 = b * epb;
    int e1 = min(e0 + epb, nE);
    for (int i = e0 + threadIdx.x; i < e1; i += 256) {
        int d = dst[i];
        unsigned s = (unsigned)src[i];
        int p = atomicAdd(&cur[d >> 8], 1);
        ebuf[p] = (s << 8) | (unsigned)(d & 255);
    }
}

// pass 3: one block per bucket. LDS hist over 256 local dsts gives offs[] and
// exact csr placement; all csr writes land in this block's dense 16KB region.
__global__ __launch_bounds__(256) void k_p2fill(const unsigned* __restrict__ ebuf,
                                                const int* __restrict__ bstart,
                                                int* __restrict__ offs,
                                                int* __restrict__ csr,
                                                int nN, int nE) {
    __shared__ int h[256], sm[256], cur[256];
    int k = blockIdx.x, t = threadIdx.x;
    int base = bstart[k], end = bstart[k + 1];
    h[t] = 0;
    __syncthreads();
    for (int i = base + t; i < end; i += 256)
        atomicAdd(&h[ebuf[i] & 255u], 1);
    __syncthreads();
    int v = h[t];
    sm[t] = v;
    __syncthreads();
    for (int o = 1; o < 256; o <<= 1) {
        int u = (t >= o) ? sm[t - o] : 0;
        __syncthreads();
        sm[t] += u;
        __syncthreads();
    }
    int excl = sm[t] - v;
    int node = (k << 8) + t;
    if (node < nN) offs[node] = base + excl;
    cur[t] = base + excl;
    if (k == 0 && t == 0) offs[nN] = nE;
    __syncthreads();
    for (int i = base + t; i < end; i += 256) {
        unsigned e = ebuf[i];
        int p = atomicAdd(&cur[e & 255u], 1);
        csr[p] = (int)(e >> 8);
    }
}

// ---- weight prep: Wt[n][k] = bf16( k<K1 ? W1[k][n] : W2[k-K1][n] ) ----------

__global__ __launch_bounds__(256) void k_wtcat(const float* __restrict__ W1,
                                               const float* __restrict__ W2,
                                               unsigned short* __restrict__ Wt,
                                               int K1, int K, int N) {
    int idx = blockIdx.x * 256 + threadIdx.x;
    if (idx >= N * K) return;
    int n = idx / K, k = idx % K;
    float v = (k < K1) ? W1[k * N + n] : W2[(k - K1) * N + n];
    Wt[idx] = f2bf(v);
}

// ---- aggregation -----------------------------------------------------------

__global__ __launch_bounds__(256) void k_agg0(const float* __restrict__ x,
                                              const int* __restrict__ offs,
                                              const int* __restrict__ csr,
                                              float* __restrict__ mean0, int nN) {
    int i = blockIdx.x * blockDim.x + threadIdx.x;
    if (i >= nN) return;
    int lo = offs[i], hi = offs[i + 1];
    float a0 = 0, a1 = 0, a2 = 0, a3 = 0, a4 = 0, a5 = 0;
    for (int e = lo; e < hi; ++e) {
        int s = csr[e];
        const float* r = x + (size_t)s * 10 + 4;
        float2 v0 = *(const float2*)(r);
        float2 v1 = *(const float2*)(r + 2);
        float2 v2 = *(const float2*)(r + 4);
        a0 += v0.x; a1 += v0.y; a2 += v1.x; a3 += v1.y; a4 += v2.x; a5 += v2.y;
    }
    float inv = 1.0f / (float)imax(hi - lo, 1);
    float* o = mean0 + (size_t)i * 6;
    o[0] = a0 * inv; o[1] = a1 * inv; o[2] = a2 * inv;
    o[3] = a3 * inv; o[4] = a4 * inv; o[5] = a5 * inv;
}

// 128-dim bf16 mean -> bf16: wave per node, 4 edges/iter, uint4 loads
__global__ __launch_bounds__(256) void k_agg128(const unsigned short* __restrict__ X,
                                                const int* __restrict__ offs,
                                                const int* __restrict__ csr,
                                                unsigned short* __restrict__ M, int nN) {
    int w = (blockIdx.x * 256 + threadIdx.x) >> 6;
    int lane = threadIdx.x & 63;
    if (w >= nN) return;
    int lo = offs[w], hi = offs[w + 1];
    int quad = lane >> 4;     // edge slot 0..3
    int fl = lane & 15;       // feature block: bf16[fl*8 .. fl*8+7]
    float a0 = 0, a1 = 0, a2 = 0, a3 = 0, a4 = 0, a5 = 0, a6 = 0, a7 = 0;
    for (int e = lo + quad; e < hi; e += 4) {
        int s = csr[e];
        uint4 v = *(const uint4*)(X + (size_t)s * 128 + fl * 8);
        a0 += bfbits_lo(v.x); a1 += bfbits_hi(v.x);
        a2 += bfbits_lo(v.y); a3 += bfbits_hi(v.y);
        a4 += bfbits_lo(v.z); a5 += bfbits_hi(v.z);
        a6 += bfbits_lo(v.w); a7 += bfbits_hi(v.w);
    }
    a0 += __shfl_xor(a0, 32); a1 += __shfl_xor(a1, 32);
    a2 += __shfl_xor(a2, 32); a3 += __shfl_xor(a3, 32);
    a4 += __shfl_xor(a4, 32); a5 += __shfl_xor(a5, 32);
    a6 += __shfl_xor(a6, 32); a7 += __shfl_xor(a7, 32);
    a0 += __shfl_xor(a0, 16); a1 += __shfl_xor(a1, 16);
    a2 += __shfl_xor(a2, 16); a3 += __shfl_xor(a3, 16);
    a4 += __shfl_xor(a4, 16); a5 += __shfl_xor(a5, 16);
    a6 += __shfl_xor(a6, 16); a7 += __shfl_xor(a7, 16);
    if (lane < 16) {
        float inv = 1.0f / (float)imax(hi - lo, 1);
        uint4 o;
        o.x = pack2bf(a0 * inv, a1 * inv);
        o.y = pack2bf(a2 * inv, a3 * inv);
        o.z = pack2bf(a4 * inv, a5 * inv);
        o.w = pack2bf(a6 * inv, a7 * inv);
        *(uint4*)(M + (size_t)w * 128 + fl * 8) = o;
    }
}

// 64-dim bf16 mean -> fp32: wave per node, 8 edges/iter, uint4 loads
__global__ __launch_bounds__(256) void k_agg64(const unsigned short* __restrict__ X,
                                               const int* __restrict__ offs,
                                               const int* __restrict__ csr,
                                               float* __restrict__ M, int nN) {
    int w = (blockIdx.x * 256 + threadIdx.x) >> 6;
    int lane = threadIdx.x & 63;
    if (w >= nN) return;
    int lo = offs[w], hi = offs[w + 1];
    int oct = lane >> 3;      // edge slot 0..7
    int fl = lane & 7;        // feature block: bf16[fl*8 .. fl*8+7]
    float a0 = 0, a1 = 0, a2 = 0, a3 = 0, a4 = 0, a5 = 0, a6 = 0, a7 = 0;
    for (int e = lo + oct; e < hi; e += 8) {
        int s = csr[e];
        uint4 v = *(const uint4*)(X + (size_t)s * 64 + fl * 8);
        a0 += bfbits_lo(v.x); a1 += bfbits_hi(v.x);
        a2 += bfbits_lo(v.y); a3 += bfbits_hi(v.y);
        a4 += bfbits_lo(v.z); a5 += bfbits_hi(v.z);
        a6 += bfbits_lo(v.w); a7 += bfbits_hi(v.w);
    }
    a0 += __shfl_xor(a0, 32); a1 += __shfl_xor(a1, 32);
    a2 += __shfl_xor(a2, 32); a3 += __shfl_xor(a3, 32);
    a4 += __shfl_xor(a4, 32); a5 += __shfl_xor(a5, 32);
    a6 += __shfl_xor(a6, 32); a7 += __shfl_xor(a7, 32);
    a0 += __shfl_xor(a0, 16); a1 += __shfl_xor(a1, 16);
    a2 += __shfl_xor(a2, 16); a3 += __shfl_xor(a3, 16);
    a4 += __shfl_xor(a4, 16); a5 += __shfl_xor(a5, 16);
    a6 += __shfl_xor(a6, 16); a7 += __shfl_xor(a7, 16);
    a0 += __shfl_xor(a0, 8);  a1 += __shfl_xor(a1, 8);
    a2 += __shfl_xor(a2, 8);  a3 += __shfl_xor(a3, 8);
    a4 += __shfl_xor(a4, 8);  a5 += __shfl_xor(a5, 8);
    a6 += __shfl_xor(a6, 8);  a7 += __shfl_xor(a7, 8);
    if (lane < 8) {
        float inv = 1.0f / (float)imax(hi - lo, 1);
        float* o = M + (size_t)w * 64 + fl * 8;
        *(float4*)(o)     = make_float4(a0 * inv, a1 * inv, a2 * inv, a3 * inv);
        *(float4*)(o + 4) = make_float4(a4 * inv, a5 * inv, a6 * inv, a7 * inv);
    }
}

// ---- layer 0 (K=6): one thread per (node, out-feature) ----------------------

__global__ __launch_bounds__(256) void k_l0(const float* __restrict__ x,
                                            const float* __restrict__ mean0,
                                            const float* __restrict__ Wl,
                                            const float* __restrict__ bl,
                                            const float* __restrict__ Wr,
                                            unsigned short* __restrict__ out, int nN) {
    int j = threadIdx.x & 127;
    int node = blockIdx.x * 2 + (threadIdx.x >> 7);
    if (node >= nN) return;
    const float* m = mean0 + (size_t)node * 6;
    const float* h = x + (size_t)node * 10 + 4;
    float v = bl[j];
#pragma unroll
    for (int k = 0; k < 6; ++k) v = fmaf(m[k], Wl[k * 128 + j], v);
#pragma unroll
    for (int k = 0; k < 6; ++k) v = fmaf(h[k], Wr[k * 128 + j], v);
    out[(size_t)node * 128 + j] = f2bf(fmaxf(v, 0.f));
}

// ---- MFMA GEMM: C = act( [A0|A1] @ Wt^T (+bias) (+add) ) --------------------

template <int KA, int KB, int N, bool RELU, bool BF16OUT, bool HASBIAS, bool HASADD>
__global__ __launch_bounds__(256) void k_mfma(const unsigned short* __restrict__ A0,
                                              const unsigned short* __restrict__ A1,
                                              const unsigned short* __restrict__ Wt,
                                              const float* __restrict__ bias,
                                              const float* __restrict__ add,
                                              void* __restrict__ Cout, int nN) {
    constexpr int K = KA + KB;
    constexpr int NB = N / 16;
    const int tid = threadIdx.x;
    const int wave = (blockIdx.x * 256 + tid) >> 6;
    const int m0 = wave * 32;
    if (m0 >= nN) return;
    const int lane = tid & 63;
    const int lr = lane & 15;
    const int lk = lane >> 4;

    f32x4 acc[2][NB];
#pragma unroll
    for (int g = 0; g < 2; ++g)
#pragma unroll
        for (int n = 0; n < NB; ++n) acc[g][n] = (f32x4){0.f, 0.f, 0.f, 0.f};

#pragma unroll
    for (int kk = 0; kk < K; kk += 32) {
        const unsigned short* Ap;
        int lda, krel;
        if (KB > 0 && kk >= KA) { Ap = A1; lda = KB; krel = kk - KA; }
        else                    { Ap = A0; lda = KA; krel = kk; }
        bf16x8 a0 = *(const bf16x8*)(Ap + (size_t)(m0 + lr) * lda + krel + lk * 8);
        bf16x8 a1 = *(const bf16x8*)(Ap + (size_t)(m0 + 16 + lr) * lda + krel + lk * 8);
#pragma unroll
        for (int n = 0; n < NB; ++n) {
            bf16x8 b = *(const bf16x8*)(Wt + (size_t)(n * 16 + lr) * K + kk + lk * 8);
            acc[0][n] = __builtin_amdgcn_mfma_f32_16x16x32_bf16(a0, b, acc[0][n], 0, 0, 0);
            acc[1][n] = __builtin_amdgcn_mfma_f32_16x16x32_bf16(a1, b, acc[1][n], 0, 0, 0);
        }
    }

#pragma unroll
    for (int g = 0; g < 2; ++g) {
#pragma unroll
        for (int r = 0; r < 4; ++r) {
            int gm = m0 + g * 16 + lk * 4 + r;
#pragma unroll
            for (int n = 0; n < NB; ++n) {
                float v = acc[g][n][r];
                if (HASBIAS) v += bias[n * 16 + lr];
                if (HASADD)  v += add[(size_t)gm * N + n * 16 + lr];
                if (RELU)    v = fmaxf(v, 0.f);
                if (BF16OUT) ((unsigned short*)Cout)[(size_t)gm * N + n * 16 + lr] = f2bf(v);
                else         ((float*)Cout)[(size_t)gm * N + n * 16 + lr] = v;
            }
        }
    }
}

// ---------------------------------------------------------------------------

extern "C" void kernel_launch(void* const* d_in, const int* in_sizes, int n_in,
                              void* d_out, int out_size, void* d_ws, size_t ws_size,
                              hipStream_t stream) {
    const float* x   = (const float*)d_in[0];
    const int*   ei  = (const int*)d_in[1];
    const float* Wl0 = (const float*)d_in[2];
    const float* bl0 = (const float*)d_in[3];
    const float* Wr0 = (const float*)d_in[4];
    const float* Wl1 = (const float*)d_in[5];
    const float* bl1 = (const float*)d_in[6];
    const float* Wr1 = (const float*)d_in[7];
    const float* Wl2 = (const float*)d_in[8];
    const float* bl2 = (const float*)d_in[9];
    const float* Wr2 = (const float*)d_in[10];

    const int nN = in_sizes[0] / 10;
    const int nE = in_sizes[1] / 2;
    const int* src = ei;
    const int* dst = ei + nE;
    const int nbk = (nN + 255) >> 8;            // 391 buckets (<=512 for LDS)
    const int epb = (nE + PB - 1) / PB;         // edges per partition block

    char* ws = (char*)d_ws;
    size_t off = 0;
    auto alloc = [&](size_t bytes) -> char* {
        char* p = ws + off;
        off = (off + bytes + 255) & ~(size_t)255;
        return p;
    };
    unsigned short* out0  = (unsigned short*)alloc((size_t)nN * 128 * 2); // reused as z2
    unsigned short* mean1 = (unsigned short*)alloc((size_t)nN * 128 * 2); // reused as meanz2 (fp32 x64)
    unsigned short* out1  = (unsigned short*)alloc((size_t)nN * 128 * 2);
    float* mean0 = (float*)alloc((size_t)nN * 6 * 4);
    unsigned short* Wt1  = (unsigned short*)alloc((size_t)128 * 256 * 2);
    unsigned short* Wt2l = (unsigned short*)alloc((size_t)64 * 128 * 2);
    unsigned short* Wt2r = (unsigned short*)alloc((size_t)64 * 128 * 2);
    int* C      = (int*)alloc((size_t)PB * nbk * 4);
    int* tot    = (int*)alloc((size_t)nbk * 4);
    int* bstart = (int*)alloc(((size_t)nbk + 1) * 4);
    int* bsum   = (int*)alloc(4 * 4);
    int* offs   = (int*)alloc(((size_t)nN + 1) * 4);
    int* csr    = (int*)alloc((size_t)nE * 4);
    unsigned* ebuf = (unsigned*)alloc((size_t)nE * 4);

    unsigned short* z2     = out0;            // out0 dead after layer-1 GEMM
    float*          meanz2 = (float*)mean1;   // mean1 dead after layer-1 GEMM

    // weight prep (independent of graph build)
    k_wtcat<<<(128 * 256 + 255) / 256, 256, 0, stream>>>(Wl1, Wr1, Wt1, 128, 256, 128);
    k_wtcat<<<(64 * 128 + 255) / 256, 256, 0, stream>>>(Wl2, Wl2, Wt2l, 128, 128, 64);
    k_wtcat<<<(64 * 128 + 255) / 256, 256, 0, stream>>>(Wr2, Wr2, Wt2r, 128, 128, 64);

    // build dst-sorted CSR via bucket partition (no global atomics, dense writes)
    k_p1count<<<PB, 256, 0, stream>>>(dst, C, nE, nbk, epb);
    k_colscan<<<nbk, 256, 0, stream>>>(C, tot, nbk);
    k_scan_a<<<1, 256, 0, stream>>>(tot, bstart, bsum, nbk);
    k_scan_b<<<1, 256, 0, stream>>>(bstart, bsum, nbk, 1);
    k_p1fill<<<PB, 256, 0, stream>>>(src, dst, bstart, C, ebuf, nE, nbk, epb);
    k_p2fill<<<nbk, 256, 0, stream>>>(ebuf, bstart, offs, csr, nN, nE);

    // layer 0 (K=6) -> out0 (bf16)
    k_agg0<<<(nN + 255) / 256, 256, 0, stream>>>(x, offs, csr, mean0, nN);
    k_l0<<<(nN + 1) / 2, 256, 0, stream>>>(x, mean0, Wl0, bl0, Wr0, out0, nN);

    const int gemm_grid = (nN / 32 + 3) / 4 + 1;   // 4 waves/block, 32 rows/wave

    // layer 1: mean1 = agg(out0); out1 = relu([mean1|out0] @ Wt1^T + bl1)
    k_agg128<<<(nN + 3) / 4, 256, 0, stream>>>(out0, offs, csr, mean1, nN);
    k_mfma<128, 128, 128, true, true, true, false><<<gemm_grid, 256, 0, stream>>>(
        mean1, out0, Wt1, bl1, nullptr, out1, nN);

    // layer 2 (reordered): z2 = out1@Wl2 (bf16); out = relu(out1@Wr2 + bl2 + agg(z2))
    k_mfma<128, 0, 64, false, true, false, false><<<gemm_grid, 256, 0, stream>>>(
        out1, nullptr, Wt2l, nullptr, nullptr, z2, nN);
    k_agg64<<<(nN + 3) / 4, 256, 0, stream>>>(z2, offs, csr, meanz2, nN);
    k_mfma<128, 0, 64, true, false, true, true><<<gemm_grid, 256, 0, stream>>>(
        out1, nullptr, Wt2r, bl2, meanz2, (float*)d_out, nN);
}

// Round 5
// 315.523 us; speedup vs baseline: 2.8426x; 1.0544x over previous
//
#include <hip/hip_runtime.h>

// ---------------------------------------------------------------------------
// GraphSAGE 3-layer forward.
//   h = x[:,4:10]; per layer: mean_agg(h) @ Wl + bl + h @ Wr, relu
// Round-5 changes:
//   - agg128/agg64 restructured: thread-per-(node,16B-chunk), private 4x-
//     unrolled edge loop -> 4 independent uint4 loads in flight per thread,
//     no cross-lane reduce. (was: wave-per-node, 65us @ VALUBusy 42%,
//     2.7 TB/s beyond-L2 = latency-bound, ~1 load in flight per thread)
// ---------------------------------------------------------------------------

typedef __attribute__((ext_vector_type(8))) short bf16x8;   // 8 bf16 = 4 VGPR
typedef __attribute__((ext_vector_type(4))) float f32x4;

constexpr int PB = 256;   // partition pass blocks (== colscan threads, fixed)

static __device__ __forceinline__ int imax(int a, int b) { return a > b ? a : b; }

static __device__ __forceinline__ float bfbits_lo(unsigned u) {
    union { unsigned i; float f; } v; v.i = u << 16; return v.f;
}
static __device__ __forceinline__ float bfbits_hi(unsigned u) {
    union { unsigned i; float f; } v; v.i = u & 0xffff0000u; return v.f;
}
static __device__ __forceinline__ unsigned short f2bf(float f) {
    unsigned u = __float_as_uint(f);
    u = (u + 0x7fffu + ((u >> 16) & 1u)) >> 16;
    return (unsigned short)u;
}
static __device__ __forceinline__ unsigned pack2bf(float a, float b) {
    return (unsigned)f2bf(a) | ((unsigned)f2bf(b) << 16);
}

// ---- graph build: bucket partition + per-bucket counting sort ---------------

// pass 1a: per-(block,bucket) edge counts. C[PB][nbk].
__global__ __launch_bounds__(256) void k_p1count(const int* __restrict__ dst,
                                                 int* __restrict__ C,
                                                 int nE, int nbk, int epb) {
    __shared__ int h[512];
    for (int i = threadIdx.x; i < nbk; i += 256) h[i] = 0;
    __syncthreads();
    int e0 = blockIdx.x * epb;
    int e1 = min(e0 + epb, nE);
    for (int i = e0 + threadIdx.x; i < e1; i += 256)
        atomicAdd(&h[dst[i] >> 8], 1);
    __syncthreads();
    for (int i = threadIdx.x; i < nbk; i += 256)
        C[blockIdx.x * nbk + i] = h[i];
}

// pass 1b: exclusive scan down each bucket column (over the PB=256 blocks);
// emit per-bucket totals.
__global__ __launch_bounds__(256) void k_colscan(int* __restrict__ C,
                                                 int* __restrict__ tot, int nbk) {
    __shared__ int sm[256];
    int k = blockIdx.x, t = threadIdx.x;
    int v = C[t * nbk + k];
    sm[t] = v;
    __syncthreads();
    for (int o = 1; o < 256; o <<= 1) {
        int u = (t >= o) ? sm[t - o] : 0;
        __syncthreads();
        sm[t] += u;
        __syncthreads();
    }
    C[t * nbk + k] = sm[t] - v;
    if (t == 255) tot[k] = sm[255];
}

// small scan (n <= 1024, one block) for bucket starts
__global__ __launch_bounds__(256) void k_scan_a(const int* __restrict__ cnt,
                                                int* __restrict__ offs,
                                                int* __restrict__ bsum, int n) {
    __shared__ int sm[256];
    int t = threadIdx.x;
    int base = blockIdx.x * 1024 + t * 4;
    int v0 = 0, v1 = 0, v2 = 0, v3 = 0;
    if (base + 3 < n) {
        int4 q = *(const int4*)(cnt + base);
        v0 = q.x; v1 = q.y; v2 = q.z; v3 = q.w;
    } else {
        if (base < n)     v0 = cnt[base];
        if (base + 1 < n) v1 = cnt[base + 1];
        if (base + 2 < n) v2 = cnt[base + 2];
    }
    int s = v0 + v1 + v2 + v3;
    sm[t] = s;
    __syncthreads();
    for (int o = 1; o < 256; o <<= 1) {
        int u = (t >= o) ? sm[t - o] : 0;
        __syncthreads();
        sm[t] += u;
        __syncthreads();
    }
    int excl = sm[t] - s;
    if (base < n)     offs[base]     = excl;
    if (base + 1 < n) offs[base + 1] = excl + v0;
    if (base + 2 < n) offs[base + 2] = excl + v0 + v1;
    if (base + 3 < n) offs[base + 3] = excl + v0 + v1 + v2;
    if (t == 255) bsum[blockIdx.x] = sm[255];
}

__global__ __launch_bounds__(256) void k_scan_b(int* __restrict__ offs,
                                                const int* __restrict__ bsum,
                                                int n, int nb) {
    __shared__ int pfx;
    int t = threadIdx.x, b = blockIdx.x;
    if (t == 0) {
        int s = 0;
        for (int i = 0; i < b; ++i) s += bsum[i];
        pfx = s;
        if (b == nb - 1) offs[n] = s + bsum[b];
    }
    __syncthreads();
    if (b == 0) return;
    int base = b * 1024 + t * 4;
    int p = pfx;
    if (base < n)     offs[base]     += p;
    if (base + 1 < n) offs[base + 1] += p;
    if (base + 2 < n) offs[base + 2] += p;
    if (base + 3 < n) offs[base + 3] += p;
}

// pass 2: scatter packed (src<<8 | dst&255) into bucket-partitioned ebuf.
__global__ __launch_bounds__(256) void k_p1fill(const int* __restrict__ src,
                                                const int* __restrict__ dst,
                                                const int* __restrict__ bstart,
                                                const int* __restrict__ C,
                                                unsigned* __restrict__ ebuf,
                                                int nE, int nbk, int epb) {
    __shared__ int cur[512];
    int b = blockIdx.x;
    for (int i = threadIdx.x; i < nbk; i += 256)
        cur[i] = bstart[i] + C[b * nbk + i];
    __syncthreads();
    int e0 = b * epb;
    int e1 = min(e0 + epb, nE);
    for (int i = e0 + threadIdx.x; i < e1; i += 256) {
        int d = dst[i];
        unsigned s = (unsigned)src[i];
        int p = atomicAdd(&cur[d >> 8], 1);
        ebuf[p] = (s << 8) | (unsigned)(d & 255);
    }
}

// pass 3: one block per bucket; LDS hist gives offs[] and dense csr placement.
__global__ __launch_bounds__(256) void k_p2fill(const unsigned* __restrict__ ebuf,
                                                const int* __restrict__ bstart,
                                                int* __restrict__ offs,
                                                int* __restrict__ csr,
                                                int nN, int nE) {
    __shared__ int h[256], sm[256], cur[256];
    int k = blockIdx.x, t = threadIdx.x;
    int base = bstart[k], end = bstart[k + 1];
    h[t] = 0;
    __syncthreads();
    for (int i = base + t; i < end; i += 256)
        atomicAdd(&h[ebuf[i] & 255u], 1);
    __syncthreads();
    int v = h[t];
    sm[t] = v;
    __syncthreads();
    for (int o = 1; o < 256; o <<= 1) {
        int u = (t >= o) ? sm[t - o] : 0;
        __syncthreads();
        sm[t] += u;
        __syncthreads();
    }
    int excl = sm[t] - v;
    int node = (k << 8) + t;
    if (node < nN) offs[node] = base + excl;
    cur[t] = base + excl;
    if (k == 0 && t == 0) offs[nN] = nE;
    __syncthreads();
    for (int i = base + t; i < end; i += 256) {
        unsigned e = ebuf[i];
        int p = atomicAdd(&cur[e & 255u], 1);
        csr[p] = (int)(e >> 8);
    }
}

// ---- weight prep: Wt[n][k] = bf16( k<K1 ? W1[k][n] : W2[k-K1][n] ) ----------

__global__ __launch_bounds__(256) void k_wtcat(const float* __restrict__ W1,
                                               const float* __restrict__ W2,
                                               unsigned short* __restrict__ Wt,
                                               int K1, int K, int N) {
    int idx = blockIdx.x * 256 + threadIdx.x;
    if (idx >= N * K) return;
    int n = idx / K, k = idx % K;
    float v = (k < K1) ? W1[k * N + n] : W2[(k - K1) * N + n];
    Wt[idx] = f2bf(v);
}

// ---- aggregation -----------------------------------------------------------

__global__ __launch_bounds__(256) void k_agg0(const float* __restrict__ x,
                                              const int* __restrict__ offs,
                                              const int* __restrict__ csr,
                                              float* __restrict__ mean0, int nN) {
    int i = blockIdx.x * blockDim.x + threadIdx.x;
    if (i >= nN) return;
    int lo = offs[i], hi = offs[i + 1];
    float a0 = 0, a1 = 0, a2 = 0, a3 = 0, a4 = 0, a5 = 0;
    for (int e = lo; e < hi; ++e) {
        int s = csr[e];
        const float* r = x + (size_t)s * 10 + 4;
        float2 v0 = *(const float2*)(r);
        float2 v1 = *(const float2*)(r + 2);
        float2 v2 = *(const float2*)(r + 4);
        a0 += v0.x; a1 += v0.y; a2 += v1.x; a3 += v1.y; a4 += v2.x; a5 += v2.y;
    }
    float inv = 1.0f / (float)imax(hi - lo, 1);
    float* o = mean0 + (size_t)i * 6;
    o[0] = a0 * inv; o[1] = a1 * inv; o[2] = a2 * inv;
    o[3] = a3 * inv; o[4] = a4 * inv; o[5] = a5 * inv;
}

// 128-dim bf16 mean -> bf16: thread per (node, 16B chunk), 4x-unrolled edges.
// 16 threads/node; each thread privately sums its 8 features over all edges.
__global__ __launch_bounds__(256) void k_agg128(const unsigned short* __restrict__ X,
                                                const int* __restrict__ offs,
                                                const int* __restrict__ csr,
                                                unsigned short* __restrict__ M, int nN) {
    int idx = blockIdx.x * 256 + threadIdx.x;
    int node = idx >> 4;
    int fl = idx & 15;            // features fl*8 .. fl*8+7
    if (node >= nN) return;
    int lo = offs[node], hi = offs[node + 1];
    float a0 = 0, a1 = 0, a2 = 0, a3 = 0, a4 = 0, a5 = 0, a6 = 0, a7 = 0;
    int e = lo;
    for (; e + 4 <= hi; e += 4) {
        int s0 = csr[e], s1 = csr[e + 1], s2 = csr[e + 2], s3 = csr[e + 3];
        uint4 v0 = *(const uint4*)(X + (size_t)s0 * 128 + fl * 8);
        uint4 v1 = *(const uint4*)(X + (size_t)s1 * 128 + fl * 8);
        uint4 v2 = *(const uint4*)(X + (size_t)s2 * 128 + fl * 8);
        uint4 v3 = *(const uint4*)(X + (size_t)s3 * 128 + fl * 8);
        a0 += bfbits_lo(v0.x); a1 += bfbits_hi(v0.x);
        a2 += bfbits_lo(v0.y); a3 += bfbits_hi(v0.y);
        a4 += bfbits_lo(v0.z); a5 += bfbits_hi(v0.z);
        a6 += bfbits_lo(v0.w); a7 += bfbits_hi(v0.w);
        a0 += bfbits_lo(v1.x); a1 += bfbits_hi(v1.x);
        a2 += bfbits_lo(v1.y); a3 += bfbits_hi(v1.y);
        a4 += bfbits_lo(v1.z); a5 += bfbits_hi(v1.z);
        a6 += bfbits_lo(v1.w); a7 += bfbits_hi(v1.w);
        a0 += bfbits_lo(v2.x); a1 += bfbits_hi(v2.x);
        a2 += bfbits_lo(v2.y); a3 += bfbits_hi(v2.y);
        a4 += bfbits_lo(v2.z); a5 += bfbits_hi(v2.z);
        a6 += bfbits_lo(v2.w); a7 += bfbits_hi(v2.w);
        a0 += bfbits_lo(v3.x); a1 += bfbits_hi(v3.x);
        a2 += bfbits_lo(v3.y); a3 += bfbits_hi(v3.y);
        a4 += bfbits_lo(v3.z); a5 += bfbits_hi(v3.z);
        a6 += bfbits_lo(v3.w); a7 += bfbits_hi(v3.w);
    }
    for (; e < hi; ++e) {
        int s = csr[e];
        uint4 v = *(const uint4*)(X + (size_t)s * 128 + fl * 8);
        a0 += bfbits_lo(v.x); a1 += bfbits_hi(v.x);
        a2 += bfbits_lo(v.y); a3 += bfbits_hi(v.y);
        a4 += bfbits_lo(v.z); a5 += bfbits_hi(v.z);
        a6 += bfbits_lo(v.w); a7 += bfbits_hi(v.w);
    }
    float inv = 1.0f / (float)imax(hi - lo, 1);
    uint4 o;
    o.x = pack2bf(a0 * inv, a1 * inv);
    o.y = pack2bf(a2 * inv, a3 * inv);
    o.z = pack2bf(a4 * inv, a5 * inv);
    o.w = pack2bf(a6 * inv, a7 * inv);
    *(uint4*)(M + (size_t)node * 128 + fl * 8) = o;
}

// 64-dim bf16 mean -> fp32: thread per (node, 16B chunk), 4x-unrolled edges.
// 8 threads/node.
__global__ __launch_bounds__(256) void k_agg64(const unsigned short* __restrict__ X,
                                               const int* __restrict__ offs,
                                               const int* __restrict__ csr,
                                               float* __restrict__ M, int nN) {
    int idx = blockIdx.x * 256 + threadIdx.x;
    int node = idx >> 3;
    int fl = idx & 7;             // features fl*8 .. fl*8+7
    if (node >= nN) return;
    int lo = offs[node], hi = offs[node + 1];
    float a0 = 0, a1 = 0, a2 = 0, a3 = 0, a4 = 0, a5 = 0, a6 = 0, a7 = 0;
    int e = lo;
    for (; e + 4 <= hi; e += 4) {
        int s0 = csr[e], s1 = csr[e + 1], s2 = csr[e + 2], s3 = csr[e + 3];
        uint4 v0 = *(const uint4*)(X + (size_t)s0 * 64 + fl * 8);
        uint4 v1 = *(const uint4*)(X + (size_t)s1 * 64 + fl * 8);
        uint4 v2 = *(const uint4*)(X + (size_t)s2 * 64 + fl * 8);
        uint4 v3 = *(const uint4*)(X + (size_t)s3 * 64 + fl * 8);
        a0 += bfbits_lo(v0.x); a1 += bfbits_hi(v0.x);
        a2 += bfbits_lo(v0.y); a3 += bfbits_hi(v0.y);
        a4 += bfbits_lo(v0.z); a5 += bfbits_hi(v0.z);
        a6 += bfbits_lo(v0.w); a7 += bfbits_hi(v0.w);
        a0 += bfbits_lo(v1.x); a1 += bfbits_hi(v1.x);
        a2 += bfbits_lo(v1.y); a3 += bfbits_hi(v1.y);
        a4 += bfbits_lo(v1.z); a5 += bfbits_hi(v1.z);
        a6 += bfbits_lo(v1.w); a7 += bfbits_hi(v1.w);
        a0 += bfbits_lo(v2.x); a1 += bfbits_hi(v2.x);
        a2 += bfbits_lo(v2.y); a3 += bfbits_hi(v2.y);
        a4 += bfbits_lo(v2.z); a5 += bfbits_hi(v2.z);
        a6 += bfbits_lo(v2.w); a7 += bfbits_hi(v2.w);
        a0 += bfbits_lo(v3.x); a1 += bfbits_hi(v3.x);
        a2 += bfbits_lo(v3.y); a3 += bfbits_hi(v3.y);
        a4 += bfbits_lo(v3.z); a5 += bfbits_hi(v3.z);
        a6 += bfbits_lo(v3.w); a7 += bfbits_hi(v3.w);
    }
    for (; e < hi; ++e) {
        int s = csr[e];
        uint4 v = *(const uint4*)(X + (size_t)s * 64 + fl * 8);
        a0 += bfbits_lo(v.x); a1 += bfbits_hi(v.x);
        a2 += bfbits_lo(v.y); a3 += bfbits_hi(v.y);
        a4 += bfbits_lo(v.z); a5 += bfbits_hi(v.z);
        a6 += bfbits_lo(v.w); a7 += bfbits_hi(v.w);
    }
    float inv = 1.0f / (float)imax(hi - lo, 1);
    float* o = M + (size_t)node * 64 + fl * 8;
    *(float4*)(o)     = make_float4(a0 * inv, a1 * inv, a2 * inv, a3 * inv);
    *(float4*)(o + 4) = make_float4(a4 * inv, a5 * inv, a6 * inv, a7 * inv);
}

// ---- layer 0 (K=6): one thread per (node, out-feature) ----------------------

__global__ __launch_bounds__(256) void k_l0(const float* __restrict__ x,
                                            const float* __restrict__ mean0,
                                            const float* __restrict__ Wl,
                                            const float* __restrict__ bl,
                                            const float* __restrict__ Wr,
                                            unsigned short* __restrict__ out, int nN) {
    int j = threadIdx.x & 127;
    int node = blockIdx.x * 2 + (threadIdx.x >> 7);
    if (node >= nN) return;
    const float* m = mean0 + (size_t)node * 6;
    const float* h = x + (size_t)node * 10 + 4;
    float v = bl[j];
#pragma unroll
    for (int k = 0; k < 6; ++k) v = fmaf(m[k], Wl[k * 128 + j], v);
#pragma unroll
    for (int k = 0; k < 6; ++k) v = fmaf(h[k], Wr[k * 128 + j], v);
    out[(size_t)node * 128 + j] = f2bf(fmaxf(v, 0.f));
}

// ---- MFMA GEMM: C = act( [A0|A1] @ Wt^T (+bias) (+add) ) --------------------

template <int KA, int KB, int N, bool RELU, bool BF16OUT, bool HASBIAS, bool HASADD>
__global__ __launch_bounds__(256) void k_mfma(const unsigned short* __restrict__ A0,
                                              const unsigned short* __restrict__ A1,
                                              const unsigned short* __restrict__ Wt,
                                              const float* __restrict__ bias,
                                              const float* __restrict__ add,
                                              void* __restrict__ Cout, int nN) {
    constexpr int K = KA + KB;
    constexpr int NB = N / 16;
    const int tid = threadIdx.x;
    const int wave = (blockIdx.x * 256 + tid) >> 6;
    const int m0 = wave * 32;
    if (m0 >= nN) return;
    const int lane = tid & 63;
    const int lr = lane & 15;
    const int lk = lane >> 4;

    f32x4 acc[2][NB];
#pragma unroll
    for (int g = 0; g < 2; ++g)
#pragma unroll
        for (int n = 0; n < NB; ++n) acc[g][n] = (f32x4){0.f, 0.f, 0.f, 0.f};

#pragma unroll
    for (int kk = 0; kk < K; kk += 32) {
        const unsigned short* Ap;
        int lda, krel;
        if (KB > 0 && kk >= KA) { Ap = A1; lda = KB; krel = kk - KA; }
        else                    { Ap = A0; lda = KA; krel = kk; }
        bf16x8 a0 = *(const bf16x8*)(Ap + (size_t)(m0 + lr) * lda + krel + lk * 8);
        bf16x8 a1 = *(const bf16x8*)(Ap + (size_t)(m0 + 16 + lr) * lda + krel + lk * 8);
#pragma unroll
        for (int n = 0; n < NB; ++n) {
            bf16x8 b = *(const bf16x8*)(Wt + (size_t)(n * 16 + lr) * K + kk + lk * 8);
            acc[0][n] = __builtin_amdgcn_mfma_f32_16x16x32_bf16(a0, b, acc[0][n], 0, 0, 0);
            acc[1][n] = __builtin_amdgcn_mfma_f32_16x16x32_bf16(a1, b, acc[1][n], 0, 0, 0);
        }
    }

#pragma unroll
    for (int g = 0; g < 2; ++g) {
#pragma unroll
        for (int r = 0; r < 4; ++r) {
            int gm = m0 + g * 16 + lk * 4 + r;
#pragma unroll
            for (int n = 0; n < NB; ++n) {
                float v = acc[g][n][r];
                if (HASBIAS) v += bias[n * 16 + lr];
                if (HASADD)  v += add[(size_t)gm * N + n * 16 + lr];
                if (RELU)    v = fmaxf(v, 0.f);
                if (BF16OUT) ((unsigned short*)Cout)[(size_t)gm * N + n * 16 + lr] = f2bf(v);
                else         ((float*)Cout)[(size_t)gm * N + n * 16 + lr] = v;
            }
        }
    }
}

// ---------------------------------------------------------------------------

extern "C" void kernel_launch(void* const* d_in, const int* in_sizes, int n_in,
                              void* d_out, int out_size, void* d_ws, size_t ws_size,
                              hipStream_t stream) {
    const float* x   = (const float*)d_in[0];
    const int*   ei  = (const int*)d_in[1];
    const float* Wl0 = (const float*)d_in[2];
    const float* bl0 = (const float*)d_in[3];
    const float* Wr0 = (const float*)d_in[4];
    const float* Wl1 = (const float*)d_in[5];
    const float* bl1 = (const float*)d_in[6];
    const float* Wr1 = (const float*)d_in[7];
    const float* Wl2 = (const float*)d_in[8];
    const float* bl2 = (const float*)d_in[9];
    const float* Wr2 = (const float*)d_in[10];

    const int nN = in_sizes[0] / 10;
    const int nE = in_sizes[1] / 2;
    const int* src = ei;
    const int* dst = ei + nE;
    const int nbk = (nN + 255) >> 8;            // 391 buckets (<=512 for LDS)
    const int epb = (nE + PB - 1) / PB;         // edges per partition block

    char* ws = (char*)d_ws;
    size_t off = 0;
    auto alloc = [&](size_t bytes) -> char* {
        char* p = ws + off;
        off = (off + bytes + 255) & ~(size_t)255;
        return p;
    };
    unsigned short* out0  = (unsigned short*)alloc((size_t)nN * 128 * 2); // reused as z2
    unsigned short* mean1 = (unsigned short*)alloc((size_t)nN * 128 * 2); // reused as meanz2 (fp32 x64)
    unsigned short* out1  = (unsigned short*)alloc((size_t)nN * 128 * 2);
    float* mean0 = (float*)alloc((size_t)nN * 6 * 4);
    unsigned short* Wt1  = (unsigned short*)alloc((size_t)128 * 256 * 2);
    unsigned short* Wt2l = (unsigned short*)alloc((size_t)64 * 128 * 2);
    unsigned short* Wt2r = (unsigned short*)alloc((size_t)64 * 128 * 2);
    int* C      = (int*)alloc((size_t)PB * nbk * 4);
    int* tot    = (int*)alloc((size_t)nbk * 4);
    int* bstart = (int*)alloc(((size_t)nbk + 1) * 4);
    int* bsum   = (int*)alloc(4 * 4);
    int* offs   = (int*)alloc(((size_t)nN + 1) * 4);
    int* csr    = (int*)alloc((size_t)nE * 4);
    unsigned* ebuf = (unsigned*)alloc((size_t)nE * 4);

    unsigned short* z2     = out0;            // out0 dead after layer-1 GEMM
    float*          meanz2 = (float*)mean1;   // mean1 dead after layer-1 GEMM

    // weight prep (independent of graph build)
    k_wtcat<<<(128 * 256 + 255) / 256, 256, 0, stream>>>(Wl1, Wr1, Wt1, 128, 256, 128);
    k_wtcat<<<(64 * 128 + 255) / 256, 256, 0, stream>>>(Wl2, Wl2, Wt2l, 128, 128, 64);
    k_wtcat<<<(64 * 128 + 255) / 256, 256, 0, stream>>>(Wr2, Wr2, Wt2r, 128, 128, 64);

    // build dst-sorted CSR via bucket partition (no global atomics, dense writes)
    k_p1count<<<PB, 256, 0, stream>>>(dst, C, nE, nbk, epb);
    k_colscan<<<nbk, 256, 0, stream>>>(C, tot, nbk);
    k_scan_a<<<1, 256, 0, stream>>>(tot, bstart, bsum, nbk);
    k_scan_b<<<1, 256, 0, stream>>>(bstart, bsum, nbk, 1);
    k_p1fill<<<PB, 256, 0, stream>>>(src, dst, bstart, C, ebuf, nE, nbk, epb);
    k_p2fill<<<nbk, 256, 0, stream>>>(ebuf, bstart, offs, csr, nN, nE);

    // layer 0 (K=6) -> out0 (bf16)
    k_agg0<<<(nN + 255) / 256, 256, 0, stream>>>(x, offs, csr, mean0, nN);
    k_l0<<<(nN + 1) / 2, 256, 0, stream>>>(x, mean0, Wl0, bl0, Wr0, out0, nN);

    const int gemm_grid = (nN / 32 + 3) / 4 + 1;   // 4 waves/block, 32 rows/wave

    // layer 1: mean1 = agg(out0); out1 = relu([mean1|out0] @ Wt1^T + bl1)
    k_agg128<<<((size_t)nN * 16 + 255) / 256, 256, 0, stream>>>(out0, offs, csr, mean1, nN);
    k_mfma<128, 128, 128, true, true, true, false><<<gemm_grid, 256, 0, stream>>>(
        mean1, out0, Wt1, bl1, nullptr, out1, nN);

    // layer 2 (reordered): z2 = out1@Wl2 (bf16); out = relu(out1@Wr2 + bl2 + agg(z2))
    k_mfma<128, 0, 64, false, true, false, false><<<gemm_grid, 256, 0, stream>>>(
        out1, nullptr, Wt2l, nullptr, nullptr, z2, nN);
    k_agg64<<<((size_t)nN * 8 + 255) / 256, 256, 0, stream>>>(z2, offs, csr, meanz2, nN);
    k_mfma<128, 0, 64, true, false, true, true><<<gemm_grid, 256, 0, stream>>>(
        out1, nullptr, Wt2r, bl2, meanz2, (float*)d_out, nN);
}

// Round 6
// 296.601 us; speedup vs baseline: 3.0239x; 1.0638x over previous
//
#include <hip/hip_runtime.h>

// ---------------------------------------------------------------------------
// GraphSAGE 3-layer forward.
//   h = x[:,4:10]; per layer: mean_agg(h) @ Wl + bl + h @ Wr, relu
// Round-6 changes:
//   - weights pre-packed in FRAGMENT-LINEAR order (k_wtfrag): the bf16x8 that
//     lane L of a wave consumes for (k-step ks, col-block n) sits at
//     ((ks*NB+n)*64+L)*8. B-loads become base+lane*16 => one coalesced 1KiB
//     request/instruction instead of 16 scattered 512B-apart lines.
//     (was: layer-1 k_mfma 60us @ MfmaUtil 3.8%, occupancy 20% -- latency-
//     bound on scattered B gathers at L2 latency)
// ---------------------------------------------------------------------------

typedef __attribute__((ext_vector_type(8))) short bf16x8;   // 8 bf16 = 4 VGPR
typedef __attribute__((ext_vector_type(4))) float f32x4;

constexpr int PB = 256;   // partition pass blocks (== colscan threads, fixed)

static __device__ __forceinline__ int imax(int a, int b) { return a > b ? a : b; }

static __device__ __forceinline__ float bfbits_lo(unsigned u) {
    union { unsigned i; float f; } v; v.i = u << 16; return v.f;
}
static __device__ __forceinline__ float bfbits_hi(unsigned u) {
    union { unsigned i; float f; } v; v.i = u & 0xffff0000u; return v.f;
}
static __device__ __forceinline__ unsigned short f2bf(float f) {
    unsigned u = __float_as_uint(f);
    u = (u + 0x7fffu + ((u >> 16) & 1u)) >> 16;
    return (unsigned short)u;
}
static __device__ __forceinline__ unsigned pack2bf(float a, float b) {
    return (unsigned)f2bf(a) | ((unsigned)f2bf(b) << 16);
}

// ---- graph build: bucket partition + per-bucket counting sort ---------------

__global__ __launch_bounds__(256) void k_p1count(const int* __restrict__ dst,
                                                 int* __restrict__ C,
                                                 int nE, int nbk, int epb) {
    __shared__ int h[512];
    for (int i = threadIdx.x; i < nbk; i += 256) h[i] = 0;
    __syncthreads();
    int e0 = blockIdx.x * epb;
    int e1 = min(e0 + epb, nE);
    for (int i = e0 + threadIdx.x; i < e1; i += 256)
        atomicAdd(&h[dst[i] >> 8], 1);
    __syncthreads();
    for (int i = threadIdx.x; i < nbk; i += 256)
        C[blockIdx.x * nbk + i] = h[i];
}

__global__ __launch_bounds__(256) void k_colscan(int* __restrict__ C,
                                                 int* __restrict__ tot, int nbk) {
    __shared__ int sm[256];
    int k = blockIdx.x, t = threadIdx.x;
    int v = C[t * nbk + k];
    sm[t] = v;
    __syncthreads();
    for (int o = 1; o < 256; o <<= 1) {
        int u = (t >= o) ? sm[t - o] : 0;
        __syncthreads();
        sm[t] += u;
        __syncthreads();
    }
    C[t * nbk + k] = sm[t] - v;
    if (t == 255) tot[k] = sm[255];
}

__global__ __launch_bounds__(256) void k_scan_a(const int* __restrict__ cnt,
                                                int* __restrict__ offs,
                                                int* __restrict__ bsum, int n) {
    __shared__ int sm[256];
    int t = threadIdx.x;
    int base = blockIdx.x * 1024 + t * 4;
    int v0 = 0, v1 = 0, v2 = 0, v3 = 0;
    if (base + 3 < n) {
        int4 q = *(const int4*)(cnt + base);
        v0 = q.x; v1 = q.y; v2 = q.z; v3 = q.w;
    } else {
        if (base < n)     v0 = cnt[base];
        if (base + 1 < n) v1 = cnt[base + 1];
        if (base + 2 < n) v2 = cnt[base + 2];
    }
    int s = v0 + v1 + v2 + v3;
    sm[t] = s;
    __syncthreads();
    for (int o = 1; o < 256; o <<= 1) {
        int u = (t >= o) ? sm[t - o] : 0;
        __syncthreads();
        sm[t] += u;
        __syncthreads();
    }
    int excl = sm[t] - s;
    if (base < n)     offs[base]     = excl;
    if (base + 1 < n) offs[base + 1] = excl + v0;
    if (base + 2 < n) offs[base + 2] = excl + v0 + v1;
    if (base + 3 < n) offs[base + 3] = excl + v0 + v1 + v2;
    if (t == 255) bsum[blockIdx.x] = sm[255];
}

__global__ __launch_bounds__(256) void k_scan_b(int* __restrict__ offs,
                                                const int* __restrict__ bsum,
                                                int n, int nb) {
    __shared__ int pfx;
    int t = threadIdx.x, b = blockIdx.x;
    if (t == 0) {
        int s = 0;
        for (int i = 0; i < b; ++i) s += bsum[i];
        pfx = s;
        if (b == nb - 1) offs[n] = s + bsum[b];
    }
    __syncthreads();
    if (b == 0) return;
    int base = b * 1024 + t * 4;
    int p = pfx;
    if (base < n)     offs[base]     += p;
    if (base + 1 < n) offs[base + 1] += p;
    if (base + 2 < n) offs[base + 2] += p;
    if (base + 3 < n) offs[base + 3] += p;
}

__global__ __launch_bounds__(256) void k_p1fill(const int* __restrict__ src,
                                                const int* __restrict__ dst,
                                                const int* __restrict__ bstart,
                                                const int* __restrict__ C,
                                                unsigned* __restrict__ ebuf,
                                                int nE, int nbk, int epb) {
    __shared__ int cur[512];
    int b = blockIdx.x;
    for (int i = threadIdx.x; i < nbk; i += 256)
        cur[i] = bstart[i] + C[b * nbk + i];
    __syncthreads();
    int e0 = b * epb;
    int e1 = min(e0 + epb, nE);
    for (int i = e0 + threadIdx.x; i < e1; i += 256) {
        int d = dst[i];
        unsigned s = (unsigned)src[i];
        int p = atomicAdd(&cur[d >> 8], 1);
        ebuf[p] = (s << 8) | (unsigned)(d & 255);
    }
}

__global__ __launch_bounds__(256) void k_p2fill(const unsigned* __restrict__ ebuf,
                                                const int* __restrict__ bstart,
                                                int* __restrict__ offs,
                                                int* __restrict__ csr,
                                                int nN, int nE) {
    __shared__ int h[256], sm[256], cur[256];
    int k = blockIdx.x, t = threadIdx.x;
    int base = bstart[k], end = bstart[k + 1];
    h[t] = 0;
    __syncthreads();
    for (int i = base + t; i < end; i += 256)
        atomicAdd(&h[ebuf[i] & 255u], 1);
    __syncthreads();
    int v = h[t];
    sm[t] = v;
    __syncthreads();
    for (int o = 1; o < 256; o <<= 1) {
        int u = (t >= o) ? sm[t - o] : 0;
        __syncthreads();
        sm[t] += u;
        __syncthreads();
    }
    int excl = sm[t] - v;
    int node = (k << 8) + t;
    if (node < nN) offs[node] = base + excl;
    cur[t] = base + excl;
    if (k == 0 && t == 0) offs[nN] = nE;
    __syncthreads();
    for (int i = base + t; i < end; i += 256) {
        unsigned e = ebuf[i];
        int p = atomicAdd(&cur[e & 255u], 1);
        csr[p] = (int)(e >> 8);
    }
}

// ---- weight prep: fragment-linear packing -----------------------------------
// Chunk c = ((ks*NB + n)*64 + lane); contents = bf16 W[k..k+7][row] where
// row = n*16 + (lane&15), k = ks*32 + (lane>>4)*8. Wave reads chunk at
// base + lane*16B -> fully coalesced. Logical W = [W1; W2] (K1 + K2 rows).
__global__ __launch_bounds__(256) void k_wtfrag(const float* __restrict__ W1,
                                                const float* __restrict__ W2,
                                                unsigned short* __restrict__ Wt,
                                                int K1, int K, int N) {
    int c = blockIdx.x * 256 + threadIdx.x;
    int NB = N >> 4;
    int nch = (N * K) >> 3;
    if (c >= nch) return;
    int lane = c & 63;
    int n = (c >> 6) % NB;
    int ks = c / (NB << 6);
    int row = n * 16 + (lane & 15);
    int col = ks * 32 + (lane >> 4) * 8;
    unsigned short o[8];
#pragma unroll
    for (int j = 0; j < 8; ++j) {
        int k = col + j;
        float v = (k < K1) ? W1[k * N + row] : W2[(k - K1) * N + row];
        o[j] = f2bf(v);
    }
    *(uint4*)(Wt + (size_t)c * 8) = *(const uint4*)o;
}

// ---- aggregation -----------------------------------------------------------

__global__ __launch_bounds__(256) void k_agg0(const float* __restrict__ x,
                                              const int* __restrict__ offs,
                                              const int* __restrict__ csr,
                                              float* __restrict__ mean0, int nN) {
    int i = blockIdx.x * blockDim.x + threadIdx.x;
    if (i >= nN) return;
    int lo = offs[i], hi = offs[i + 1];
    float a0 = 0, a1 = 0, a2 = 0, a3 = 0, a4 = 0, a5 = 0;
    for (int e = lo; e < hi; ++e) {
        int s = csr[e];
        const float* r = x + (size_t)s * 10 + 4;
        float2 v0 = *(const float2*)(r);
        float2 v1 = *(const float2*)(r + 2);
        float2 v2 = *(const float2*)(r + 4);
        a0 += v0.x; a1 += v0.y; a2 += v1.x; a3 += v1.y; a4 += v2.x; a5 += v2.y;
    }
    float inv = 1.0f / (float)imax(hi - lo, 1);
    float* o = mean0 + (size_t)i * 6;
    o[0] = a0 * inv; o[1] = a1 * inv; o[2] = a2 * inv;
    o[3] = a3 * inv; o[4] = a4 * inv; o[5] = a5 * inv;
}

// 128-dim bf16 mean -> bf16: thread per (node, 16B chunk), 4x-unrolled edges.
__global__ __launch_bounds__(256) void k_agg128(const unsigned short* __restrict__ X,
                                                const int* __restrict__ offs,
                                                const int* __restrict__ csr,
                                                unsigned short* __restrict__ M, int nN) {
    int idx = blockIdx.x * 256 + threadIdx.x;
    int node = idx >> 4;
    int fl = idx & 15;            // features fl*8 .. fl*8+7
    if (node >= nN) return;
    int lo = offs[node], hi = offs[node + 1];
    float a0 = 0, a1 = 0, a2 = 0, a3 = 0, a4 = 0, a5 = 0, a6 = 0, a7 = 0;
    int e = lo;
    for (; e + 4 <= hi; e += 4) {
        int s0 = csr[e], s1 = csr[e + 1], s2 = csr[e + 2], s3 = csr[e + 3];
        uint4 v0 = *(const uint4*)(X + (size_t)s0 * 128 + fl * 8);
        uint4 v1 = *(const uint4*)(X + (size_t)s1 * 128 + fl * 8);
        uint4 v2 = *(const uint4*)(X + (size_t)s2 * 128 + fl * 8);
        uint4 v3 = *(const uint4*)(X + (size_t)s3 * 128 + fl * 8);
        a0 += bfbits_lo(v0.x); a1 += bfbits_hi(v0.x);
        a2 += bfbits_lo(v0.y); a3 += bfbits_hi(v0.y);
        a4 += bfbits_lo(v0.z); a5 += bfbits_hi(v0.z);
        a6 += bfbits_lo(v0.w); a7 += bfbits_hi(v0.w);
        a0 += bfbits_lo(v1.x); a1 += bfbits_hi(v1.x);
        a2 += bfbits_lo(v1.y); a3 += bfbits_hi(v1.y);
        a4 += bfbits_lo(v1.z); a5 += bfbits_hi(v1.z);
        a6 += bfbits_lo(v1.w); a7 += bfbits_hi(v1.w);
        a0 += bfbits_lo(v2.x); a1 += bfbits_hi(v2.x);
        a2 += bfbits_lo(v2.y); a3 += bfbits_hi(v2.y);
        a4 += bfbits_lo(v2.z); a5 += bfbits_hi(v2.z);
        a6 += bfbits_lo(v2.w); a7 += bfbits_hi(v2.w);
        a0 += bfbits_lo(v3.x); a1 += bfbits_hi(v3.x);
        a2 += bfbits_lo(v3.y); a3 += bfbits_hi(v3.y);
        a4 += bfbits_lo(v3.z); a5 += bfbits_hi(v3.z);
        a6 += bfbits_lo(v3.w); a7 += bfbits_hi(v3.w);
    }
    for (; e < hi; ++e) {
        int s = csr[e];
        uint4 v = *(const uint4*)(X + (size_t)s * 128 + fl * 8);
        a0 += bfbits_lo(v.x); a1 += bfbits_hi(v.x);
        a2 += bfbits_lo(v.y); a3 += bfbits_hi(v.y);
        a4 += bfbits_lo(v.z); a5 += bfbits_hi(v.z);
        a6 += bfbits_lo(v.w); a7 += bfbits_hi(v.w);
    }
    float inv = 1.0f / (float)imax(hi - lo, 1);
    uint4 o;
    o.x = pack2bf(a0 * inv, a1 * inv);
    o.y = pack2bf(a2 * inv, a3 * inv);
    o.z = pack2bf(a4 * inv, a5 * inv);
    o.w = pack2bf(a6 * inv, a7 * inv);
    *(uint4*)(M + (size_t)node * 128 + fl * 8) = o;
}

// 64-dim bf16 mean -> fp32: thread per (node, 16B chunk), 4x-unrolled edges.
__global__ __launch_bounds__(256) void k_agg64(const unsigned short* __restrict__ X,
                                               const int* __restrict__ offs,
                                               const int* __restrict__ csr,
                                               float* __restrict__ M, int nN) {
    int idx = blockIdx.x * 256 + threadIdx.x;
    int node = idx >> 3;
    int fl = idx & 7;             // features fl*8 .. fl*8+7
    if (node >= nN) return;
    int lo = offs[node], hi = offs[node + 1];
    float a0 = 0, a1 = 0, a2 = 0, a3 = 0, a4 = 0, a5 = 0, a6 = 0, a7 = 0;
    int e = lo;
    for (; e + 4 <= hi; e += 4) {
        int s0 = csr[e], s1 = csr[e + 1], s2 = csr[e + 2], s3 = csr[e + 3];
        uint4 v0 = *(const uint4*)(X + (size_t)s0 * 64 + fl * 8);
        uint4 v1 = *(const uint4*)(X + (size_t)s1 * 64 + fl * 8);
        uint4 v2 = *(const uint4*)(X + (size_t)s2 * 64 + fl * 8);
        uint4 v3 = *(const uint4*)(X + (size_t)s3 * 64 + fl * 8);
        a0 += bfbits_lo(v0.x); a1 += bfbits_hi(v0.x);
        a2 += bfbits_lo(v0.y); a3 += bfbits_hi(v0.y);
        a4 += bfbits_lo(v0.z); a5 += bfbits_hi(v0.z);
        a6 += bfbits_lo(v0.w); a7 += bfbits_hi(v0.w);
        a0 += bfbits_lo(v1.x); a1 += bfbits_hi(v1.x);
        a2 += bfbits_lo(v1.y); a3 += bfbits_hi(v1.y);
        a4 += bfbits_lo(v1.z); a5 += bfbits_hi(v1.z);
        a6 += bfbits_lo(v1.w); a7 += bfbits_hi(v1.w);
        a0 += bfbits_lo(v2.x); a1 += bfbits_hi(v2.x);
        a2 += bfbits_lo(v2.y); a3 += bfbits_hi(v2.y);
        a4 += bfbits_lo(v2.z); a5 += bfbits_hi(v2.z);
        a6 += bfbits_lo(v2.w); a7 += bfbits_hi(v2.w);
        a0 += bfbits_lo(v3.x); a1 += bfbits_hi(v3.x);
        a2 += bfbits_lo(v3.y); a3 += bfbits_hi(v3.y);
        a4 += bfbits_lo(v3.z); a5 += bfbits_hi(v3.z);
        a6 += bfbits_lo(v3.w); a7 += bfbits_hi(v3.w);
    }
    for (; e < hi; ++e) {
        int s = csr[e];
        uint4 v = *(const uint4*)(X + (size_t)s * 64 + fl * 8);
        a0 += bfbits_lo(v.x); a1 += bfbits_hi(v.x);
        a2 += bfbits_lo(v.y); a3 += bfbits_hi(v.y);
        a4 += bfbits_lo(v.z); a5 += bfbits_hi(v.z);
        a6 += bfbits_lo(v.w); a7 += bfbits_hi(v.w);
    }
    float inv = 1.0f / (float)imax(hi - lo, 1);
    float* o = M + (size_t)node * 64 + fl * 8;
    *(float4*)(o)     = make_float4(a0 * inv, a1 * inv, a2 * inv, a3 * inv);
    *(float4*)(o + 4) = make_float4(a4 * inv, a5 * inv, a6 * inv, a7 * inv);
}

// ---- layer 0 (K=6): one thread per (node, out-feature) ----------------------

__global__ __launch_bounds__(256) void k_l0(const float* __restrict__ x,
                                            const float* __restrict__ mean0,
                                            const float* __restrict__ Wl,
                                            const float* __restrict__ bl,
                                            const float* __restrict__ Wr,
                                            unsigned short* __restrict__ out, int nN) {
    int j = threadIdx.x & 127;
    int node = blockIdx.x * 2 + (threadIdx.x >> 7);
    if (node >= nN) return;
    const float* m = mean0 + (size_t)node * 6;
    const float* h = x + (size_t)node * 10 + 4;
    float v = bl[j];
#pragma unroll
    for (int k = 0; k < 6; ++k) v = fmaf(m[k], Wl[k * 128 + j], v);
#pragma unroll
    for (int k = 0; k < 6; ++k) v = fmaf(h[k], Wr[k * 128 + j], v);
    out[(size_t)node * 128 + j] = f2bf(fmaxf(v, 0.f));
}

// ---- MFMA GEMM: C = act( [A0|A1] @ W^T (+bias) (+add) ) ---------------------
// Wt is fragment-linear (see k_wtfrag): B-load = base + lane*16B, coalesced.

template <int KA, int KB, int N, bool RELU, bool BF16OUT, bool HASBIAS, bool HASADD>
__global__ __launch_bounds__(256) void k_mfma(const unsigned short* __restrict__ A0,
                                              const unsigned short* __restrict__ A1,
                                              const unsigned short* __restrict__ Wt,
                                              const float* __restrict__ bias,
                                              const float* __restrict__ add,
                                              void* __restrict__ Cout, int nN) {
    constexpr int K = KA + KB;
    constexpr int NB = N / 16;
    const int tid = threadIdx.x;
    const int wave = (blockIdx.x * 256 + tid) >> 6;
    const int m0 = wave * 32;
    if (m0 >= nN) return;
    const int lane = tid & 63;
    const int lr = lane & 15;
    const int lk = lane >> 4;

    f32x4 acc[2][NB];
#pragma unroll
    for (int g = 0; g < 2; ++g)
#pragma unroll
        for (int n = 0; n < NB; ++n) acc[g][n] = (f32x4){0.f, 0.f, 0.f, 0.f};

#pragma unroll
    for (int kk = 0; kk < K; kk += 32) {
        const unsigned short* Ap;
        int lda, krel;
        if (KB > 0 && kk >= KA) { Ap = A1; lda = KB; krel = kk - KA; }
        else                    { Ap = A0; lda = KA; krel = kk; }
        bf16x8 a0 = *(const bf16x8*)(Ap + (size_t)(m0 + lr) * lda + krel + lk * 8);
        bf16x8 a1 = *(const bf16x8*)(Ap + (size_t)(m0 + 16 + lr) * lda + krel + lk * 8);
        const unsigned short* Wk = Wt + (((size_t)(kk >> 5) * NB) << 6) * 8 + lane * 8;
#pragma unroll
        for (int n = 0; n < NB; ++n) {
            bf16x8 b = *(const bf16x8*)(Wk + ((size_t)n << 6) * 8);
            acc[0][n] = __builtin_amdgcn_mfma_f32_16x16x32_bf16(a0, b, acc[0][n], 0, 0, 0);
            acc[1][n] = __builtin_amdgcn_mfma_f32_16x16x32_bf16(a1, b, acc[1][n], 0, 0, 0);
        }
    }

#pragma unroll
    for (int g = 0; g < 2; ++g) {
#pragma unroll
        for (int r = 0; r < 4; ++r) {
            int gm = m0 + g * 16 + lk * 4 + r;
#pragma unroll
            for (int n = 0; n < NB; ++n) {
                float v = acc[g][n][r];
                if (HASBIAS) v += bias[n * 16 + lr];
                if (HASADD)  v += add[(size_t)gm * N + n * 16 + lr];
                if (RELU)    v = fmaxf(v, 0.f);
                if (BF16OUT) ((unsigned short*)Cout)[(size_t)gm * N + n * 16 + lr] = f2bf(v);
                else         ((float*)Cout)[(size_t)gm * N + n * 16 + lr] = v;
            }
        }
    }
}

// ---------------------------------------------------------------------------

extern "C" void kernel_launch(void* const* d_in, const int* in_sizes, int n_in,
                              void* d_out, int out_size, void* d_ws, size_t ws_size,
                              hipStream_t stream) {
    const float* x   = (const float*)d_in[0];
    const int*   ei  = (const int*)d_in[1];
    const float* Wl0 = (const float*)d_in[2];
    const float* bl0 = (const float*)d_in[3];
    const float* Wr0 = (const float*)d_in[4];
    const float* Wl1 = (const float*)d_in[5];
    const float* bl1 = (const float*)d_in[6];
    const float* Wr1 = (const float*)d_in[7];
    const float* Wl2 = (const float*)d_in[8];
    const float* bl2 = (const float*)d_in[9];
    const float* Wr2 = (const float*)d_in[10];

    const int nN = in_sizes[0] / 10;
    const int nE = in_sizes[1] / 2;
    const int* src = ei;
    const int* dst = ei + nE;
    const int nbk = (nN + 255) >> 8;            // 391 buckets (<=512 for LDS)
    const int epb = (nE + PB - 1) / PB;         // edges per partition block

    char* ws = (char*)d_ws;
    size_t off = 0;
    auto alloc = [&](size_t bytes) -> char* {
        char* p = ws + off;
        off = (off + bytes + 255) & ~(size_t)255;
        return p;
    };
    unsigned short* out0  = (unsigned short*)alloc((size_t)nN * 128 * 2); // reused as z2
    unsigned short* mean1 = (unsigned short*)alloc((size_t)nN * 128 * 2); // reused as meanz2 (fp32 x64)
    unsigned short* out1  = (unsigned short*)alloc((size_t)nN * 128 * 2);
    float* mean0 = (float*)alloc((size_t)nN * 6 * 4);
    unsigned short* Wt1  = (unsigned short*)alloc((size_t)128 * 256 * 2);
    unsigned short* Wt2l = (unsigned short*)alloc((size_t)64 * 128 * 2);
    unsigned short* Wt2r = (unsigned short*)alloc((size_t)64 * 128 * 2);
    int* C      = (int*)alloc((size_t)PB * nbk * 4);
    int* tot    = (int*)alloc((size_t)nbk * 4);
    int* bstart = (int*)alloc(((size_t)nbk + 1) * 4);
    int* bsum   = (int*)alloc(4 * 4);
    int* offs   = (int*)alloc(((size_t)nN + 1) * 4);
    int* csr    = (int*)alloc((size_t)nE * 4);
    unsigned* ebuf = (unsigned*)alloc((size_t)nE * 4);

    unsigned short* z2     = out0;            // out0 dead after layer-1 GEMM
    float*          meanz2 = (float*)mean1;   // mean1 dead after layer-1 GEMM

    // weight prep: fragment-linear packing (independent of graph build)
    k_wtfrag<<<(128 * 256 / 8 + 255) / 256, 256, 0, stream>>>(Wl1, Wr1, Wt1, 128, 256, 128);
    k_wtfrag<<<(64 * 128 / 8 + 255) / 256, 256, 0, stream>>>(Wl2, Wl2, Wt2l, 128, 128, 64);
    k_wtfrag<<<(64 * 128 / 8 + 255) / 256, 256, 0, stream>>>(Wr2, Wr2, Wt2r, 128, 128, 64);

    // build dst-sorted CSR via bucket partition (no global atomics, dense writes)
    k_p1count<<<PB, 256, 0, stream>>>(dst, C, nE, nbk, epb);
    k_colscan<<<nbk, 256, 0, stream>>>(C, tot, nbk);
    k_scan_a<<<1, 256, 0, stream>>>(tot, bstart, bsum, nbk);
    k_scan_b<<<1, 256, 0, stream>>>(bstart, bsum, nbk, 1);
    k_p1fill<<<PB, 256, 0, stream>>>(src, dst, bstart, C, ebuf, nE, nbk, epb);
    k_p2fill<<<nbk, 256, 0, stream>>>(ebuf, bstart, offs, csr, nN, nE);

    // layer 0 (K=6) -> out0 (bf16)
    k_agg0<<<(nN + 255) / 256, 256, 0, stream>>>(x, offs, csr, mean0, nN);
    k_l0<<<(nN + 1) / 2, 256, 0, stream>>>(x, mean0, Wl0, bl0, Wr0, out0, nN);

    const int gemm_grid = (nN / 32 + 3) / 4 + 1;   // 4 waves/block, 32 rows/wave

    // layer 1: mean1 = agg(out0); out1 = relu([mean1|out0] @ W1 + bl1)
    k_agg128<<<((size_t)nN * 16 + 255) / 256, 256, 0, stream>>>(out0, offs, csr, mean1, nN);
    k_mfma<128, 128, 128, true, true, true, false><<<gemm_grid, 256, 0, stream>>>(
        mean1, out0, Wt1, bl1, nullptr, out1, nN);

    // layer 2 (reordered): z2 = out1@Wl2 (bf16); out = relu(out1@Wr2 + bl2 + agg(z2))
    k_mfma<128, 0, 64, false, true, false, false><<<gemm_grid, 256, 0, stream>>>(
        out1, nullptr, Wt2l, nullptr, nullptr, z2, nN);
    k_agg64<<<((size_t)nN * 8 + 255) / 256, 256, 0, stream>>>(z2, offs, csr, meanz2, nN);
    k_mfma<128, 0, 64, true, false, true, true><<<gemm_grid, 256, 0, stream>>>(
        out1, nullptr, Wt2r, bl2, meanz2, (float*)d_out, nN);
}

// Round 7
// 271.042 us; speedup vs baseline: 3.3091x; 1.0943x over previous
//
#include <hip/hip_runtime.h>

// ---------------------------------------------------------------------------
// GraphSAGE 3-layer forward.
//   h = x[:,4:10]; per layer: mean_agg(h) @ Wl + bl + h @ Wr, relu
// Round-7 changes:
//   - layer-1 gather table stored as OCP fp8-e4m3 (scaled x32): row 256->128B,
//     gather volume 410->205 MB, loads/edge halved. bf16 copy kept for the
//     GEMM A-operand. HW packed cvt (v_cvt_pk_f32_fp8) decode.
//     (was: k_agg128 58us @ FETCH 178MB, 3.6 TB/s beyond-L2)
//   - k_agg0 4x-unrolled edge loop (12 independent loads in flight).
// ---------------------------------------------------------------------------

typedef __attribute__((ext_vector_type(8))) short bf16x8;   // 8 bf16 = 4 VGPR
typedef __attribute__((ext_vector_type(4))) float f32x4;
typedef __attribute__((ext_vector_type(2))) float f32x2;

constexpr int PB = 256;   // partition pass blocks (== colscan threads, fixed)
constexpr float F8SCALE = 32.0f;

static __device__ __forceinline__ int imax(int a, int b) { return a > b ? a : b; }

static __device__ __forceinline__ float bfbits_lo(unsigned u) {
    union { unsigned i; float f; } v; v.i = u << 16; return v.f;
}
static __device__ __forceinline__ float bfbits_hi(unsigned u) {
    union { unsigned i; float f; } v; v.i = u & 0xffff0000u; return v.f;
}
static __device__ __forceinline__ unsigned short f2bf(float f) {
    unsigned u = __float_as_uint(f);
    u = (u + 0x7fffu + ((u >> 16) & 1u)) >> 16;
    return (unsigned short)u;
}
static __device__ __forceinline__ unsigned pack2bf(float a, float b) {
    return (unsigned)f2bf(a) | ((unsigned)f2bf(b) << 16);
}
// accumulate 4 fp8-e4m3 bytes (one dword) into a[0..3]
static __device__ __forceinline__ void acc_f8x4(unsigned u, float* a) {
    f32x2 lo = __builtin_amdgcn_cvt_pk_f32_fp8((int)u, false);
    f32x2 hi = __builtin_amdgcn_cvt_pk_f32_fp8((int)u, true);
    a[0] += lo[0]; a[1] += lo[1]; a[2] += hi[0]; a[3] += hi[1];
}

// ---- graph build: bucket partition + per-bucket counting sort ---------------

__global__ __launch_bounds__(256) void k_p1count(const int* __restrict__ dst,
                                                 int* __restrict__ C,
                                                 int nE, int nbk, int epb) {
    __shared__ int h[512];
    for (int i = threadIdx.x; i < nbk; i += 256) h[i] = 0;
    __syncthreads();
    int e0 = blockIdx.x * epb;
    int e1 = min(e0 + epb, nE);
    for (int i = e0 + threadIdx.x; i < e1; i += 256)
        atomicAdd(&h[dst[i] >> 8], 1);
    __syncthreads();
    for (int i = threadIdx.x; i < nbk; i += 256)
        C[blockIdx.x * nbk + i] = h[i];
}

__global__ __launch_bounds__(256) void k_colscan(int* __restrict__ C,
                                                 int* __restrict__ tot, int nbk) {
    __shared__ int sm[256];
    int k = blockIdx.x, t = threadIdx.x;
    int v = C[t * nbk + k];
    sm[t] = v;
    __syncthreads();
    for (int o = 1; o < 256; o <<= 1) {
        int u = (t >= o) ? sm[t - o] : 0;
        __syncthreads();
        sm[t] += u;
        __syncthreads();
    }
    C[t * nbk + k] = sm[t] - v;
    if (t == 255) tot[k] = sm[255];
}

__global__ __launch_bounds__(256) void k_scan_a(const int* __restrict__ cnt,
                                                int* __restrict__ offs,
                                                int* __restrict__ bsum, int n) {
    __shared__ int sm[256];
    int t = threadIdx.x;
    int base = blockIdx.x * 1024 + t * 4;
    int v0 = 0, v1 = 0, v2 = 0, v3 = 0;
    if (base + 3 < n) {
        int4 q = *(const int4*)(cnt + base);
        v0 = q.x; v1 = q.y; v2 = q.z; v3 = q.w;
    } else {
        if (base < n)     v0 = cnt[base];
        if (base + 1 < n) v1 = cnt[base + 1];
        if (base + 2 < n) v2 = cnt[base + 2];
    }
    int s = v0 + v1 + v2 + v3;
    sm[t] = s;
    __syncthreads();
    for (int o = 1; o < 256; o <<= 1) {
        int u = (t >= o) ? sm[t - o] : 0;
        __syncthreads();
        sm[t] += u;
        __syncthreads();
    }
    int excl = sm[t] - s;
    if (base < n)     offs[base]     = excl;
    if (base + 1 < n) offs[base + 1] = excl + v0;
    if (base + 2 < n) offs[base + 2] = excl + v0 + v1;
    if (base + 3 < n) offs[base + 3] = excl + v0 + v1 + v2;
    if (t == 255) bsum[blockIdx.x] = sm[255];
}

__global__ __launch_bounds__(256) void k_scan_b(int* __restrict__ offs,
                                                const int* __restrict__ bsum,
                                                int n, int nb) {
    __shared__ int pfx;
    int t = threadIdx.x, b = blockIdx.x;
    if (t == 0) {
        int s = 0;
        for (int i = 0; i < b; ++i) s += bsum[i];
        pfx = s;
        if (b == nb - 1) offs[n] = s + bsum[b];
    }
    __syncthreads();
    if (b == 0) return;
    int base = b * 1024 + t * 4;
    int p = pfx;
    if (base < n)     offs[base]     += p;
    if (base + 1 < n) offs[base + 1] += p;
    if (base + 2 < n) offs[base + 2] += p;
    if (base + 3 < n) offs[base + 3] += p;
}

__global__ __launch_bounds__(256) void k_p1fill(const int* __restrict__ src,
                                                const int* __restrict__ dst,
                                                const int* __restrict__ bstart,
                                                const int* __restrict__ C,
                                                unsigned* __restrict__ ebuf,
                                                int nE, int nbk, int epb) {
    __shared__ int cur[512];
    int b = blockIdx.x;
    for (int i = threadIdx.x; i < nbk; i += 256)
        cur[i] = bstart[i] + C[b * nbk + i];
    __syncthreads();
    int e0 = b * epb;
    int e1 = min(e0 + epb, nE);
    for (int i = e0 + threadIdx.x; i < e1; i += 256) {
        int d = dst[i];
        unsigned s = (unsigned)src[i];
        int p = atomicAdd(&cur[d >> 8], 1);
        ebuf[p] = (s << 8) | (unsigned)(d & 255);
    }
}

__global__ __launch_bounds__(256) void k_p2fill(const unsigned* __restrict__ ebuf,
                                                const int* __restrict__ bstart,
                                                int* __restrict__ offs,
                                                int* __restrict__ csr,
                                                int nN, int nE) {
    __shared__ int h[256], sm[256], cur[256];
    int k = blockIdx.x, t = threadIdx.x;
    int base = bstart[k], end = bstart[k + 1];
    h[t] = 0;
    __syncthreads();
    for (int i = base + t; i < end; i += 256)
        atomicAdd(&h[ebuf[i] & 255u], 1);
    __syncthreads();
    int v = h[t];
    sm[t] = v;
    __syncthreads();
    for (int o = 1; o < 256; o <<= 1) {
        int u = (t >= o) ? sm[t - o] : 0;
        __syncthreads();
        sm[t] += u;
        __syncthreads();
    }
    int excl = sm[t] - v;
    int node = (k << 8) + t;
    if (node < nN) offs[node] = base + excl;
    cur[t] = base + excl;
    if (k == 0 && t == 0) offs[nN] = nE;
    __syncthreads();
    for (int i = base + t; i < end; i += 256) {
        unsigned e = ebuf[i];
        int p = atomicAdd(&cur[e & 255u], 1);
        csr[p] = (int)(e >> 8);
    }
}

// ---- weight prep: fragment-linear packing -----------------------------------
// Chunk c = ((ks*NB + n)*64 + lane); contents = bf16 W[k..k+7][row] where
// row = n*16 + (lane&15), k = ks*32 + (lane>>4)*8. Wave reads chunk at
// base + lane*16B -> fully coalesced. Logical W = [W1; W2] (K1 + K2 rows).
__global__ __launch_bounds__(256) void k_wtfrag(const float* __restrict__ W1,
                                                const float* __restrict__ W2,
                                                unsigned short* __restrict__ Wt,
                                                int K1, int K, int N) {
    int c = blockIdx.x * 256 + threadIdx.x;
    int NB = N >> 4;
    int nch = (N * K) >> 3;
    if (c >= nch) return;
    int lane = c & 63;
    int n = (c >> 6) % NB;
    int ks = c / (NB << 6);
    int row = n * 16 + (lane & 15);
    int col = ks * 32 + (lane >> 4) * 8;
    unsigned short o[8];
#pragma unroll
    for (int j = 0; j < 8; ++j) {
        int k = col + j;
        float v = (k < K1) ? W1[k * N + row] : W2[(k - K1) * N + row];
        o[j] = f2bf(v);
    }
    *(uint4*)(Wt + (size_t)c * 8) = *(const uint4*)o;
}

// ---- aggregation -----------------------------------------------------------

// 6-dim mean of x[:,4:10]; one thread per node, 4x-unrolled edges
__global__ __launch_bounds__(256) void k_agg0(const float* __restrict__ x,
                                              const int* __restrict__ offs,
                                              const int* __restrict__ csr,
                                              float* __restrict__ mean0, int nN) {
    int i = blockIdx.x * blockDim.x + threadIdx.x;
    if (i >= nN) return;
    int lo = offs[i], hi = offs[i + 1];
    float a0 = 0, a1 = 0, a2 = 0, a3 = 0, a4 = 0, a5 = 0;
    int e = lo;
    for (; e + 4 <= hi; e += 4) {
        int s0 = csr[e], s1 = csr[e + 1], s2 = csr[e + 2], s3 = csr[e + 3];
        const float* r0 = x + (size_t)s0 * 10 + 4;
        const float* r1 = x + (size_t)s1 * 10 + 4;
        const float* r2 = x + (size_t)s2 * 10 + 4;
        const float* r3 = x + (size_t)s3 * 10 + 4;
        float2 u0 = *(const float2*)(r0), u1 = *(const float2*)(r0 + 2), u2 = *(const float2*)(r0 + 4);
        float2 w0 = *(const float2*)(r1), w1 = *(const float2*)(r1 + 2), w2 = *(const float2*)(r1 + 4);
        float2 p0 = *(const float2*)(r2), p1 = *(const float2*)(r2 + 2), p2 = *(const float2*)(r2 + 4);
        float2 q0 = *(const float2*)(r3), q1 = *(const float2*)(r3 + 2), q2 = *(const float2*)(r3 + 4);
        a0 += u0.x + w0.x + p0.x + q0.x;
        a1 += u0.y + w0.y + p0.y + q0.y;
        a2 += u1.x + w1.x + p1.x + q1.x;
        a3 += u1.y + w1.y + p1.y + q1.y;
        a4 += u2.x + w2.x + p2.x + q2.x;
        a5 += u2.y + w2.y + p2.y + q2.y;
    }
    for (; e < hi; ++e) {
        int s = csr[e];
        const float* r = x + (size_t)s * 10 + 4;
        float2 v0 = *(const float2*)(r);
        float2 v1 = *(const float2*)(r + 2);
        float2 v2 = *(const float2*)(r + 4);
        a0 += v0.x; a1 += v0.y; a2 += v1.x; a3 += v1.y; a4 += v2.x; a5 += v2.y;
    }
    float inv = 1.0f / (float)imax(hi - lo, 1);
    float* o = mean0 + (size_t)i * 6;
    o[0] = a0 * inv; o[1] = a1 * inv; o[2] = a2 * inv;
    o[3] = a3 * inv; o[4] = a4 * inv; o[5] = a5 * inv;
}

// 128-dim fp8 mean -> bf16: thread per (node, 16B = 16-feature chunk),
// 4x-unrolled edges. Table values pre-scaled by F8SCALE.
__global__ __launch_bounds__(256) void k_agg128f8(const unsigned char* __restrict__ X,
                                                  const int* __restrict__ offs,
                                                  const int* __restrict__ csr,
                                                  unsigned short* __restrict__ M, int nN) {
    int idx = blockIdx.x * 256 + threadIdx.x;
    int node = idx >> 3;
    int fl = idx & 7;             // features fl*16 .. fl*16+15
    if (node >= nN) return;
    int lo = offs[node], hi = offs[node + 1];
    float a[16];
#pragma unroll
    for (int j = 0; j < 16; ++j) a[j] = 0.f;
    int e = lo;
    for (; e + 4 <= hi; e += 4) {
        int s0 = csr[e], s1 = csr[e + 1], s2 = csr[e + 2], s3 = csr[e + 3];
        uint4 v0 = *(const uint4*)(X + (size_t)s0 * 128 + fl * 16);
        uint4 v1 = *(const uint4*)(X + (size_t)s1 * 128 + fl * 16);
        uint4 v2 = *(const uint4*)(X + (size_t)s2 * 128 + fl * 16);
        uint4 v3 = *(const uint4*)(X + (size_t)s3 * 128 + fl * 16);
        acc_f8x4(v0.x, a + 0);  acc_f8x4(v0.y, a + 4);
        acc_f8x4(v0.z, a + 8);  acc_f8x4(v0.w, a + 12);
        acc_f8x4(v1.x, a + 0);  acc_f8x4(v1.y, a + 4);
        acc_f8x4(v1.z, a + 8);  acc_f8x4(v1.w, a + 12);
        acc_f8x4(v2.x, a + 0);  acc_f8x4(v2.y, a + 4);
        acc_f8x4(v2.z, a + 8);  acc_f8x4(v2.w, a + 12);
        acc_f8x4(v3.x, a + 0);  acc_f8x4(v3.y, a + 4);
        acc_f8x4(v3.z, a + 8);  acc_f8x4(v3.w, a + 12);
    }
    for (; e < hi; ++e) {
        int s = csr[e];
        uint4 v = *(const uint4*)(X + (size_t)s * 128 + fl * 16);
        acc_f8x4(v.x, a + 0);  acc_f8x4(v.y, a + 4);
        acc_f8x4(v.z, a + 8);  acc_f8x4(v.w, a + 12);
    }
    float inv = 1.0f / (F8SCALE * (float)imax(hi - lo, 1));
    unsigned o[8];
#pragma unroll
    for (int j = 0; j < 8; ++j) o[j] = pack2bf(a[2 * j] * inv, a[2 * j + 1] * inv);
    unsigned short* mp = M + (size_t)node * 128 + fl * 16;
    *(uint4*)(mp)     = *(const uint4*)(o);
    *(uint4*)(mp + 8) = *(const uint4*)(o + 4);
}

// 64-dim bf16 mean -> fp32: thread per (node, 16B chunk), 4x-unrolled edges.
__global__ __launch_bounds__(256) void k_agg64(const unsigned short* __restrict__ X,
                                               const int* __restrict__ offs,
                                               const int* __restrict__ csr,
                                               float* __restrict__ M, int nN) {
    int idx = blockIdx.x * 256 + threadIdx.x;
    int node = idx >> 3;
    int fl = idx & 7;             // features fl*8 .. fl*8+7
    if (node >= nN) return;
    int lo = offs[node], hi = offs[node + 1];
    float a0 = 0, a1 = 0, a2 = 0, a3 = 0, a4 = 0, a5 = 0, a6 = 0, a7 = 0;
    int e = lo;
    for (; e + 4 <= hi; e += 4) {
        int s0 = csr[e], s1 = csr[e + 1], s2 = csr[e + 2], s3 = csr[e + 3];
        uint4 v0 = *(const uint4*)(X + (size_t)s0 * 64 + fl * 8);
        uint4 v1 = *(const uint4*)(X + (size_t)s1 * 64 + fl * 8);
        uint4 v2 = *(const uint4*)(X + (size_t)s2 * 64 + fl * 8);
        uint4 v3 = *(const uint4*)(X + (size_t)s3 * 64 + fl * 8);
        a0 += bfbits_lo(v0.x); a1 += bfbits_hi(v0.x);
        a2 += bfbits_lo(v0.y); a3 += bfbits_hi(v0.y);
        a4 += bfbits_lo(v0.z); a5 += bfbits_hi(v0.z);
        a6 += bfbits_lo(v0.w); a7 += bfbits_hi(v0.w);
        a0 += bfbits_lo(v1.x); a1 += bfbits_hi(v1.x);
        a2 += bfbits_lo(v1.y); a3 += bfbits_hi(v1.y);
        a4 += bfbits_lo(v1.z); a5 += bfbits_hi(v1.z);
        a6 += bfbits_lo(v1.w); a7 += bfbits_hi(v1.w);
        a0 += bfbits_lo(v2.x); a1 += bfbits_hi(v2.x);
        a2 += bfbits_lo(v2.y); a3 += bfbits_hi(v2.y);
        a4 += bfbits_lo(v2.z); a5 += bfbits_hi(v2.z);
        a6 += bfbits_lo(v2.w); a7 += bfbits_hi(v2.w);
        a0 += bfbits_lo(v3.x); a1 += bfbits_hi(v3.x);
        a2 += bfbits_lo(v3.y); a3 += bfbits_hi(v3.y);
        a4 += bfbits_lo(v3.z); a5 += bfbits_hi(v3.z);
        a6 += bfbits_lo(v3.w); a7 += bfbits_hi(v3.w);
    }
    for (; e < hi; ++e) {
        int s = csr[e];
        uint4 v = *(const uint4*)(X + (size_t)s * 64 + fl * 8);
        a0 += bfbits_lo(v.x); a1 += bfbits_hi(v.x);
        a2 += bfbits_lo(v.y); a3 += bfbits_hi(v.y);
        a4 += bfbits_lo(v.z); a5 += bfbits_hi(v.z);
        a6 += bfbits_lo(v.w); a7 += bfbits_hi(v.w);
    }
    float inv = 1.0f / (float)imax(hi - lo, 1);
    float* o = M + (size_t)node * 64 + fl * 8;
    *(float4*)(o)     = make_float4(a0 * inv, a1 * inv, a2 * inv, a3 * inv);
    *(float4*)(o + 4) = make_float4(a4 * inv, a5 * inv, a6 * inv, a7 * inv);
}

// ---- layer 0 (K=6): one thread per (node, out-feature) ----------------------
// writes bf16 (GEMM A-operand) and fp8-e4m3 x F8SCALE (gather table)

__global__ __launch_bounds__(256) void k_l0(const float* __restrict__ x,
                                            const float* __restrict__ mean0,
                                            const float* __restrict__ Wl,
                                            const float* __restrict__ bl,
                                            const float* __restrict__ Wr,
                                            unsigned short* __restrict__ out,
                                            unsigned char* __restrict__ out8, int nN) {
    int j = threadIdx.x & 127;
    int node = blockIdx.x * 2 + (threadIdx.x >> 7);
    if (node >= nN) return;
    const float* m = mean0 + (size_t)node * 6;
    const float* h = x + (size_t)node * 10 + 4;
    float v = bl[j];
#pragma unroll
    for (int k = 0; k < 6; ++k) v = fmaf(m[k], Wl[k * 128 + j], v);
#pragma unroll
    for (int k = 0; k < 6; ++k) v = fmaf(h[k], Wr[k * 128 + j], v);
    v = fmaxf(v, 0.f);
    out[(size_t)node * 128 + j] = f2bf(v);
    float vs = v * F8SCALE;
    int pk = __builtin_amdgcn_cvt_pk_fp8_f32(vs, vs, 0, false);
    out8[(size_t)node * 128 + j] = (unsigned char)(pk & 0xff);
}

// ---- MFMA GEMM: C = act( [A0|A1] @ W^T (+bias) (+add) ) ---------------------
// Wt is fragment-linear (see k_wtfrag): B-load = base + lane*16B, coalesced.

template <int KA, int KB, int N, bool RELU, bool BF16OUT, bool HASBIAS, bool HASADD>
__global__ __launch_bounds__(256) void k_mfma(const unsigned short* __restrict__ A0,
                                              const unsigned short* __restrict__ A1,
                                              const unsigned short* __restrict__ Wt,
                                              const float* __restrict__ bias,
                                              const float* __restrict__ add,
                                              void* __restrict__ Cout, int nN) {
    constexpr int K = KA + KB;
    constexpr int NB = N / 16;
    const int tid = threadIdx.x;
    const int wave = (blockIdx.x * 256 + tid) >> 6;
    const int m0 = wave * 32;
    if (m0 >= nN) return;
    const int lane = tid & 63;
    const int lr = lane & 15;
    const int lk = lane >> 4;

    f32x4 acc[2][NB];
#pragma unroll
    for (int g = 0; g < 2; ++g)
#pragma unroll
        for (int n = 0; n < NB; ++n) acc[g][n] = (f32x4){0.f, 0.f, 0.f, 0.f};

#pragma unroll
    for (int kk = 0; kk < K; kk += 32) {
        const unsigned short* Ap;
        int lda, krel;
        if (KB > 0 && kk >= KA) { Ap = A1; lda = KB; krel = kk - KA; }
        else                    { Ap = A0; lda = KA; krel = kk; }
        bf16x8 a0 = *(const bf16x8*)(Ap + (size_t)(m0 + lr) * lda + krel + lk * 8);
        bf16x8 a1 = *(const bf16x8*)(Ap + (size_t)(m0 + 16 + lr) * lda + krel + lk * 8);
        const unsigned short* Wk = Wt + (((size_t)(kk >> 5) * NB) << 6) * 8 + lane * 8;
#pragma unroll
        for (int n = 0; n < NB; ++n) {
            bf16x8 b = *(const bf16x8*)(Wk + ((size_t)n << 6) * 8);
            acc[0][n] = __builtin_amdgcn_mfma_f32_16x16x32_bf16(a0, b, acc[0][n], 0, 0, 0);
            acc[1][n] = __builtin_amdgcn_mfma_f32_16x16x32_bf16(a1, b, acc[1][n], 0, 0, 0);
        }
    }

#pragma unroll
    for (int g = 0; g < 2; ++g) {
#pragma unroll
        for (int r = 0; r < 4; ++r) {
            int gm = m0 + g * 16 + lk * 4 + r;
#pragma unroll
            for (int n = 0; n < NB; ++n) {
                float v = acc[g][n][r];
                if (HASBIAS) v += bias[n * 16 + lr];
                if (HASADD)  v += add[(size_t)gm * N + n * 16 + lr];
                if (RELU)    v = fmaxf(v, 0.f);
                if (BF16OUT) ((unsigned short*)Cout)[(size_t)gm * N + n * 16 + lr] = f2bf(v);
                else         ((float*)Cout)[(size_t)gm * N + n * 16 + lr] = v;
            }
        }
    }
}

// ---------------------------------------------------------------------------

extern "C" void kernel_launch(void* const* d_in, const int* in_sizes, int n_in,
                              void* d_out, int out_size, void* d_ws, size_t ws_size,
                              hipStream_t stream) {
    const float* x   = (const float*)d_in[0];
    const int*   ei  = (const int*)d_in[1];
    const float* Wl0 = (const float*)d_in[2];
    const float* bl0 = (const float*)d_in[3];
    const float* Wr0 = (const float*)d_in[4];
    const float* Wl1 = (const float*)d_in[5];
    const float* bl1 = (const float*)d_in[6];
    const float* Wr1 = (const float*)d_in[7];
    const float* Wl2 = (const float*)d_in[8];
    const float* bl2 = (const float*)d_in[9];
    const float* Wr2 = (const float*)d_in[10];

    const int nN = in_sizes[0] / 10;
    const int nE = in_sizes[1] / 2;
    const int* src = ei;
    const int* dst = ei + nE;
    const int nbk = (nN + 255) >> 8;            // 391 buckets (<=512 for LDS)
    const int epb = (nE + PB - 1) / PB;         // edges per partition block

    char* ws = (char*)d_ws;
    size_t off = 0;
    auto alloc = [&](size_t bytes) -> char* {
        char* p = ws + off;
        off = (off + bytes + 255) & ~(size_t)255;
        return p;
    };
    unsigned short* out0   = (unsigned short*)alloc((size_t)nN * 128 * 2); // reused as z2
    unsigned char*  out0f8 = (unsigned char*)alloc((size_t)nN * 128);
    unsigned short* mean1  = (unsigned short*)alloc((size_t)nN * 128 * 2); // reused as meanz2 (fp32 x64)
    unsigned short* out1   = (unsigned short*)alloc((size_t)nN * 128 * 2);
    float* mean0 = (float*)alloc((size_t)nN * 6 * 4);
    unsigned short* Wt1  = (unsigned short*)alloc((size_t)128 * 256 * 2);
    unsigned short* Wt2l = (unsigned short*)alloc((size_t)64 * 128 * 2);
    unsigned short* Wt2r = (unsigned short*)alloc((size_t)64 * 128 * 2);
    int* C      = (int*)alloc((size_t)PB * nbk * 4);
    int* tot    = (int*)alloc((size_t)nbk * 4);
    int* bstart = (int*)alloc(((size_t)nbk + 1) * 4);
    int* bsum   = (int*)alloc(4 * 4);
    int* offs   = (int*)alloc(((size_t)nN + 1) * 4);
    int* csr    = (int*)alloc((size_t)nE * 4);
    unsigned* ebuf = (unsigned*)alloc((size_t)nE * 4);

    unsigned short* z2     = out0;            // out0 dead after layer-1 GEMM
    float*          meanz2 = (float*)mean1;   // mean1 dead after layer-1 GEMM

    // weight prep: fragment-linear packing (independent of graph build)
    k_wtfrag<<<(128 * 256 / 8 + 255) / 256, 256, 0, stream>>>(Wl1, Wr1, Wt1, 128, 256, 128);
    k_wtfrag<<<(64 * 128 / 8 + 255) / 256, 256, 0, stream>>>(Wl2, Wl2, Wt2l, 128, 128, 64);
    k_wtfrag<<<(64 * 128 / 8 + 255) / 256, 256, 0, stream>>>(Wr2, Wr2, Wt2r, 128, 128, 64);

    // build dst-sorted CSR via bucket partition (no global atomics, dense writes)
    k_p1count<<<PB, 256, 0, stream>>>(dst, C, nE, nbk, epb);
    k_colscan<<<nbk, 256, 0, stream>>>(C, tot, nbk);
    k_scan_a<<<1, 256, 0, stream>>>(tot, bstart, bsum, nbk);
    k_scan_b<<<1, 256, 0, stream>>>(bstart, bsum, nbk, 1);
    k_p1fill<<<PB, 256, 0, stream>>>(src, dst, bstart, C, ebuf, nE, nbk, epb);
    k_p2fill<<<nbk, 256, 0, stream>>>(ebuf, bstart, offs, csr, nN, nE);

    // layer 0 (K=6) -> out0 (bf16) + out0f8 (fp8 gather table)
    k_agg0<<<(nN + 255) / 256, 256, 0, stream>>>(x, offs, csr, mean0, nN);
    k_l0<<<(nN + 1) / 2, 256, 0, stream>>>(x, mean0, Wl0, bl0, Wr0, out0, out0f8, nN);

    const int gemm_grid = (nN / 32 + 3) / 4 + 1;   // 4 waves/block, 32 rows/wave

    // layer 1: mean1 = agg(out0f8); out1 = relu([mean1|out0] @ W1 + bl1)
    k_agg128f8<<<((size_t)nN * 8 + 255) / 256, 256, 0, stream>>>(out0f8, offs, csr, mean1, nN);
    k_mfma<128, 128, 128, true, true, true, false><<<gemm_grid, 256, 0, stream>>>(
        mean1, out0, Wt1, bl1, nullptr, out1, nN);

    // layer 2 (reordered): z2 = out1@Wl2 (bf16); out = relu(out1@Wr2 + bl2 + agg(z2))
    k_mfma<128, 0, 64, false, true, false, false><<<gemm_grid, 256, 0, stream>>>(
        out1, nullptr, Wt2l, nullptr, nullptr, z2, nN);
    k_agg64<<<((size_t)nN * 8 + 255) / 256, 256, 0, stream>>>(z2, offs, csr, meanz2, nN);
    k_mfma<128, 0, 64, true, false, true, true><<<gemm_grid, 256, 0, stream>>>(
        out1, nullptr, Wt2r, bl2, meanz2, (float*)d_out, nN);
}

// Round 8
// 243.873 us; speedup vs baseline: 3.6777x; 1.1114x over previous
//
#include <hip/hip_runtime.h>

// ---------------------------------------------------------------------------
// GraphSAGE 3-layer forward.
//   h = x[:,4:10]; per layer: mean_agg(h) @ Wl + bl + h @ Wr, relu
// Round-8 changes:
//   - k_mfma: double-buffered REGISTER prefetch across k-steps. Round-7's
//     VGPR_Count=68 left no operand headroom -> 10 serialized global loads
//     per k-step (MfmaUtil 3.9%, 55us). Now step ks+1's A/B fragments load
//     into named regs (a0n/a1n/bn[]) before ks's MFMAs issue; ~165 VGPR,
//     still 3 waves/SIMD, one exposed latency per k-step instead of ten.
// ---------------------------------------------------------------------------

typedef __attribute__((ext_vector_type(8))) short bf16x8;   // 8 bf16 = 4 VGPR
typedef __attribute__((ext_vector_type(4))) float f32x4;
typedef __attribute__((ext_vector_type(2))) float f32x2;

constexpr int PB = 256;   // partition pass blocks (== colscan threads, fixed)
constexpr float F8SCALE = 32.0f;

static __device__ __forceinline__ int imax(int a, int b) { return a > b ? a : b; }

static __device__ __forceinline__ float bfbits_lo(unsigned u) {
    union { unsigned i; float f; } v; v.i = u << 16; return v.f;
}
static __device__ __forceinline__ float bfbits_hi(unsigned u) {
    union { unsigned i; float f; } v; v.i = u & 0xffff0000u; return v.f;
}
static __device__ __forceinline__ unsigned short f2bf(float f) {
    unsigned u = __float_as_uint(f);
    u = (u + 0x7fffu + ((u >> 16) & 1u)) >> 16;
    return (unsigned short)u;
}
static __device__ __forceinline__ unsigned pack2bf(float a, float b) {
    return (unsigned)f2bf(a) | ((unsigned)f2bf(b) << 16);
}
// accumulate 4 fp8-e4m3 bytes (one dword) into a[0..3]
static __device__ __forceinline__ void acc_f8x4(unsigned u, float* a) {
    f32x2 lo = __builtin_amdgcn_cvt_pk_f32_fp8((int)u, false);
    f32x2 hi = __builtin_amdgcn_cvt_pk_f32_fp8((int)u, true);
    a[0] += lo[0]; a[1] += lo[1]; a[2] += hi[0]; a[3] += hi[1];
}

// ---- graph build: bucket partition + per-bucket counting sort ---------------

__global__ __launch_bounds__(256) void k_p1count(const int* __restrict__ dst,
                                                 int* __restrict__ C,
                                                 int nE, int nbk, int epb) {
    __shared__ int h[512];
    for (int i = threadIdx.x; i < nbk; i += 256) h[i] = 0;
    __syncthreads();
    int e0 = blockIdx.x * epb;
    int e1 = min(e0 + epb, nE);
    for (int i = e0 + threadIdx.x; i < e1; i += 256)
        atomicAdd(&h[dst[i] >> 8], 1);
    __syncthreads();
    for (int i = threadIdx.x; i < nbk; i += 256)
        C[blockIdx.x * nbk + i] = h[i];
}

__global__ __launch_bounds__(256) void k_colscan(int* __restrict__ C,
                                                 int* __restrict__ tot, int nbk) {
    __shared__ int sm[256];
    int k = blockIdx.x, t = threadIdx.x;
    int v = C[t * nbk + k];
    sm[t] = v;
    __syncthreads();
    for (int o = 1; o < 256; o <<= 1) {
        int u = (t >= o) ? sm[t - o] : 0;
        __syncthreads();
        sm[t] += u;
        __syncthreads();
    }
    C[t * nbk + k] = sm[t] - v;
    if (t == 255) tot[k] = sm[255];
}

__global__ __launch_bounds__(256) void k_scan_a(const int* __restrict__ cnt,
                                                int* __restrict__ offs,
                                                int* __restrict__ bsum, int n) {
    __shared__ int sm[256];
    int t = threadIdx.x;
    int base = blockIdx.x * 1024 + t * 4;
    int v0 = 0, v1 = 0, v2 = 0, v3 = 0;
    if (base + 3 < n) {
        int4 q = *(const int4*)(cnt + base);
        v0 = q.x; v1 = q.y; v2 = q.z; v3 = q.w;
    } else {
        if (base < n)     v0 = cnt[base];
        if (base + 1 < n) v1 = cnt[base + 1];
        if (base + 2 < n) v2 = cnt[base + 2];
    }
    int s = v0 + v1 + v2 + v3;
    sm[t] = s;
    __syncthreads();
    for (int o = 1; o < 256; o <<= 1) {
        int u = (t >= o) ? sm[t - o] : 0;
        __syncthreads();
        sm[t] += u;
        __syncthreads();
    }
    int excl = sm[t] - s;
    if (base < n)     offs[base]     = excl;
    if (base + 1 < n) offs[base + 1] = excl + v0;
    if (base + 2 < n) offs[base + 2] = excl + v0 + v1;
    if (base + 3 < n) offs[base + 3] = excl + v0 + v1 + v2;
    if (t == 255) bsum[blockIdx.x] = sm[255];
}

__global__ __launch_bounds__(256) void k_scan_b(int* __restrict__ offs,
                                                const int* __restrict__ bsum,
                                                int n, int nb) {
    __shared__ int pfx;
    int t = threadIdx.x, b = blockIdx.x;
    if (t == 0) {
        int s = 0;
        for (int i = 0; i < b; ++i) s += bsum[i];
        pfx = s;
        if (b == nb - 1) offs[n] = s + bsum[b];
    }
    __syncthreads();
    if (b == 0) return;
    int base = b * 1024 + t * 4;
    int p = pfx;
    if (base < n)     offs[base]     += p;
    if (base + 1 < n) offs[base + 1] += p;
    if (base + 2 < n) offs[base + 2] += p;
    if (base + 3 < n) offs[base + 3] += p;
}

__global__ __launch_bounds__(256) void k_p1fill(const int* __restrict__ src,
                                                const int* __restrict__ dst,
                                                const int* __restrict__ bstart,
                                                const int* __restrict__ C,
                                                unsigned* __restrict__ ebuf,
                                                int nE, int nbk, int epb) {
    __shared__ int cur[512];
    int b = blockIdx.x;
    for (int i = threadIdx.x; i < nbk; i += 256)
        cur[i] = bstart[i] + C[b * nbk + i];
    __syncthreads();
    int e0 = b * epb;
    int e1 = min(e0 + epb, nE);
    for (int i = e0 + threadIdx.x; i < e1; i += 256) {
        int d = dst[i];
        unsigned s = (unsigned)src[i];
        int p = atomicAdd(&cur[d >> 8], 1);
        ebuf[p] = (s << 8) | (unsigned)(d & 255);
    }
}

__global__ __launch_bounds__(256) void k_p2fill(const unsigned* __restrict__ ebuf,
                                                const int* __restrict__ bstart,
                                                int* __restrict__ offs,
                                                int* __restrict__ csr,
                                                int nN, int nE) {
    __shared__ int h[256], sm[256], cur[256];
    int k = blockIdx.x, t = threadIdx.x;
    int base = bstart[k], end = bstart[k + 1];
    h[t] = 0;
    __syncthreads();
    for (int i = base + t; i < end; i += 256)
        atomicAdd(&h[ebuf[i] & 255u], 1);
    __syncthreads();
    int v = h[t];
    sm[t] = v;
    __syncthreads();
    for (int o = 1; o < 256; o <<= 1) {
        int u = (t >= o) ? sm[t - o] : 0;
        __syncthreads();
        sm[t] += u;
        __syncthreads();
    }
    int excl = sm[t] - v;
    int node = (k << 8) + t;
    if (node < nN) offs[node] = base + excl;
    cur[t] = base + excl;
    if (k == 0 && t == 0) offs[nN] = nE;
    __syncthreads();
    for (int i = base + t; i < end; i += 256) {
        unsigned e = ebuf[i];
        int p = atomicAdd(&cur[e & 255u], 1);
        csr[p] = (int)(e >> 8);
    }
}

// ---- weight prep: fragment-linear packing -----------------------------------
// Chunk c = ((ks*NB + n)*64 + lane); contents = bf16 W[k..k+7][row] where
// row = n*16 + (lane&15), k = ks*32 + (lane>>4)*8. Wave reads chunk at
// base + lane*16B -> fully coalesced. Logical W = [W1; W2] (K1 + K2 rows).
__global__ __launch_bounds__(256) void k_wtfrag(const float* __restrict__ W1,
                                                const float* __restrict__ W2,
                                                unsigned short* __restrict__ Wt,
                                                int K1, int K, int N) {
    int c = blockIdx.x * 256 + threadIdx.x;
    int NB = N >> 4;
    int nch = (N * K) >> 3;
    if (c >= nch) return;
    int lane = c & 63;
    int n = (c >> 6) % NB;
    int ks = c / (NB << 6);
    int row = n * 16 + (lane & 15);
    int col = ks * 32 + (lane >> 4) * 8;
    unsigned short o[8];
#pragma unroll
    for (int j = 0; j < 8; ++j) {
        int k = col + j;
        float v = (k < K1) ? W1[k * N + row] : W2[(k - K1) * N + row];
        o[j] = f2bf(v);
    }
    *(uint4*)(Wt + (size_t)c * 8) = *(const uint4*)o;
}

// ---- aggregation -----------------------------------------------------------

// 6-dim mean of x[:,4:10]; one thread per node, 4x-unrolled edges
__global__ __launch_bounds__(256) void k_agg0(const float* __restrict__ x,
                                              const int* __restrict__ offs,
                                              const int* __restrict__ csr,
                                              float* __restrict__ mean0, int nN) {
    int i = blockIdx.x * blockDim.x + threadIdx.x;
    if (i >= nN) return;
    int lo = offs[i], hi = offs[i + 1];
    float a0 = 0, a1 = 0, a2 = 0, a3 = 0, a4 = 0, a5 = 0;
    int e = lo;
    for (; e + 4 <= hi; e += 4) {
        int s0 = csr[e], s1 = csr[e + 1], s2 = csr[e + 2], s3 = csr[e + 3];
        const float* r0 = x + (size_t)s0 * 10 + 4;
        const float* r1 = x + (size_t)s1 * 10 + 4;
        const float* r2 = x + (size_t)s2 * 10 + 4;
        const float* r3 = x + (size_t)s3 * 10 + 4;
        float2 u0 = *(const float2*)(r0), u1 = *(const float2*)(r0 + 2), u2 = *(const float2*)(r0 + 4);
        float2 w0 = *(const float2*)(r1), w1 = *(const float2*)(r1 + 2), w2 = *(const float2*)(r1 + 4);
        float2 p0 = *(const float2*)(r2), p1 = *(const float2*)(r2 + 2), p2 = *(const float2*)(r2 + 4);
        float2 q0 = *(const float2*)(r3), q1 = *(const float2*)(r3 + 2), q2 = *(const float2*)(r3 + 4);
        a0 += u0.x + w0.x + p0.x + q0.x;
        a1 += u0.y + w0.y + p0.y + q0.y;
        a2 += u1.x + w1.x + p1.x + q1.x;
        a3 += u1.y + w1.y + p1.y + q1.y;
        a4 += u2.x + w2.x + p2.x + q2.x;
        a5 += u2.y + w2.y + p2.y + q2.y;
    }
    for (; e < hi; ++e) {
        int s = csr[e];
        const float* r = x + (size_t)s * 10 + 4;
        float2 v0 = *(const float2*)(r);
        float2 v1 = *(const float2*)(r + 2);
        float2 v2 = *(const float2*)(r + 4);
        a0 += v0.x; a1 += v0.y; a2 += v1.x; a3 += v1.y; a4 += v2.x; a5 += v2.y;
    }
    float inv = 1.0f / (float)imax(hi - lo, 1);
    float* o = mean0 + (size_t)i * 6;
    o[0] = a0 * inv; o[1] = a1 * inv; o[2] = a2 * inv;
    o[3] = a3 * inv; o[4] = a4 * inv; o[5] = a5 * inv;
}

// 128-dim fp8 mean -> bf16: thread per (node, 16B = 16-feature chunk),
// 4x-unrolled edges. Table values pre-scaled by F8SCALE.
__global__ __launch_bounds__(256) void k_agg128f8(const unsigned char* __restrict__ X,
                                                  const int* __restrict__ offs,
                                                  const int* __restrict__ csr,
                                                  unsigned short* __restrict__ M, int nN) {
    int idx = blockIdx.x * 256 + threadIdx.x;
    int node = idx >> 3;
    int fl = idx & 7;             // features fl*16 .. fl*16+15
    if (node >= nN) return;
    int lo = offs[node], hi = offs[node + 1];
    float a[16];
#pragma unroll
    for (int j = 0; j < 16; ++j) a[j] = 0.f;
    int e = lo;
    for (; e + 4 <= hi; e += 4) {
        int s0 = csr[e], s1 = csr[e + 1], s2 = csr[e + 2], s3 = csr[e + 3];
        uint4 v0 = *(const uint4*)(X + (size_t)s0 * 128 + fl * 16);
        uint4 v1 = *(const uint4*)(X + (size_t)s1 * 128 + fl * 16);
        uint4 v2 = *(const uint4*)(X + (size_t)s2 * 128 + fl * 16);
        uint4 v3 = *(const uint4*)(X + (size_t)s3 * 128 + fl * 16);
        acc_f8x4(v0.x, a + 0);  acc_f8x4(v0.y, a + 4);
        acc_f8x4(v0.z, a + 8);  acc_f8x4(v0.w, a + 12);
        acc_f8x4(v1.x, a + 0);  acc_f8x4(v1.y, a + 4);
        acc_f8x4(v1.z, a + 8);  acc_f8x4(v1.w, a + 12);
        acc_f8x4(v2.x, a + 0);  acc_f8x4(v2.y, a + 4);
        acc_f8x4(v2.z, a + 8);  acc_f8x4(v2.w, a + 12);
        acc_f8x4(v3.x, a + 0);  acc_f8x4(v3.y, a + 4);
        acc_f8x4(v3.z, a + 8);  acc_f8x4(v3.w, a + 12);
    }
    for (; e < hi; ++e) {
        int s = csr[e];
        uint4 v = *(const uint4*)(X + (size_t)s * 128 + fl * 16);
        acc_f8x4(v.x, a + 0);  acc_f8x4(v.y, a + 4);
        acc_f8x4(v.z, a + 8);  acc_f8x4(v.w, a + 12);
    }
    float inv = 1.0f / (F8SCALE * (float)imax(hi - lo, 1));
    unsigned o[8];
#pragma unroll
    for (int j = 0; j < 8; ++j) o[j] = pack2bf(a[2 * j] * inv, a[2 * j + 1] * inv);
    unsigned short* mp = M + (size_t)node * 128 + fl * 16;
    *(uint4*)(mp)     = *(const uint4*)(o);
    *(uint4*)(mp + 8) = *(const uint4*)(o + 4);
}

// 64-dim bf16 mean -> fp32: thread per (node, 16B chunk), 4x-unrolled edges.
__global__ __launch_bounds__(256) void k_agg64(const unsigned short* __restrict__ X,
                                               const int* __restrict__ offs,
                                               const int* __restrict__ csr,
                                               float* __restrict__ M, int nN) {
    int idx = blockIdx.x * 256 + threadIdx.x;
    int node = idx >> 3;
    int fl = idx & 7;             // features fl*8 .. fl*8+7
    if (node >= nN) return;
    int lo = offs[node], hi = offs[node + 1];
    float a0 = 0, a1 = 0, a2 = 0, a3 = 0, a4 = 0, a5 = 0, a6 = 0, a7 = 0;
    int e = lo;
    for (; e + 4 <= hi; e += 4) {
        int s0 = csr[e], s1 = csr[e + 1], s2 = csr[e + 2], s3 = csr[e + 3];
        uint4 v0 = *(const uint4*)(X + (size_t)s0 * 64 + fl * 8);
        uint4 v1 = *(const uint4*)(X + (size_t)s1 * 64 + fl * 8);
        uint4 v2 = *(const uint4*)(X + (size_t)s2 * 64 + fl * 8);
        uint4 v3 = *(const uint4*)(X + (size_t)s3 * 64 + fl * 8);
        a0 += bfbits_lo(v0.x); a1 += bfbits_hi(v0.x);
        a2 += bfbits_lo(v0.y); a3 += bfbits_hi(v0.y);
        a4 += bfbits_lo(v0.z); a5 += bfbits_hi(v0.z);
        a6 += bfbits_lo(v0.w); a7 += bfbits_hi(v0.w);
        a0 += bfbits_lo(v1.x); a1 += bfbits_hi(v1.x);
        a2 += bfbits_lo(v1.y); a3 += bfbits_hi(v1.y);
        a4 += bfbits_lo(v1.z); a5 += bfbits_hi(v1.z);
        a6 += bfbits_lo(v1.w); a7 += bfbits_hi(v1.w);
        a0 += bfbits_lo(v2.x); a1 += bfbits_hi(v2.x);
        a2 += bfbits_lo(v2.y); a3 += bfbits_hi(v2.y);
        a4 += bfbits_lo(v2.z); a5 += bfbits_hi(v2.z);
        a6 += bfbits_lo(v2.w); a7 += bfbits_hi(v2.w);
        a0 += bfbits_lo(v3.x); a1 += bfbits_hi(v3.x);
        a2 += bfbits_lo(v3.y); a3 += bfbits_hi(v3.y);
        a4 += bfbits_lo(v3.z); a5 += bfbits_hi(v3.z);
        a6 += bfbits_lo(v3.w); a7 += bfbits_hi(v3.w);
    }
    for (; e < hi; ++e) {
        int s = csr[e];
        uint4 v = *(const uint4*)(X + (size_t)s * 64 + fl * 8);
        a0 += bfbits_lo(v.x); a1 += bfbits_hi(v.x);
        a2 += bfbits_lo(v.y); a3 += bfbits_hi(v.y);
        a4 += bfbits_lo(v.z); a5 += bfbits_hi(v.z);
        a6 += bfbits_lo(v.w); a7 += bfbits_hi(v.w);
    }
    float inv = 1.0f / (float)imax(hi - lo, 1);
    float* o = M + (size_t)node * 64 + fl * 8;
    *(float4*)(o)     = make_float4(a0 * inv, a1 * inv, a2 * inv, a3 * inv);
    *(float4*)(o + 4) = make_float4(a4 * inv, a5 * inv, a6 * inv, a7 * inv);
}

// ---- layer 0 (K=6): one thread per (node, out-feature) ----------------------
// writes bf16 (GEMM A-operand) and fp8-e4m3 x F8SCALE (gather table)

__global__ __launch_bounds__(256) void k_l0(const float* __restrict__ x,
                                            const float* __restrict__ mean0,
                                            const float* __restrict__ Wl,
                                            const float* __restrict__ bl,
                                            const float* __restrict__ Wr,
                                            unsigned short* __restrict__ out,
                                            unsigned char* __restrict__ out8, int nN) {
    int j = threadIdx.x & 127;
    int node = blockIdx.x * 2 + (threadIdx.x >> 7);
    if (node >= nN) return;
    const float* m = mean0 + (size_t)node * 6;
    const float* h = x + (size_t)node * 10 + 4;
    float v = bl[j];
#pragma unroll
    for (int k = 0; k < 6; ++k) v = fmaf(m[k], Wl[k * 128 + j], v);
#pragma unroll
    for (int k = 0; k < 6; ++k) v = fmaf(h[k], Wr[k * 128 + j], v);
    v = fmaxf(v, 0.f);
    out[(size_t)node * 128 + j] = f2bf(v);
    float vs = v * F8SCALE;
    int pk = __builtin_amdgcn_cvt_pk_fp8_f32(vs, vs, 0, false);
    out8[(size_t)node * 128 + j] = (unsigned char)(pk & 0xff);
}

// ---- MFMA GEMM: C = act( [A0|A1] @ W^T (+bias) (+add) ) ---------------------
// Wt fragment-linear (k_wtfrag). Double-buffered register prefetch: step
// ks+1's A/B fragments are loaded into named regs before ks's MFMAs.

template <int KA, int KB, int N, bool RELU, bool BF16OUT, bool HASBIAS, bool HASADD>
__global__ __launch_bounds__(256) void k_mfma(const unsigned short* __restrict__ A0,
                                              const unsigned short* __restrict__ A1,
                                              const unsigned short* __restrict__ Wt,
                                              const float* __restrict__ bias,
                                              const float* __restrict__ add,
                                              void* __restrict__ Cout, int nN) {
    constexpr int K = KA + KB;
    constexpr int NSTEP = K / 32;
    constexpr int NB = N / 16;
    const int tid = threadIdx.x;
    const int wave = (blockIdx.x * 256 + tid) >> 6;
    const int m0 = wave * 32;
    if (m0 >= nN) return;
    const int lane = tid & 63;
    const int lr = lane & 15;
    const int lk = lane >> 4;

    f32x4 acc[2][NB];
#pragma unroll
    for (int g = 0; g < 2; ++g)
#pragma unroll
        for (int n = 0; n < NB; ++n) acc[g][n] = (f32x4){0.f, 0.f, 0.f, 0.f};

    auto loadA = [&](int kk, bf16x8& a0, bf16x8& a1) {
        const unsigned short* Ap;
        int lda, krel;
        if (KB > 0 && kk >= KA) { Ap = A1; lda = KB; krel = kk - KA; }
        else                    { Ap = A0; lda = KA; krel = kk; }
        a0 = *(const bf16x8*)(Ap + (size_t)(m0 + lr) * lda + krel + lk * 8);
        a1 = *(const bf16x8*)(Ap + (size_t)(m0 + 16 + lr) * lda + krel + lk * 8);
    };
    auto loadB = [&](int ks, bf16x8* b) {
        const unsigned short* Wk = Wt + (((size_t)ks * NB) << 6) * 8 + lane * 8;
#pragma unroll
        for (int n = 0; n < NB; ++n)
            b[n] = *(const bf16x8*)(Wk + ((size_t)n << 6) * 8);
    };

    bf16x8 a0c, a1c, a0n, a1n;
    bf16x8 bc[NB], bn[NB];
    loadA(0, a0c, a1c);
    loadB(0, bc);

#pragma unroll
    for (int ks = 0; ks < NSTEP; ++ks) {
        if (ks + 1 < NSTEP) {           // issue next step's loads FIRST
            loadA((ks + 1) * 32, a0n, a1n);
            loadB(ks + 1, bn);
        }
#pragma unroll
        for (int n = 0; n < NB; ++n) {
            acc[0][n] = __builtin_amdgcn_mfma_f32_16x16x32_bf16(a0c, bc[n], acc[0][n], 0, 0, 0);
            acc[1][n] = __builtin_amdgcn_mfma_f32_16x16x32_bf16(a1c, bc[n], acc[1][n], 0, 0, 0);
        }
        if (ks + 1 < NSTEP) {           // register rename (folds after unroll)
            a0c = a0n; a1c = a1n;
#pragma unroll
            for (int n = 0; n < NB; ++n) bc[n] = bn[n];
        }
    }

#pragma unroll
    for (int g = 0; g < 2; ++g) {
#pragma unroll
        for (int r = 0; r < 4; ++r) {
            int gm = m0 + g * 16 + lk * 4 + r;
#pragma unroll
            for (int n = 0; n < NB; ++n) {
                float v = acc[g][n][r];
                if (HASBIAS) v += bias[n * 16 + lr];
                if (HASADD)  v += add[(size_t)gm * N + n * 16 + lr];
                if (RELU)    v = fmaxf(v, 0.f);
                if (BF16OUT) ((unsigned short*)Cout)[(size_t)gm * N + n * 16 + lr] = f2bf(v);
                else         ((float*)Cout)[(size_t)gm * N + n * 16 + lr] = v;
            }
        }
    }
}

// ---------------------------------------------------------------------------

extern "C" void kernel_launch(void* const* d_in, const int* in_sizes, int n_in,
                              void* d_out, int out_size, void* d_ws, size_t ws_size,
                              hipStream_t stream) {
    const float* x   = (const float*)d_in[0];
    const int*   ei  = (const int*)d_in[1];
    const float* Wl0 = (const float*)d_in[2];
    const float* bl0 = (const float*)d_in[3];
    const float* Wr0 = (const float*)d_in[4];
    const float* Wl1 = (const float*)d_in[5];
    const float* bl1 = (const float*)d_in[6];
    const float* Wr1 = (const float*)d_in[7];
    const float* Wl2 = (const float*)d_in[8];
    const float* bl2 = (const float*)d_in[9];
    const float* Wr2 = (const float*)d_in[10];

    const int nN = in_sizes[0] / 10;
    const int nE = in_sizes[1] / 2;
    const int* src = ei;
    const int* dst = ei + nE;
    const int nbk = (nN + 255) >> 8;            // 391 buckets (<=512 for LDS)
    const int epb = (nE + PB - 1) / PB;         // edges per partition block

    char* ws = (char*)d_ws;
    size_t off = 0;
    auto alloc = [&](size_t bytes) -> char* {
        char* p = ws + off;
        off = (off + bytes + 255) & ~(size_t)255;
        return p;
    };
    unsigned short* out0   = (unsigned short*)alloc((size_t)nN * 128 * 2); // reused as z2
    unsigned char*  out0f8 = (unsigned char*)alloc((size_t)nN * 128);
    unsigned short* mean1  = (unsigned short*)alloc((size_t)nN * 128 * 2); // reused as meanz2 (fp32 x64)
    unsigned short* out1   = (unsigned short*)alloc((size_t)nN * 128 * 2);
    float* mean0 = (float*)alloc((size_t)nN * 6 * 4);
    unsigned short* Wt1  = (unsigned short*)alloc((size_t)128 * 256 * 2);
    unsigned short* Wt2l = (unsigned short*)alloc((size_t)64 * 128 * 2);
    unsigned short* Wt2r = (unsigned short*)alloc((size_t)64 * 128 * 2);
    int* C      = (int*)alloc((size_t)PB * nbk * 4);
    int* tot    = (int*)alloc((size_t)nbk * 4);
    int* bstart = (int*)alloc(((size_t)nbk + 1) * 4);
    int* bsum   = (int*)alloc(4 * 4);
    int* offs   = (int*)alloc(((size_t)nN + 1) * 4);
    int* csr    = (int*)alloc((size_t)nE * 4);
    unsigned* ebuf = (unsigned*)alloc((size_t)nE * 4);

    unsigned short* z2     = out0;            // out0 dead after layer-1 GEMM
    float*          meanz2 = (float*)mean1;   // mean1 dead after layer-1 GEMM

    // weight prep: fragment-linear packing (independent of graph build)
    k_wtfrag<<<(128 * 256 / 8 + 255) / 256, 256, 0, stream>>>(Wl1, Wr1, Wt1, 128, 256, 128);
    k_wtfrag<<<(64 * 128 / 8 + 255) / 256, 256, 0, stream>>>(Wl2, Wl2, Wt2l, 128, 128, 64);
    k_wtfrag<<<(64 * 128 / 8 + 255) / 256, 256, 0, stream>>>(Wr2, Wr2, Wt2r, 128, 128, 64);

    // build dst-sorted CSR via bucket partition (no global atomics, dense writes)
    k_p1count<<<PB, 256, 0, stream>>>(dst, C, nE, nbk, epb);
    k_colscan<<<nbk, 256, 0, stream>>>(C, tot, nbk);
    k_scan_a<<<1, 256, 0, stream>>>(tot, bstart, bsum, nbk);
    k_scan_b<<<1, 256, 0, stream>>>(bstart, bsum, nbk, 1);
    k_p1fill<<<PB, 256, 0, stream>>>(src, dst, bstart, C, ebuf, nE, nbk, epb);
    k_p2fill<<<nbk, 256, 0, stream>>>(ebuf, bstart, offs, csr, nN, nE);

    // layer 0 (K=6) -> out0 (bf16) + out0f8 (fp8 gather table)
    k_agg0<<<(nN + 255) / 256, 256, 0, stream>>>(x, offs, csr, mean0, nN);
    k_l0<<<(nN + 1) / 2, 256, 0, stream>>>(x, mean0, Wl0, bl0, Wr0, out0, out0f8, nN);

    const int gemm_grid = (nN / 32 + 3) / 4 + 1;   // 4 waves/block, 32 rows/wave

    // layer 1: mean1 = agg(out0f8); out1 = relu([mean1|out0] @ W1 + bl1)
    k_agg128f8<<<((size_t)nN * 8 + 255) / 256, 256, 0, stream>>>(out0f8, offs, csr, mean1, nN);
    k_mfma<128, 128, 128, true, true, true, false><<<gemm_grid, 256, 0, stream>>>(
        mean1, out0, Wt1, bl1, nullptr, out1, nN);

    // layer 2 (reordered): z2 = out1@Wl2 (bf16); out = relu(out1@Wr2 + bl2 + agg(z2))
    k_mfma<128, 0, 64, false, true, false, false><<<gemm_grid, 256, 0, stream>>>(
        out1, nullptr, Wt2l, nullptr, nullptr, z2, nN);
    k_agg64<<<((size_t)nN * 8 + 255) / 256, 256, 0, stream>>>(z2, offs, csr, meanz2, nN);
    k_mfma<128, 0, 64, true, false, true, true><<<gemm_grid, 256, 0, stream>>>(
        out1, nullptr, Wt2r, bl2, meanz2, (float*)d_out, nN);
}

// Round 9
// 222.996 us; speedup vs baseline: 4.0220x; 1.0936x over previous
//
#include <hip/hip_runtime.h>

// ---------------------------------------------------------------------------
// GraphSAGE 3-layer forward.
//   h = x[:,4:10]; per layer: mean_agg(h) @ Wl + bl + h @ Wr, relu
// Round-9 changes:
//   - k_l0 restructured: 8 features/thread (was 1). m/h rows loaded once per
//     thread (3x float2 each), weights as L1-resident float4 pairs, outputs
//     packed into one uint4 bf16 store + one uint2 fp8 store.
//     (was: 52us for 38MB written -- instruction-issue bound, 12.8M threads
//     x 26 scalar loads; roofline ~8us)
// ---------------------------------------------------------------------------

typedef __attribute__((ext_vector_type(8))) short bf16x8;   // 8 bf16 = 4 VGPR
typedef __attribute__((ext_vector_type(4))) float f32x4;
typedef __attribute__((ext_vector_type(2))) float f32x2;

constexpr int PB = 256;   // partition pass blocks (== colscan threads, fixed)
constexpr float F8SCALE = 32.0f;

static __device__ __forceinline__ int imax(int a, int b) { return a > b ? a : b; }

static __device__ __forceinline__ float bfbits_lo(unsigned u) {
    union { unsigned i; float f; } v; v.i = u << 16; return v.f;
}
static __device__ __forceinline__ float bfbits_hi(unsigned u) {
    union { unsigned i; float f; } v; v.i = u & 0xffff0000u; return v.f;
}
static __device__ __forceinline__ unsigned short f2bf(float f) {
    unsigned u = __float_as_uint(f);
    u = (u + 0x7fffu + ((u >> 16) & 1u)) >> 16;
    return (unsigned short)u;
}
static __device__ __forceinline__ unsigned pack2bf(float a, float b) {
    return (unsigned)f2bf(a) | ((unsigned)f2bf(b) << 16);
}
// accumulate 4 fp8-e4m3 bytes (one dword) into a[0..3]
static __device__ __forceinline__ void acc_f8x4(unsigned u, float* a) {
    f32x2 lo = __builtin_amdgcn_cvt_pk_f32_fp8((int)u, false);
    f32x2 hi = __builtin_amdgcn_cvt_pk_f32_fp8((int)u, true);
    a[0] += lo[0]; a[1] += lo[1]; a[2] += hi[0]; a[3] += hi[1];
}

// ---- graph build: bucket partition + per-bucket counting sort ---------------

__global__ __launch_bounds__(256) void k_p1count(const int* __restrict__ dst,
                                                 int* __restrict__ C,
                                                 int nE, int nbk, int epb) {
    __shared__ int h[512];
    for (int i = threadIdx.x; i < nbk; i += 256) h[i] = 0;
    __syncthreads();
    int e0 = blockIdx.x * epb;
    int e1 = min(e0 + epb, nE);
    for (int i = e0 + threadIdx.x; i < e1; i += 256)
        atomicAdd(&h[dst[i] >> 8], 1);
    __syncthreads();
    for (int i = threadIdx.x; i < nbk; i += 256)
        C[blockIdx.x * nbk + i] = h[i];
}

__global__ __launch_bounds__(256) void k_colscan(int* __restrict__ C,
                                                 int* __restrict__ tot, int nbk) {
    __shared__ int sm[256];
    int k = blockIdx.x, t = threadIdx.x;
    int v = C[t * nbk + k];
    sm[t] = v;
    __syncthreads();
    for (int o = 1; o < 256; o <<= 1) {
        int u = (t >= o) ? sm[t - o] : 0;
        __syncthreads();
        sm[t] += u;
        __syncthreads();
    }
    C[t * nbk + k] = sm[t] - v;
    if (t == 255) tot[k] = sm[255];
}

__global__ __launch_bounds__(256) void k_scan_a(const int* __restrict__ cnt,
                                                int* __restrict__ offs,
                                                int* __restrict__ bsum, int n) {
    __shared__ int sm[256];
    int t = threadIdx.x;
    int base = blockIdx.x * 1024 + t * 4;
    int v0 = 0, v1 = 0, v2 = 0, v3 = 0;
    if (base + 3 < n) {
        int4 q = *(const int4*)(cnt + base);
        v0 = q.x; v1 = q.y; v2 = q.z; v3 = q.w;
    } else {
        if (base < n)     v0 = cnt[base];
        if (base + 1 < n) v1 = cnt[base + 1];
        if (base + 2 < n) v2 = cnt[base + 2];
    }
    int s = v0 + v1 + v2 + v3;
    sm[t] = s;
    __syncthreads();
    for (int o = 1; o < 256; o <<= 1) {
        int u = (t >= o) ? sm[t - o] : 0;
        __syncthreads();
        sm[t] += u;
        __syncthreads();
    }
    int excl = sm[t] - s;
    if (base < n)     offs[base]     = excl;
    if (base + 1 < n) offs[base + 1] = excl + v0;
    if (base + 2 < n) offs[base + 2] = excl + v0 + v1;
    if (base + 3 < n) offs[base + 3] = excl + v0 + v1 + v2;
    if (t == 255) bsum[blockIdx.x] = sm[255];
}

__global__ __launch_bounds__(256) void k_scan_b(int* __restrict__ offs,
                                                const int* __restrict__ bsum,
                                                int n, int nb) {
    __shared__ int pfx;
    int t = threadIdx.x, b = blockIdx.x;
    if (t == 0) {
        int s = 0;
        for (int i = 0; i < b; ++i) s += bsum[i];
        pfx = s;
        if (b == nb - 1) offs[n] = s + bsum[b];
    }
    __syncthreads();
    if (b == 0) return;
    int base = b * 1024 + t * 4;
    int p = pfx;
    if (base < n)     offs[base]     += p;
    if (base + 1 < n) offs[base + 1] += p;
    if (base + 2 < n) offs[base + 2] += p;
    if (base + 3 < n) offs[base + 3] += p;
}

__global__ __launch_bounds__(256) void k_p1fill(const int* __restrict__ src,
                                                const int* __restrict__ dst,
                                                const int* __restrict__ bstart,
                                                const int* __restrict__ C,
                                                unsigned* __restrict__ ebuf,
                                                int nE, int nbk, int epb) {
    __shared__ int cur[512];
    int b = blockIdx.x;
    for (int i = threadIdx.x; i < nbk; i += 256)
        cur[i] = bstart[i] + C[b * nbk + i];
    __syncthreads();
    int e0 = b * epb;
    int e1 = min(e0 + epb, nE);
    for (int i = e0 + threadIdx.x; i < e1; i += 256) {
        int d = dst[i];
        unsigned s = (unsigned)src[i];
        int p = atomicAdd(&cur[d >> 8], 1);
        ebuf[p] = (s << 8) | (unsigned)(d & 255);
    }
}

__global__ __launch_bounds__(256) void k_p2fill(const unsigned* __restrict__ ebuf,
                                                const int* __restrict__ bstart,
                                                int* __restrict__ offs,
                                                int* __restrict__ csr,
                                                int nN, int nE) {
    __shared__ int h[256], sm[256], cur[256];
    int k = blockIdx.x, t = threadIdx.x;
    int base = bstart[k], end = bstart[k + 1];
    h[t] = 0;
    __syncthreads();
    for (int i = base + t; i < end; i += 256)
        atomicAdd(&h[ebuf[i] & 255u], 1);
    __syncthreads();
    int v = h[t];
    sm[t] = v;
    __syncthreads();
    for (int o = 1; o < 256; o <<= 1) {
        int u = (t >= o) ? sm[t - o] : 0;
        __syncthreads();
        sm[t] += u;
        __syncthreads();
    }
    int excl = sm[t] - v;
    int node = (k << 8) + t;
    if (node < nN) offs[node] = base + excl;
    cur[t] = base + excl;
    if (k == 0 && t == 0) offs[nN] = nE;
    __syncthreads();
    for (int i = base + t; i < end; i += 256) {
        unsigned e = ebuf[i];
        int p = atomicAdd(&cur[e & 255u], 1);
        csr[p] = (int)(e >> 8);
    }
}

// ---- weight prep: fragment-linear packing -----------------------------------

__global__ __launch_bounds__(256) void k_wtfrag(const float* __restrict__ W1,
                                                const float* __restrict__ W2,
                                                unsigned short* __restrict__ Wt,
                                                int K1, int K, int N) {
    int c = blockIdx.x * 256 + threadIdx.x;
    int NB = N >> 4;
    int nch = (N * K) >> 3;
    if (c >= nch) return;
    int lane = c & 63;
    int n = (c >> 6) % NB;
    int ks = c / (NB << 6);
    int row = n * 16 + (lane & 15);
    int col = ks * 32 + (lane >> 4) * 8;
    unsigned short o[8];
#pragma unroll
    for (int j = 0; j < 8; ++j) {
        int k = col + j;
        float v = (k < K1) ? W1[k * N + row] : W2[(k - K1) * N + row];
        o[j] = f2bf(v);
    }
    *(uint4*)(Wt + (size_t)c * 8) = *(const uint4*)o;
}

// ---- aggregation -----------------------------------------------------------

// 6-dim mean of x[:,4:10]; one thread per node, 4x-unrolled edges
__global__ __launch_bounds__(256) void k_agg0(const float* __restrict__ x,
                                              const int* __restrict__ offs,
                                              const int* __restrict__ csr,
                                              float* __restrict__ mean0, int nN) {
    int i = blockIdx.x * blockDim.x + threadIdx.x;
    if (i >= nN) return;
    int lo = offs[i], hi = offs[i + 1];
    float a0 = 0, a1 = 0, a2 = 0, a3 = 0, a4 = 0, a5 = 0;
    int e = lo;
    for (; e + 4 <= hi; e += 4) {
        int s0 = csr[e], s1 = csr[e + 1], s2 = csr[e + 2], s3 = csr[e + 3];
        const float* r0 = x + (size_t)s0 * 10 + 4;
        const float* r1 = x + (size_t)s1 * 10 + 4;
        const float* r2 = x + (size_t)s2 * 10 + 4;
        const float* r3 = x + (size_t)s3 * 10 + 4;
        float2 u0 = *(const float2*)(r0), u1 = *(const float2*)(r0 + 2), u2 = *(const float2*)(r0 + 4);
        float2 w0 = *(const float2*)(r1), w1 = *(const float2*)(r1 + 2), w2 = *(const float2*)(r1 + 4);
        float2 p0 = *(const float2*)(r2), p1 = *(const float2*)(r2 + 2), p2 = *(const float2*)(r2 + 4);
        float2 q0 = *(const float2*)(r3), q1 = *(const float2*)(r3 + 2), q2 = *(const float2*)(r3 + 4);
        a0 += u0.x + w0.x + p0.x + q0.x;
        a1 += u0.y + w0.y + p0.y + q0.y;
        a2 += u1.x + w1.x + p1.x + q1.x;
        a3 += u1.y + w1.y + p1.y + q1.y;
        a4 += u2.x + w2.x + p2.x + q2.x;
        a5 += u2.y + w2.y + p2.y + q2.y;
    }
    for (; e < hi; ++e) {
        int s = csr[e];
        const float* r = x + (size_t)s * 10 + 4;
        float2 v0 = *(const float2*)(r);
        float2 v1 = *(const float2*)(r + 2);
        float2 v2 = *(const float2*)(r + 4);
        a0 += v0.x; a1 += v0.y; a2 += v1.x; a3 += v1.y; a4 += v2.x; a5 += v2.y;
    }
    float inv = 1.0f / (float)imax(hi - lo, 1);
    float* o = mean0 + (size_t)i * 6;
    o[0] = a0 * inv; o[1] = a1 * inv; o[2] = a2 * inv;
    o[3] = a3 * inv; o[4] = a4 * inv; o[5] = a5 * inv;
}

// 128-dim fp8 mean -> bf16: thread per (node, 16B = 16-feature chunk),
// 4x-unrolled edges. Table values pre-scaled by F8SCALE.
__global__ __launch_bounds__(256) void k_agg128f8(const unsigned char* __restrict__ X,
                                                  const int* __restrict__ offs,
                                                  const int* __restrict__ csr,
                                                  unsigned short* __restrict__ M, int nN) {
    int idx = blockIdx.x * 256 + threadIdx.x;
    int node = idx >> 3;
    int fl = idx & 7;             // features fl*16 .. fl*16+15
    if (node >= nN) return;
    int lo = offs[node], hi = offs[node + 1];
    float a[16];
#pragma unroll
    for (int j = 0; j < 16; ++j) a[j] = 0.f;
    int e = lo;
    for (; e + 4 <= hi; e += 4) {
        int s0 = csr[e], s1 = csr[e + 1], s2 = csr[e + 2], s3 = csr[e + 3];
        uint4 v0 = *(const uint4*)(X + (size_t)s0 * 128 + fl * 16);
        uint4 v1 = *(const uint4*)(X + (size_t)s1 * 128 + fl * 16);
        uint4 v2 = *(const uint4*)(X + (size_t)s2 * 128 + fl * 16);
        uint4 v3 = *(const uint4*)(X + (size_t)s3 * 128 + fl * 16);
        acc_f8x4(v0.x, a + 0);  acc_f8x4(v0.y, a + 4);
        acc_f8x4(v0.z, a + 8);  acc_f8x4(v0.w, a + 12);
        acc_f8x4(v1.x, a + 0);  acc_f8x4(v1.y, a + 4);
        acc_f8x4(v1.z, a + 8);  acc_f8x4(v1.w, a + 12);
        acc_f8x4(v2.x, a + 0);  acc_f8x4(v2.y, a + 4);
        acc_f8x4(v2.z, a + 8);  acc_f8x4(v2.w, a + 12);
        acc_f8x4(v3.x, a + 0);  acc_f8x4(v3.y, a + 4);
        acc_f8x4(v3.z, a + 8);  acc_f8x4(v3.w, a + 12);
    }
    for (; e < hi; ++e) {
        int s = csr[e];
        uint4 v = *(const uint4*)(X + (size_t)s * 128 + fl * 16);
        acc_f8x4(v.x, a + 0);  acc_f8x4(v.y, a + 4);
        acc_f8x4(v.z, a + 8);  acc_f8x4(v.w, a + 12);
    }
    float inv = 1.0f / (F8SCALE * (float)imax(hi - lo, 1));
    unsigned o[8];
#pragma unroll
    for (int j = 0; j < 8; ++j) o[j] = pack2bf(a[2 * j] * inv, a[2 * j + 1] * inv);
    unsigned short* mp = M + (size_t)node * 128 + fl * 16;
    *(uint4*)(mp)     = *(const uint4*)(o);
    *(uint4*)(mp + 8) = *(const uint4*)(o + 4);
}

// 64-dim bf16 mean -> fp32: thread per (node, 16B chunk), 4x-unrolled edges.
__global__ __launch_bounds__(256) void k_agg64(const unsigned short* __restrict__ X,
                                               const int* __restrict__ offs,
                                               const int* __restrict__ csr,
                                               float* __restrict__ M, int nN) {
    int idx = blockIdx.x * 256 + threadIdx.x;
    int node = idx >> 3;
    int fl = idx & 7;             // features fl*8 .. fl*8+7
    if (node >= nN) return;
    int lo = offs[node], hi = offs[node + 1];
    float a0 = 0, a1 = 0, a2 = 0, a3 = 0, a4 = 0, a5 = 0, a6 = 0, a7 = 0;
    int e = lo;
    for (; e + 4 <= hi; e += 4) {
        int s0 = csr[e], s1 = csr[e + 1], s2 = csr[e + 2], s3 = csr[e + 3];
        uint4 v0 = *(const uint4*)(X + (size_t)s0 * 64 + fl * 8);
        uint4 v1 = *(const uint4*)(X + (size_t)s1 * 64 + fl * 8);
        uint4 v2 = *(const uint4*)(X + (size_t)s2 * 64 + fl * 8);
        uint4 v3 = *(const uint4*)(X + (size_t)s3 * 64 + fl * 8);
        a0 += bfbits_lo(v0.x); a1 += bfbits_hi(v0.x);
        a2 += bfbits_lo(v0.y); a3 += bfbits_hi(v0.y);
        a4 += bfbits_lo(v0.z); a5 += bfbits_hi(v0.z);
        a6 += bfbits_lo(v0.w); a7 += bfbits_hi(v0.w);
        a0 += bfbits_lo(v1.x); a1 += bfbits_hi(v1.x);
        a2 += bfbits_lo(v1.y); a3 += bfbits_hi(v1.y);
        a4 += bfbits_lo(v1.z); a5 += bfbits_hi(v1.z);
        a6 += bfbits_lo(v1.w); a7 += bfbits_hi(v1.w);
        a0 += bfbits_lo(v2.x); a1 += bfbits_hi(v2.x);
        a2 += bfbits_lo(v2.y); a3 += bfbits_hi(v2.y);
        a4 += bfbits_lo(v2.z); a5 += bfbits_hi(v2.z);
        a6 += bfbits_lo(v2.w); a7 += bfbits_hi(v2.w);
        a0 += bfbits_lo(v3.x); a1 += bfbits_hi(v3.x);
        a2 += bfbits_lo(v3.y); a3 += bfbits_hi(v3.y);
        a4 += bfbits_lo(v3.z); a5 += bfbits_hi(v3.z);
        a6 += bfbits_lo(v3.w); a7 += bfbits_hi(v3.w);
    }
    for (; e < hi; ++e) {
        int s = csr[e];
        uint4 v = *(const uint4*)(X + (size_t)s * 64 + fl * 8);
        a0 += bfbits_lo(v.x); a1 += bfbits_hi(v.x);
        a2 += bfbits_lo(v.y); a3 += bfbits_hi(v.y);
        a4 += bfbits_lo(v.z); a5 += bfbits_hi(v.z);
        a6 += bfbits_lo(v.w); a7 += bfbits_hi(v.w);
    }
    float inv = 1.0f / (float)imax(hi - lo, 1);
    float* o = M + (size_t)node * 64 + fl * 8;
    *(float4*)(o)     = make_float4(a0 * inv, a1 * inv, a2 * inv, a3 * inv);
    *(float4*)(o + 4) = make_float4(a4 * inv, a5 * inv, a6 * inv, a7 * inv);
}

// ---- layer 0 (K=6): 8 features per thread, 16 threads per node --------------
// writes bf16 (GEMM A-operand) and fp8-e4m3 x F8SCALE (gather table)

__global__ __launch_bounds__(256) void k_l0(const float* __restrict__ x,
                                            const float* __restrict__ mean0,
                                            const float* __restrict__ Wl,
                                            const float* __restrict__ bl,
                                            const float* __restrict__ Wr,
                                            unsigned short* __restrict__ out,
                                            unsigned char* __restrict__ out8, int nN) {
    int idx = blockIdx.x * 256 + threadIdx.x;
    int node = idx >> 4;
    int j0 = (idx & 15) * 8;
    if (node >= nN) return;
    const float* mp = mean0 + (size_t)node * 6;
    float2 m01 = *(const float2*)mp, m23 = *(const float2*)(mp + 2), m45 = *(const float2*)(mp + 4);
    const float* hp = x + (size_t)node * 10 + 4;
    float2 h01 = *(const float2*)hp, h23 = *(const float2*)(hp + 2), h45 = *(const float2*)(hp + 4);
    float m[6] = {m01.x, m01.y, m23.x, m23.y, m45.x, m45.y};
    float h[6] = {h01.x, h01.y, h23.x, h23.y, h45.x, h45.y};
    float4 b0 = *(const float4*)(bl + j0);
    float4 b1 = *(const float4*)(bl + j0 + 4);
    float v[8] = {b0.x, b0.y, b0.z, b0.w, b1.x, b1.y, b1.z, b1.w};
#pragma unroll
    for (int k = 0; k < 6; ++k) {
        float4 w0 = *(const float4*)(Wl + k * 128 + j0);
        float4 w1 = *(const float4*)(Wl + k * 128 + j0 + 4);
        v[0] = fmaf(m[k], w0.x, v[0]); v[1] = fmaf(m[k], w0.y, v[1]);
        v[2] = fmaf(m[k], w0.z, v[2]); v[3] = fmaf(m[k], w0.w, v[3]);
        v[4] = fmaf(m[k], w1.x, v[4]); v[5] = fmaf(m[k], w1.y, v[5]);
        v[6] = fmaf(m[k], w1.z, v[6]); v[7] = fmaf(m[k], w1.w, v[7]);
    }
#pragma unroll
    for (int k = 0; k < 6; ++k) {
        float4 w0 = *(const float4*)(Wr + k * 128 + j0);
        float4 w1 = *(const float4*)(Wr + k * 128 + j0 + 4);
        v[0] = fmaf(h[k], w0.x, v[0]); v[1] = fmaf(h[k], w0.y, v[1]);
        v[2] = fmaf(h[k], w0.z, v[2]); v[3] = fmaf(h[k], w0.w, v[3]);
        v[4] = fmaf(h[k], w1.x, v[4]); v[5] = fmaf(h[k], w1.y, v[5]);
        v[6] = fmaf(h[k], w1.z, v[6]); v[7] = fmaf(h[k], w1.w, v[7]);
    }
#pragma unroll
    for (int t = 0; t < 8; ++t) v[t] = fmaxf(v[t], 0.f);
    unsigned ob[4];
#pragma unroll
    for (int t = 0; t < 4; ++t) ob[t] = pack2bf(v[2 * t], v[2 * t + 1]);
    *(uint4*)(out + (size_t)node * 128 + j0) = *(const uint4*)ob;
    int d0 = __builtin_amdgcn_cvt_pk_fp8_f32(v[0] * F8SCALE, v[1] * F8SCALE, 0, false);
    d0     = __builtin_amdgcn_cvt_pk_fp8_f32(v[2] * F8SCALE, v[3] * F8SCALE, d0, true);
    int d1 = __builtin_amdgcn_cvt_pk_fp8_f32(v[4] * F8SCALE, v[5] * F8SCALE, 0, false);
    d1     = __builtin_amdgcn_cvt_pk_fp8_f32(v[6] * F8SCALE, v[7] * F8SCALE, d1, true);
    uint2 o8; o8.x = (unsigned)d0; o8.y = (unsigned)d1;
    *(uint2*)(out8 + (size_t)node * 128 + j0) = o8;
}

// ---- MFMA GEMM: C = act( [A0|A1] @ W^T (+bias) (+add) ) ---------------------
// Wt fragment-linear (k_wtfrag). Double-buffered register prefetch.

template <int KA, int KB, int N, bool RELU, bool BF16OUT, bool HASBIAS, bool HASADD>
__global__ __launch_bounds__(256) void k_mfma(const unsigned short* __restrict__ A0,
                                              const unsigned short* __restrict__ A1,
                                              const unsigned short* __restrict__ Wt,
                                              const float* __restrict__ bias,
                                              const float* __restrict__ add,
                                              void* __restrict__ Cout, int nN) {
    constexpr int K = KA + KB;
    constexpr int NSTEP = K / 32;
    constexpr int NB = N / 16;
    const int tid = threadIdx.x;
    const int wave = (blockIdx.x * 256 + tid) >> 6;
    const int m0 = wave * 32;
    if (m0 >= nN) return;
    const int lane = tid & 63;
    const int lr = lane & 15;
    const int lk = lane >> 4;

    f32x4 acc[2][NB];
#pragma unroll
    for (int g = 0; g < 2; ++g)
#pragma unroll
        for (int n = 0; n < NB; ++n) acc[g][n] = (f32x4){0.f, 0.f, 0.f, 0.f};

    auto loadA = [&](int kk, bf16x8& a0, bf16x8& a1) {
        const unsigned short* Ap;
        int lda, krel;
        if (KB > 0 && kk >= KA) { Ap = A1; lda = KB; krel = kk - KA; }
        else                    { Ap = A0; lda = KA; krel = kk; }
        a0 = *(const bf16x8*)(Ap + (size_t)(m0 + lr) * lda + krel + lk * 8);
        a1 = *(const bf16x8*)(Ap + (size_t)(m0 + 16 + lr) * lda + krel + lk * 8);
    };
    auto loadB = [&](int ks, bf16x8* b) {
        const unsigned short* Wk = Wt + (((size_t)ks * NB) << 6) * 8 + lane * 8;
#pragma unroll
        for (int n = 0; n < NB; ++n)
            b[n] = *(const bf16x8*)(Wk + ((size_t)n << 6) * 8);
    };

    bf16x8 a0c, a1c, a0n, a1n;
    bf16x8 bc[NB], bn[NB];
    loadA(0, a0c, a1c);
    loadB(0, bc);

#pragma unroll
    for (int ks = 0; ks < NSTEP; ++ks) {
        if (ks + 1 < NSTEP) {           // issue next step's loads FIRST
            loadA((ks + 1) * 32, a0n, a1n);
            loadB(ks + 1, bn);
        }
#pragma unroll
        for (int n = 0; n < NB; ++n) {
            acc[0][n] = __builtin_amdgcn_mfma_f32_16x16x32_bf16(a0c, bc[n], acc[0][n], 0, 0, 0);
            acc[1][n] = __builtin_amdgcn_mfma_f32_16x16x32_bf16(a1c, bc[n], acc[1][n], 0, 0, 0);
        }
        if (ks + 1 < NSTEP) {           // register rename (folds after unroll)
            a0c = a0n; a1c = a1n;
#pragma unroll
            for (int n = 0; n < NB; ++n) bc[n] = bn[n];
        }
    }

#pragma unroll
    for (int g = 0; g < 2; ++g) {
#pragma unroll
        for (int r = 0; r < 4; ++r) {
            int gm = m0 + g * 16 + lk * 4 + r;
#pragma unroll
            for (int n = 0; n < NB; ++n) {
                float v = acc[g][n][r];
                if (HASBIAS) v += bias[n * 16 + lr];
                if (HASADD)  v += add[(size_t)gm * N + n * 16 + lr];
                if (RELU)    v = fmaxf(v, 0.f);
                if (BF16OUT) ((unsigned short*)Cout)[(size_t)gm * N + n * 16 + lr] = f2bf(v);
                else         ((float*)Cout)[(size_t)gm * N + n * 16 + lr] = v;
            }
        }
    }
}

// ---------------------------------------------------------------------------

extern "C" void kernel_launch(void* const* d_in, const int* in_sizes, int n_in,
                              void* d_out, int out_size, void* d_ws, size_t ws_size,
                              hipStream_t stream) {
    const float* x   = (const float*)d_in[0];
    const int*   ei  = (const int*)d_in[1];
    const float* Wl0 = (const float*)d_in[2];
    const float* bl0 = (const float*)d_in[3];
    const float* Wr0 = (const float*)d_in[4];
    const float* Wl1 = (const float*)d_in[5];
    const float* bl1 = (const float*)d_in[6];
    const float* Wr1 = (const float*)d_in[7];
    const float* Wl2 = (const float*)d_in[8];
    const float* bl2 = (const float*)d_in[9];
    const float* Wr2 = (const float*)d_in[10];

    const int nN = in_sizes[0] / 10;
    const int nE = in_sizes[1] / 2;
    const int* src = ei;
    const int* dst = ei + nE;
    const int nbk = (nN + 255) >> 8;            // 391 buckets (<=512 for LDS)
    const int epb = (nE + PB - 1) / PB;         // edges per partition block

    char* ws = (char*)d_ws;
    size_t off = 0;
    auto alloc = [&](size_t bytes) -> char* {
        char* p = ws + off;
        off = (off + bytes + 255) & ~(size_t)255;
        return p;
    };
    unsigned short* out0   = (unsigned short*)alloc((size_t)nN * 128 * 2); // reused as z2
    unsigned char*  out0f8 = (unsigned char*)alloc((size_t)nN * 128);
    unsigned short* mean1  = (unsigned short*)alloc((size_t)nN * 128 * 2); // reused as meanz2 (fp32 x64)
    unsigned short* out1   = (unsigned short*)alloc((size_t)nN * 128 * 2);
    float* mean0 = (float*)alloc((size_t)nN * 6 * 4);
    unsigned short* Wt1  = (unsigned short*)alloc((size_t)128 * 256 * 2);
    unsigned short* Wt2l = (unsigned short*)alloc((size_t)64 * 128 * 2);
    unsigned short* Wt2r = (unsigned short*)alloc((size_t)64 * 128 * 2);
    int* C      = (int*)alloc((size_t)PB * nbk * 4);
    int* tot    = (int*)alloc((size_t)nbk * 4);
    int* bstart = (int*)alloc(((size_t)nbk + 1) * 4);
    int* bsum   = (int*)alloc(4 * 4);
    int* offs   = (int*)alloc(((size_t)nN + 1) * 4);
    int* csr    = (int*)alloc((size_t)nE * 4);
    unsigned* ebuf = (unsigned*)alloc((size_t)nE * 4);

    unsigned short* z2     = out0;            // out0 dead after layer-1 GEMM
    float*          meanz2 = (float*)mean1;   // mean1 dead after layer-1 GEMM

    // weight prep: fragment-linear packing (independent of graph build)
    k_wtfrag<<<(128 * 256 / 8 + 255) / 256, 256, 0, stream>>>(Wl1, Wr1, Wt1, 128, 256, 128);
    k_wtfrag<<<(64 * 128 / 8 + 255) / 256, 256, 0, stream>>>(Wl2, Wl2, Wt2l, 128, 128, 64);
    k_wtfrag<<<(64 * 128 / 8 + 255) / 256, 256, 0, stream>>>(Wr2, Wr2, Wt2r, 128, 128, 64);

    // build dst-sorted CSR via bucket partition (no global atomics, dense writes)
    k_p1count<<<PB, 256, 0, stream>>>(dst, C, nE, nbk, epb);
    k_colscan<<<nbk, 256, 0, stream>>>(C, tot, nbk);
    k_scan_a<<<1, 256, 0, stream>>>(tot, bstart, bsum, nbk);
    k_scan_b<<<1, 256, 0, stream>>>(bstart, bsum, nbk, 1);
    k_p1fill<<<PB, 256, 0, stream>>>(src, dst, bstart, C, ebuf, nE, nbk, epb);
    k_p2fill<<<nbk, 256, 0, stream>>>(ebuf, bstart, offs, csr, nN, nE);

    // layer 0 (K=6) -> out0 (bf16) + out0f8 (fp8 gather table)
    k_agg0<<<(nN + 255) / 256, 256, 0, stream>>>(x, offs, csr, mean0, nN);
    k_l0<<<((size_t)nN * 16 + 255) / 256, 256, 0, stream>>>(x, mean0, Wl0, bl0, Wr0, out0, out0f8, nN);

    const int gemm_grid = (nN / 32 + 3) / 4 + 1;   // 4 waves/block, 32 rows/wave

    // layer 1: mean1 = agg(out0f8); out1 = relu([mean1|out0] @ W1 + bl1)
    k_agg128f8<<<((size_t)nN * 8 + 255) / 256, 256, 0, stream>>>(out0f8, offs, csr, mean1, nN);
    k_mfma<128, 128, 128, true, true, true, false><<<gemm_grid, 256, 0, stream>>>(
        mean1, out0, Wt1, bl1, nullptr, out1, nN);

    // layer 2 (reordered): z2 = out1@Wl2 (bf16); out = relu(out1@Wr2 + bl2 + agg(z2))
    k_mfma<128, 0, 64, false, true, false, false><<<gemm_grid, 256, 0, stream>>>(
        out1, nullptr, Wt2l, nullptr, nullptr, z2, nN);
    k_agg64<<<((size_t)nN * 8 + 255) / 256, 256, 0, stream>>>(z2, offs, csr, meanz2, nN);
    k_mfma<128, 0, 64, true, false, true, true><<<gemm_grid, 256, 0, stream>>>(
        out1, nullptr, Wt2r, bl2, meanz2, (float*)d_out, nN);
}

// Round 10
// 220.955 us; speedup vs baseline: 4.0592x; 1.0092x over previous
//
#include <hip/hip_runtime.h>

// ---------------------------------------------------------------------------
// GraphSAGE 3-layer forward.
//   h = x[:,4:10]; per layer: mean_agg(h) @ Wl + bl + h @ Wr, relu
// Round-10 changes:
//   - agg128f8 / agg64: 8-edge unrolled main loop (8 independent uint4 loads
//     in flight per thread; was 4). Gathers were at ~6.8 TB/s L3 service,
//     MLP-limited not BW-limited.
//   - 3x k_wtfrag launches fused into one k_wtfrag_all.
//   - k_scan_b dropped (scan_a is single-block for the 391 bucket totals and
//     now writes the grand total itself).
// ---------------------------------------------------------------------------

typedef __attribute__((ext_vector_type(8))) short bf16x8;   // 8 bf16 = 4 VGPR
typedef __attribute__((ext_vector_type(4))) float f32x4;
typedef __attribute__((ext_vector_type(2))) float f32x2;

constexpr int PB = 256;   // partition pass blocks (== colscan threads, fixed)
constexpr float F8SCALE = 32.0f;

static __device__ __forceinline__ int imax(int a, int b) { return a > b ? a : b; }

static __device__ __forceinline__ float bfbits_lo(unsigned u) {
    union { unsigned i; float f; } v; v.i = u << 16; return v.f;
}
static __device__ __forceinline__ float bfbits_hi(unsigned u) {
    union { unsigned i; float f; } v; v.i = u & 0xffff0000u; return v.f;
}
static __device__ __forceinline__ unsigned short f2bf(float f) {
    unsigned u = __float_as_uint(f);
    u = (u + 0x7fffu + ((u >> 16) & 1u)) >> 16;
    return (unsigned short)u;
}
static __device__ __forceinline__ unsigned pack2bf(float a, float b) {
    return (unsigned)f2bf(a) | ((unsigned)f2bf(b) << 16);
}
// accumulate 4 fp8-e4m3 bytes (one dword) into a[0..3]
static __device__ __forceinline__ void acc_f8x4(unsigned u, float* a) {
    f32x2 lo = __builtin_amdgcn_cvt_pk_f32_fp8((int)u, false);
    f32x2 hi = __builtin_amdgcn_cvt_pk_f32_fp8((int)u, true);
    a[0] += lo[0]; a[1] += lo[1]; a[2] += hi[0]; a[3] += hi[1];
}
// accumulate a uint4 of bf16 pairs into a[0..7]
static __device__ __forceinline__ void acc_bf8(uint4 v, float* a) {
    a[0] += bfbits_lo(v.x); a[1] += bfbits_hi(v.x);
    a[2] += bfbits_lo(v.y); a[3] += bfbits_hi(v.y);
    a[4] += bfbits_lo(v.z); a[5] += bfbits_hi(v.z);
    a[6] += bfbits_lo(v.w); a[7] += bfbits_hi(v.w);
}

// ---- graph build: bucket partition + per-bucket counting sort ---------------

__global__ __launch_bounds__(256) void k_p1count(const int* __restrict__ dst,
                                                 int* __restrict__ C,
                                                 int nE, int nbk, int epb) {
    __shared__ int h[512];
    for (int i = threadIdx.x; i < nbk; i += 256) h[i] = 0;
    __syncthreads();
    int e0 = blockIdx.x * epb;
    int e1 = min(e0 + epb, nE);
    for (int i = e0 + threadIdx.x; i < e1; i += 256)
        atomicAdd(&h[dst[i] >> 8], 1);
    __syncthreads();
    for (int i = threadIdx.x; i < nbk; i += 256)
        C[blockIdx.x * nbk + i] = h[i];
}

__global__ __launch_bounds__(256) void k_colscan(int* __restrict__ C,
                                                 int* __restrict__ tot, int nbk) {
    __shared__ int sm[256];
    int k = blockIdx.x, t = threadIdx.x;
    int v = C[t * nbk + k];
    sm[t] = v;
    __syncthreads();
    for (int o = 1; o < 256; o <<= 1) {
        int u = (t >= o) ? sm[t - o] : 0;
        __syncthreads();
        sm[t] += u;
        __syncthreads();
    }
    C[t * nbk + k] = sm[t] - v;
    if (t == 255) tot[k] = sm[255];
}

// single-block exclusive scan (n <= 1024); writes grand total at offs[n]
__global__ __launch_bounds__(256) void k_scan_a(const int* __restrict__ cnt,
                                                int* __restrict__ offs, int n) {
    __shared__ int sm[256];
    int t = threadIdx.x;
    int base = t * 4;
    int v0 = 0, v1 = 0, v2 = 0, v3 = 0;
    if (base + 3 < n) {
        int4 q = *(const int4*)(cnt + base);
        v0 = q.x; v1 = q.y; v2 = q.z; v3 = q.w;
    } else {
        if (base < n)     v0 = cnt[base];
        if (base + 1 < n) v1 = cnt[base + 1];
        if (base + 2 < n) v2 = cnt[base + 2];
    }
    int s = v0 + v1 + v2 + v3;
    sm[t] = s;
    __syncthreads();
    for (int o = 1; o < 256; o <<= 1) {
        int u = (t >= o) ? sm[t - o] : 0;
        __syncthreads();
        sm[t] += u;
        __syncthreads();
    }
    int excl = sm[t] - s;
    if (base < n)     offs[base]     = excl;
    if (base + 1 < n) offs[base + 1] = excl + v0;
    if (base + 2 < n) offs[base + 2] = excl + v0 + v1;
    if (base + 3 < n) offs[base + 3] = excl + v0 + v1 + v2;
    if (t == 255) offs[n] = sm[255];
}

__global__ __launch_bounds__(256) void k_p1fill(const int* __restrict__ src,
                                                const int* __restrict__ dst,
                                                const int* __restrict__ bstart,
                                                const int* __restrict__ C,
                                                unsigned* __restrict__ ebuf,
                                                int nE, int nbk, int epb) {
    __shared__ int cur[512];
    int b = blockIdx.x;
    for (int i = threadIdx.x; i < nbk; i += 256)
        cur[i] = bstart[i] + C[b * nbk + i];
    __syncthreads();
    int e0 = b * epb;
    int e1 = min(e0 + epb, nE);
    for (int i = e0 + threadIdx.x; i < e1; i += 256) {
        int d = dst[i];
        unsigned s = (unsigned)src[i];
        int p = atomicAdd(&cur[d >> 8], 1);
        ebuf[p] = (s << 8) | (unsigned)(d & 255);
    }
}

__global__ __launch_bounds__(256) void k_p2fill(const unsigned* __restrict__ ebuf,
                                                const int* __restrict__ bstart,
                                                int* __restrict__ offs,
                                                int* __restrict__ csr,
                                                int nN, int nE) {
    __shared__ int h[256], sm[256], cur[256];
    int k = blockIdx.x, t = threadIdx.x;
    int base = bstart[k], end = bstart[k + 1];
    h[t] = 0;
    __syncthreads();
    for (int i = base + t; i < end; i += 256)
        atomicAdd(&h[ebuf[i] & 255u], 1);
    __syncthreads();
    int v = h[t];
    sm[t] = v;
    __syncthreads();
    for (int o = 1; o < 256; o <<= 1) {
        int u = (t >= o) ? sm[t - o] : 0;
        __syncthreads();
        sm[t] += u;
        __syncthreads();
    }
    int excl = sm[t] - v;
    int node = (k << 8) + t;
    if (node < nN) offs[node] = base + excl;
    cur[t] = base + excl;
    if (k == 0 && t == 0) offs[nN] = nE;
    __syncthreads();
    for (int i = base + t; i < end; i += 256) {
        unsigned e = ebuf[i];
        int p = atomicAdd(&cur[e & 255u], 1);
        csr[p] = (int)(e >> 8);
    }
}

// ---- weight prep: fragment-linear packing, all three buffers in one launch --

static __device__ __forceinline__ void wtfrag_one(const float* __restrict__ W1,
                                                  const float* __restrict__ W2,
                                                  unsigned short* __restrict__ Wt,
                                                  int K1, int K, int N, int c) {
    int NB = N >> 4;
    int lane = c & 63;
    int n = (c >> 6) % NB;
    int ks = c / (NB << 6);
    int row = n * 16 + (lane & 15);
    int col = ks * 32 + (lane >> 4) * 8;
    unsigned short o[8];
#pragma unroll
    for (int j = 0; j < 8; ++j) {
        int k = col + j;
        float v = (k < K1) ? W1[k * N + row] : W2[(k - K1) * N + row];
        o[j] = f2bf(v);
    }
    *(uint4*)(Wt + (size_t)c * 8) = *(const uint4*)o;
}

// chunks: [0,4096) Wt1; [4096,5120) Wt2l; [5120,6144) Wt2r
__global__ __launch_bounds__(256) void k_wtfrag_all(const float* __restrict__ Wl1,
                                                    const float* __restrict__ Wr1,
                                                    const float* __restrict__ Wl2,
                                                    const float* __restrict__ Wr2,
                                                    unsigned short* __restrict__ Wt1,
                                                    unsigned short* __restrict__ Wt2l,
                                                    unsigned short* __restrict__ Wt2r) {
    int c = blockIdx.x * 256 + threadIdx.x;
    if (c < 4096)      wtfrag_one(Wl1, Wr1, Wt1, 128, 256, 128, c);
    else if (c < 5120) wtfrag_one(Wl2, Wl2, Wt2l, 128, 128, 64, c - 4096);
    else if (c < 6144) wtfrag_one(Wr2, Wr2, Wt2r, 128, 128, 64, c - 5120);
}

// ---- aggregation -----------------------------------------------------------

// 6-dim mean of x[:,4:10]; one thread per node, 4x-unrolled edges
__global__ __launch_bounds__(256) void k_agg0(const float* __restrict__ x,
                                              const int* __restrict__ offs,
                                              const int* __restrict__ csr,
                                              float* __restrict__ mean0, int nN) {
    int i = blockIdx.x * blockDim.x + threadIdx.x;
    if (i >= nN) return;
    int lo = offs[i], hi = offs[i + 1];
    float a0 = 0, a1 = 0, a2 = 0, a3 = 0, a4 = 0, a5 = 0;
    int e = lo;
    for (; e + 4 <= hi; e += 4) {
        int s0 = csr[e], s1 = csr[e + 1], s2 = csr[e + 2], s3 = csr[e + 3];
        const float* r0 = x + (size_t)s0 * 10 + 4;
        const float* r1 = x + (size_t)s1 * 10 + 4;
        const float* r2 = x + (size_t)s2 * 10 + 4;
        const float* r3 = x + (size_t)s3 * 10 + 4;
        float2 u0 = *(const float2*)(r0), u1 = *(const float2*)(r0 + 2), u2 = *(const float2*)(r0 + 4);
        float2 w0 = *(const float2*)(r1), w1 = *(const float2*)(r1 + 2), w2 = *(const float2*)(r1 + 4);
        float2 p0 = *(const float2*)(r2), p1 = *(const float2*)(r2 + 2), p2 = *(const float2*)(r2 + 4);
        float2 q0 = *(const float2*)(r3), q1 = *(const float2*)(r3 + 2), q2 = *(const float2*)(r3 + 4);
        a0 += u0.x + w0.x + p0.x + q0.x;
        a1 += u0.y + w0.y + p0.y + q0.y;
        a2 += u1.x + w1.x + p1.x + q1.x;
        a3 += u1.y + w1.y + p1.y + q1.y;
        a4 += u2.x + w2.x + p2.x + q2.x;
        a5 += u2.y + w2.y + p2.y + q2.y;
    }
    for (; e < hi; ++e) {
        int s = csr[e];
        const float* r = x + (size_t)s * 10 + 4;
        float2 v0 = *(const float2*)(r);
        float2 v1 = *(const float2*)(r + 2);
        float2 v2 = *(const float2*)(r + 4);
        a0 += v0.x; a1 += v0.y; a2 += v1.x; a3 += v1.y; a4 += v2.x; a5 += v2.y;
    }
    float inv = 1.0f / (float)imax(hi - lo, 1);
    float* o = mean0 + (size_t)i * 6;
    o[0] = a0 * inv; o[1] = a1 * inv; o[2] = a2 * inv;
    o[3] = a3 * inv; o[4] = a4 * inv; o[5] = a5 * inv;
}

// 128-dim fp8 mean -> bf16: thread per (node, 16B = 16-feature chunk),
// 8x-unrolled edges (8 independent uint4 loads in flight).
__global__ __launch_bounds__(256) void k_agg128f8(const unsigned char* __restrict__ X,
                                                  const int* __restrict__ offs,
                                                  const int* __restrict__ csr,
                                                  unsigned short* __restrict__ M, int nN) {
    int idx = blockIdx.x * 256 + threadIdx.x;
    int node = idx >> 3;
    int fl = idx & 7;             // features fl*16 .. fl*16+15
    if (node >= nN) return;
    int lo = offs[node], hi = offs[node + 1];
    float a[16];
#pragma unroll
    for (int j = 0; j < 16; ++j) a[j] = 0.f;
    int e = lo;
    for (; e + 8 <= hi; e += 8) {
        uint4 v0 = *(const uint4*)(X + (size_t)csr[e + 0] * 128 + fl * 16);
        uint4 v1 = *(const uint4*)(X + (size_t)csr[e + 1] * 128 + fl * 16);
        uint4 v2 = *(const uint4*)(X + (size_t)csr[e + 2] * 128 + fl * 16);
        uint4 v3 = *(const uint4*)(X + (size_t)csr[e + 3] * 128 + fl * 16);
        uint4 v4 = *(const uint4*)(X + (size_t)csr[e + 4] * 128 + fl * 16);
        uint4 v5 = *(const uint4*)(X + (size_t)csr[e + 5] * 128 + fl * 16);
        uint4 v6 = *(const uint4*)(X + (size_t)csr[e + 6] * 128 + fl * 16);
        uint4 v7 = *(const uint4*)(X + (size_t)csr[e + 7] * 128 + fl * 16);
        acc_f8x4(v0.x, a + 0); acc_f8x4(v0.y, a + 4); acc_f8x4(v0.z, a + 8); acc_f8x4(v0.w, a + 12);
        acc_f8x4(v1.x, a + 0); acc_f8x4(v1.y, a + 4); acc_f8x4(v1.z, a + 8); acc_f8x4(v1.w, a + 12);
        acc_f8x4(v2.x, a + 0); acc_f8x4(v2.y, a + 4); acc_f8x4(v2.z, a + 8); acc_f8x4(v2.w, a + 12);
        acc_f8x4(v3.x, a + 0); acc_f8x4(v3.y, a + 4); acc_f8x4(v3.z, a + 8); acc_f8x4(v3.w, a + 12);
        acc_f8x4(v4.x, a + 0); acc_f8x4(v4.y, a + 4); acc_f8x4(v4.z, a + 8); acc_f8x4(v4.w, a + 12);
        acc_f8x4(v5.x, a + 0); acc_f8x4(v5.y, a + 4); acc_f8x4(v5.z, a + 8); acc_f8x4(v5.w, a + 12);
        acc_f8x4(v6.x, a + 0); acc_f8x4(v6.y, a + 4); acc_f8x4(v6.z, a + 8); acc_f8x4(v6.w, a + 12);
        acc_f8x4(v7.x, a + 0); acc_f8x4(v7.y, a + 4); acc_f8x4(v7.z, a + 8); acc_f8x4(v7.w, a + 12);
    }
    for (; e + 4 <= hi; e += 4) {
        uint4 v0 = *(const uint4*)(X + (size_t)csr[e + 0] * 128 + fl * 16);
        uint4 v1 = *(const uint4*)(X + (size_t)csr[e + 1] * 128 + fl * 16);
        uint4 v2 = *(const uint4*)(X + (size_t)csr[e + 2] * 128 + fl * 16);
        uint4 v3 = *(const uint4*)(X + (size_t)csr[e + 3] * 128 + fl * 16);
        acc_f8x4(v0.x, a + 0); acc_f8x4(v0.y, a + 4); acc_f8x4(v0.z, a + 8); acc_f8x4(v0.w, a + 12);
        acc_f8x4(v1.x, a + 0); acc_f8x4(v1.y, a + 4); acc_f8x4(v1.z, a + 8); acc_f8x4(v1.w, a + 12);
        acc_f8x4(v2.x, a + 0); acc_f8x4(v2.y, a + 4); acc_f8x4(v2.z, a + 8); acc_f8x4(v2.w, a + 12);
        acc_f8x4(v3.x, a + 0); acc_f8x4(v3.y, a + 4); acc_f8x4(v3.z, a + 8); acc_f8x4(v3.w, a + 12);
    }
    for (; e < hi; ++e) {
        uint4 v = *(const uint4*)(X + (size_t)csr[e] * 128 + fl * 16);
        acc_f8x4(v.x, a + 0); acc_f8x4(v.y, a + 4); acc_f8x4(v.z, a + 8); acc_f8x4(v.w, a + 12);
    }
    float inv = 1.0f / (F8SCALE * (float)imax(hi - lo, 1));
    unsigned o[8];
#pragma unroll
    for (int j = 0; j < 8; ++j) o[j] = pack2bf(a[2 * j] * inv, a[2 * j + 1] * inv);
    unsigned short* mp = M + (size_t)node * 128 + fl * 16;
    *(uint4*)(mp)     = *(const uint4*)(o);
    *(uint4*)(mp + 8) = *(const uint4*)(o + 4);
}

// 64-dim bf16 mean -> fp32: thread per (node, 16B chunk), 8x-unrolled edges.
__global__ __launch_bounds__(256) void k_agg64(const unsigned short* __restrict__ X,
                                               const int* __restrict__ offs,
                                               const int* __restrict__ csr,
                                               float* __restrict__ M, int nN) {
    int idx = blockIdx.x * 256 + threadIdx.x;
    int node = idx >> 3;
    int fl = idx & 7;             // features fl*8 .. fl*8+7
    if (node >= nN) return;
    int lo = offs[node], hi = offs[node + 1];
    float a[8] = {0, 0, 0, 0, 0, 0, 0, 0};
    int e = lo;
    for (; e + 8 <= hi; e += 8) {
        uint4 v0 = *(const uint4*)(X + (size_t)csr[e + 0] * 64 + fl * 8);
        uint4 v1 = *(const uint4*)(X + (size_t)csr[e + 1] * 64 + fl * 8);
        uint4 v2 = *(const uint4*)(X + (size_t)csr[e + 2] * 64 + fl * 8);
        uint4 v3 = *(const uint4*)(X + (size_t)csr[e + 3] * 64 + fl * 8);
        uint4 v4 = *(const uint4*)(X + (size_t)csr[e + 4] * 64 + fl * 8);
        uint4 v5 = *(const uint4*)(X + (size_t)csr[e + 5] * 64 + fl * 8);
        uint4 v6 = *(const uint4*)(X + (size_t)csr[e + 6] * 64 + fl * 8);
        uint4 v7 = *(const uint4*)(X + (size_t)csr[e + 7] * 64 + fl * 8);
        acc_bf8(v0, a); acc_bf8(v1, a); acc_bf8(v2, a); acc_bf8(v3, a);
        acc_bf8(v4, a); acc_bf8(v5, a); acc_bf8(v6, a); acc_bf8(v7, a);
    }
    for (; e + 4 <= hi; e += 4) {
        uint4 v0 = *(const uint4*)(X + (size_t)csr[e + 0] * 64 + fl * 8);
        uint4 v1 = *(const uint4*)(X + (size_t)csr[e + 1] * 64 + fl * 8);
        uint4 v2 = *(const uint4*)(X + (size_t)csr[e + 2] * 64 + fl * 8);
        uint4 v3 = *(const uint4*)(X + (size_t)csr[e + 3] * 64 + fl * 8);
        acc_bf8(v0, a); acc_bf8(v1, a); acc_bf8(v2, a); acc_bf8(v3, a);
    }
    for (; e < hi; ++e) {
        uint4 v = *(const uint4*)(X + (size_t)csr[e] * 64 + fl * 8);
        acc_bf8(v, a);
    }
    float inv = 1.0f / (float)imax(hi - lo, 1);
    float* o = M + (size_t)node * 64 + fl * 8;
    *(float4*)(o)     = make_float4(a[0] * inv, a[1] * inv, a[2] * inv, a[3] * inv);
    *(float4*)(o + 4) = make_float4(a[4] * inv, a[5] * inv, a[6] * inv, a[7] * inv);
}

// ---- layer 0 (K=6): 8 features per thread, 16 threads per node --------------
// writes bf16 (GEMM A-operand) and fp8-e4m3 x F8SCALE (gather table)

__global__ __launch_bounds__(256) void k_l0(const float* __restrict__ x,
                                            const float* __restrict__ mean0,
                                            const float* __restrict__ Wl,
                                            const float* __restrict__ bl,
                                            const float* __restrict__ Wr,
                                            unsigned short* __restrict__ out,
                                            unsigned char* __restrict__ out8, int nN) {
    int idx = blockIdx.x * 256 + threadIdx.x;
    int node = idx >> 4;
    int j0 = (idx & 15) * 8;
    if (node >= nN) return;
    const float* mp = mean0 + (size_t)node * 6;
    float2 m01 = *(const float2*)mp, m23 = *(const float2*)(mp + 2), m45 = *(const float2*)(mp + 4);
    const float* hp = x + (size_t)node * 10 + 4;
    float2 h01 = *(const float2*)hp, h23 = *(const float2*)(hp + 2), h45 = *(const float2*)(hp + 4);
    float m[6] = {m01.x, m01.y, m23.x, m23.y, m45.x, m45.y};
    float h[6] = {h01.x, h01.y, h23.x, h23.y, h45.x, h45.y};
    float4 b0 = *(const float4*)(bl + j0);
    float4 b1 = *(const float4*)(bl + j0 + 4);
    float v[8] = {b0.x, b0.y, b0.z, b0.w, b1.x, b1.y, b1.z, b1.w};
#pragma unroll
    for (int k = 0; k < 6; ++k) {
        float4 w0 = *(const float4*)(Wl + k * 128 + j0);
        float4 w1 = *(const float4*)(Wl + k * 128 + j0 + 4);
        v[0] = fmaf(m[k], w0.x, v[0]); v[1] = fmaf(m[k], w0.y, v[1]);
        v[2] = fmaf(m[k], w0.z, v[2]); v[3] = fmaf(m[k], w0.w, v[3]);
        v[4] = fmaf(m[k], w1.x, v[4]); v[5] = fmaf(m[k], w1.y, v[5]);
        v[6] = fmaf(m[k], w1.z, v[6]); v[7] = fmaf(m[k], w1.w, v[7]);
    }
#pragma unroll
    for (int k = 0; k < 6; ++k) {
        float4 w0 = *(const float4*)(Wr + k * 128 + j0);
        float4 w1 = *(const float4*)(Wr + k * 128 + j0 + 4);
        v[0] = fmaf(h[k], w0.x, v[0]); v[1] = fmaf(h[k], w0.y, v[1]);
        v[2] = fmaf(h[k], w0.z, v[2]); v[3] = fmaf(h[k], w0.w, v[3]);
        v[4] = fmaf(h[k], w1.x, v[4]); v[5] = fmaf(h[k], w1.y, v[5]);
        v[6] = fmaf(h[k], w1.z, v[6]); v[7] = fmaf(h[k], w1.w, v[7]);
    }
#pragma unroll
    for (int t = 0; t < 8; ++t) v[t] = fmaxf(v[t], 0.f);
    unsigned ob[4];
#pragma unroll
    for (int t = 0; t < 4; ++t) ob[t] = pack2bf(v[2 * t], v[2 * t + 1]);
    *(uint4*)(out + (size_t)node * 128 + j0) = *(const uint4*)ob;
    int d0 = __builtin_amdgcn_cvt_pk_fp8_f32(v[0] * F8SCALE, v[1] * F8SCALE, 0, false);
    d0     = __builtin_amdgcn_cvt_pk_fp8_f32(v[2] * F8SCALE, v[3] * F8SCALE, d0, true);
    int d1 = __builtin_amdgcn_cvt_pk_fp8_f32(v[4] * F8SCALE, v[5] * F8SCALE, 0, false);
    d1     = __builtin_amdgcn_cvt_pk_fp8_f32(v[6] * F8SCALE, v[7] * F8SCALE, d1, true);
    uint2 o8; o8.x = (unsigned)d0; o8.y = (unsigned)d1;
    *(uint2*)(out8 + (size_t)node * 128 + j0) = o8;
}

// ---- MFMA GEMM: C = act( [A0|A1] @ W^T (+bias) (+add) ) ---------------------
// Wt fragment-linear (k_wtfrag_all). Double-buffered register prefetch.

template <int KA, int KB, int N, bool RELU, bool BF16OUT, bool HASBIAS, bool HASADD>
__global__ __launch_bounds__(256) void k_mfma(const unsigned short* __restrict__ A0,
                                              const unsigned short* __restrict__ A1,
                                              const unsigned short* __restrict__ Wt,
                                              const float* __restrict__ bias,
                                              const float* __restrict__ add,
                                              void* __restrict__ Cout, int nN) {
    constexpr int K = KA + KB;
    constexpr int NSTEP = K / 32;
    constexpr int NB = N / 16;
    const int tid = threadIdx.x;
    const int wave = (blockIdx.x * 256 + tid) >> 6;
    const int m0 = wave * 32;
    if (m0 >= nN) return;
    const int lane = tid & 63;
    const int lr = lane & 15;
    const int lk = lane >> 4;

    f32x4 acc[2][NB];
#pragma unroll
    for (int g = 0; g < 2; ++g)
#pragma unroll
        for (int n = 0; n < NB; ++n) acc[g][n] = (f32x4){0.f, 0.f, 0.f, 0.f};

    auto loadA = [&](int kk, bf16x8& a0, bf16x8& a1) {
        const unsigned short* Ap;
        int lda, krel;
        if (KB > 0 && kk >= KA) { Ap = A1; lda = KB; krel = kk - KA; }
        else                    { Ap = A0; lda = KA; krel = kk; }
        a0 = *(const bf16x8*)(Ap + (size_t)(m0 + lr) * lda + krel + lk * 8);
        a1 = *(const bf16x8*)(Ap + (size_t)(m0 + 16 + lr) * lda + krel + lk * 8);
    };
    auto loadB = [&](int ks, bf16x8* b) {
        const unsigned short* Wk = Wt + (((size_t)ks * NB) << 6) * 8 + lane * 8;
#pragma unroll
        for (int n = 0; n < NB; ++n)
            b[n] = *(const bf16x8*)(Wk + ((size_t)n << 6) * 8);
    };

    bf16x8 a0c, a1c, a0n, a1n;
    bf16x8 bc[NB], bn[NB];
    loadA(0, a0c, a1c);
    loadB(0, bc);

#pragma unroll
    for (int ks = 0; ks < NSTEP; ++ks) {
        if (ks + 1 < NSTEP) {           // issue next step's loads FIRST
            loadA((ks + 1) * 32, a0n, a1n);
            loadB(ks + 1, bn);
        }
#pragma unroll
        for (int n = 0; n < NB; ++n) {
            acc[0][n] = __builtin_amdgcn_mfma_f32_16x16x32_bf16(a0c, bc[n], acc[0][n], 0, 0, 0);
            acc[1][n] = __builtin_amdgcn_mfma_f32_16x16x32_bf16(a1c, bc[n], acc[1][n], 0, 0, 0);
        }
        if (ks + 1 < NSTEP) {           // register rename (folds after unroll)
            a0c = a0n; a1c = a1n;
#pragma unroll
            for (int n = 0; n < NB; ++n) bc[n] = bn[n];
        }
    }

#pragma unroll
    for (int g = 0; g < 2; ++g) {
#pragma unroll
        for (int r = 0; r < 4; ++r) {
            int gm = m0 + g * 16 + lk * 4 + r;
#pragma unroll
            for (int n = 0; n < NB; ++n) {
                float v = acc[g][n][r];
                if (HASBIAS) v += bias[n * 16 + lr];
                if (HASADD)  v += add[(size_t)gm * N + n * 16 + lr];
                if (RELU)    v = fmaxf(v, 0.f);
                if (BF16OUT) ((unsigned short*)Cout)[(size_t)gm * N + n * 16 + lr] = f2bf(v);
                else         ((float*)Cout)[(size_t)gm * N + n * 16 + lr] = v;
            }
        }
    }
}

// ---------------------------------------------------------------------------

extern "C" void kernel_launch(void* const* d_in, const int* in_sizes, int n_in,
                              void* d_out, int out_size, void* d_ws, size_t ws_size,
                              hipStream_t stream) {
    const float* x   = (const float*)d_in[0];
    const int*   ei  = (const int*)d_in[1];
    const float* Wl0 = (const float*)d_in[2];
    const float* bl0 = (const float*)d_in[3];
    const float* Wr0 = (const float*)d_in[4];
    const float* Wl1 = (const float*)d_in[5];
    const float* bl1 = (const float*)d_in[6];
    const float* Wr1 = (const float*)d_in[7];
    const float* Wl2 = (const float*)d_in[8];
    const float* bl2 = (const float*)d_in[9];
    const float* Wr2 = (const float*)d_in[10];

    const int nN = in_sizes[0] / 10;
    const int nE = in_sizes[1] / 2;
    const int* src = ei;
    const int* dst = ei + nE;
    const int nbk = (nN + 255) >> 8;            // 391 buckets (<=512 for LDS)
    const int epb = (nE + PB - 1) / PB;         // edges per partition block

    char* ws = (char*)d_ws;
    size_t off = 0;
    auto alloc = [&](size_t bytes) -> char* {
        char* p = ws + off;
        off = (off + bytes + 255) & ~(size_t)255;
        return p;
    };
    unsigned short* out0   = (unsigned short*)alloc((size_t)nN * 128 * 2); // reused as z2
    unsigned char*  out0f8 = (unsigned char*)alloc((size_t)nN * 128);
    unsigned short* mean1  = (unsigned short*)alloc((size_t)nN * 128 * 2); // reused as meanz2 (fp32 x64)
    unsigned short* out1   = (unsigned short*)alloc((size_t)nN * 128 * 2);
    float* mean0 = (float*)alloc((size_t)nN * 6 * 4);
    unsigned short* Wt1  = (unsigned short*)alloc((size_t)128 * 256 * 2);
    unsigned short* Wt2l = (unsigned short*)alloc((size_t)64 * 128 * 2);
    unsigned short* Wt2r = (unsigned short*)alloc((size_t)64 * 128 * 2);
    int* C      = (int*)alloc((size_t)PB * nbk * 4);
    int* tot    = (int*)alloc((size_t)nbk * 4);
    int* bstart = (int*)alloc(((size_t)nbk + 1) * 4);
    int* offs   = (int*)alloc(((size_t)nN + 1) * 4);
    int* csr    = (int*)alloc((size_t)nE * 4);
    unsigned* ebuf = (unsigned*)alloc((size_t)nE * 4);

    unsigned short* z2     = out0;            // out0 dead after layer-1 GEMM
    float*          meanz2 = (float*)mean1;   // mean1 dead after layer-1 GEMM

    // weight prep: fragment-linear packing (single launch, independent of graph)
    k_wtfrag_all<<<24, 256, 0, stream>>>(Wl1, Wr1, Wl2, Wr2, Wt1, Wt2l, Wt2r);

    // build dst-sorted CSR via bucket partition (no global atomics, dense writes)
    k_p1count<<<PB, 256, 0, stream>>>(dst, C, nE, nbk, epb);
    k_colscan<<<nbk, 256, 0, stream>>>(C, tot, nbk);
    k_scan_a<<<1, 256, 0, stream>>>(tot, bstart, nbk);
    k_p1fill<<<PB, 256, 0, stream>>>(src, dst, bstart, C, ebuf, nE, nbk, epb);
    k_p2fill<<<nbk, 256, 0, stream>>>(ebuf, bstart, offs, csr, nN, nE);

    // layer 0 (K=6) -> out0 (bf16) + out0f8 (fp8 gather table)
    k_agg0<<<(nN + 255) / 256, 256, 0, stream>>>(x, offs, csr, mean0, nN);
    k_l0<<<((size_t)nN * 16 + 255) / 256, 256, 0, stream>>>(x, mean0, Wl0, bl0, Wr0, out0, out0f8, nN);

    const int gemm_grid = (nN / 32 + 3) / 4 + 1;   // 4 waves/block, 32 rows/wave

    // layer 1: mean1 = agg(out0f8); out1 = relu([mean1|out0] @ W1 + bl1)
    k_agg128f8<<<((size_t)nN * 8 + 255) / 256, 256, 0, stream>>>(out0f8, offs, csr, mean1, nN);
    k_mfma<128, 128, 128, true, true, true, false><<<gemm_grid, 256, 0, stream>>>(
        mean1, out0, Wt1, bl1, nullptr, out1, nN);

    // layer 2 (reordered): z2 = out1@Wl2 (bf16); out = relu(out1@Wr2 + bl2 + agg(z2))
    k_mfma<128, 0, 64, false, true, false, false><<<gemm_grid, 256, 0, stream>>>(
        out1, nullptr, Wt2l, nullptr, nullptr, z2, nN);
    k_agg64<<<((size_t)nN * 8 + 255) / 256, 256, 0, stream>>>(z2, offs, csr, meanz2, nN);
    k_mfma<128, 0, 64, true, false, true, true><<<gemm_grid, 256, 0, stream>>>(
        out1, nullptr, Wt2r, bl2, meanz2, (float*)d_out, nN);
}

// Round 11
// 198.856 us; speedup vs baseline: 4.5103x; 1.1111x over previous
//
#include <hip/hip_runtime.h>

// ---------------------------------------------------------------------------
// GraphSAGE 3-layer forward.
//   h = x[:,4:10]; per layer: mean_agg(h) @ Wl + bl + h @ Wr, relu
// Round-11 changes (structural eliminations; gathers are at L3 service floor):
//   - layer-2: ONE GEMM (k_mfma_l2) computes z2=out1@Wl2 (bf16) AND
//     y2=out1@Wr2 (f32); final add+bias+relu fused into agg64 epilogue.
//     (-1 launch, -25.6MB out1 re-read, meanz2 round-trip eliminated)
//   - agg0 + l0 fused (k_l0f): 16 lanes/node, shfl_xor butterfly mean.
//   - wtfrag fused into p1count launch (block-range dispatch).
//   13 -> 10 launches.
// ---------------------------------------------------------------------------

typedef __attribute__((ext_vector_type(8))) short bf16x8;   // 8 bf16 = 4 VGPR
typedef __attribute__((ext_vector_type(4))) float f32x4;
typedef __attribute__((ext_vector_type(2))) float f32x2;

constexpr int PB = 256;   // partition pass blocks (== colscan threads, fixed)
constexpr int WTCH = 6144; // weight-prep chunks: 4096 (Wt1) + 2048 (Wt2)
constexpr float F8SCALE = 32.0f;

static __device__ __forceinline__ int imax(int a, int b) { return a > b ? a : b; }

static __device__ __forceinline__ float bfbits_lo(unsigned u) {
    union { unsigned i; float f; } v; v.i = u << 16; return v.f;
}
static __device__ __forceinline__ float bfbits_hi(unsigned u) {
    union { unsigned i; float f; } v; v.i = u & 0xffff0000u; return v.f;
}
static __device__ __forceinline__ unsigned short f2bf(float f) {
    unsigned u = __float_as_uint(f);
    u = (u + 0x7fffu + ((u >> 16) & 1u)) >> 16;
    return (unsigned short)u;
}
static __device__ __forceinline__ unsigned pack2bf(float a, float b) {
    return (unsigned)f2bf(a) | ((unsigned)f2bf(b) << 16);
}
// accumulate 4 fp8-e4m3 bytes (one dword) into a[0..3]
static __device__ __forceinline__ void acc_f8x4(unsigned u, float* a) {
    f32x2 lo = __builtin_amdgcn_cvt_pk_f32_fp8((int)u, false);
    f32x2 hi = __builtin_amdgcn_cvt_pk_f32_fp8((int)u, true);
    a[0] += lo[0]; a[1] += lo[1]; a[2] += hi[0]; a[3] += hi[1];
}
// accumulate a uint4 of bf16 pairs into a[0..7]
static __device__ __forceinline__ void acc_bf8(uint4 v, float* a) {
    a[0] += bfbits_lo(v.x); a[1] += bfbits_hi(v.x);
    a[2] += bfbits_lo(v.y); a[3] += bfbits_hi(v.y);
    a[4] += bfbits_lo(v.z); a[5] += bfbits_hi(v.z);
    a[6] += bfbits_lo(v.w); a[7] += bfbits_hi(v.w);
}

// ---- weight prep (device helpers) -------------------------------------------
// Fragment-linear: chunk c = ((ks*NB + n)*64 + lane); 8 bf16 of W[k..k+7][col]
// where col = n*16 + (lane&15), k = ks*32 + (lane>>4)*8.

// K-concat: logical W = [W1; W2] rows (K1 + K-K1), N output cols
static __device__ __forceinline__ void wtfrag_katk(const float* __restrict__ W1,
                                                   const float* __restrict__ W2,
                                                   unsigned short* __restrict__ Wt,
                                                   int K1, int K, int N, int c) {
    int NB = N >> 4;
    int lane = c & 63;
    int n = (c >> 6) % NB;
    int ks = c / (NB << 6);
    int row = n * 16 + (lane & 15);
    int col = ks * 32 + (lane >> 4) * 8;
    unsigned short o[8];
#pragma unroll
    for (int j = 0; j < 8; ++j) {
        int k = col + j;
        float v = (k < K1) ? W1[k * N + row] : W2[(k - K1) * N + row];
        o[j] = f2bf(v);
    }
    *(uint4*)(Wt + (size_t)c * 8) = *(const uint4*)o;
}

// N-concat: output cols 0..Nh-1 from Wa[K][Nh], cols Nh..2Nh-1 from Wb[K][Nh]
static __device__ __forceinline__ void wtfrag_natn(const float* __restrict__ Wa,
                                                   const float* __restrict__ Wb,
                                                   unsigned short* __restrict__ Wt,
                                                   int K, int Nh, int c) {
    int NB = (2 * Nh) >> 4;
    int lane = c & 63;
    int n = (c >> 6) % NB;
    int ks = c / (NB << 6);
    int row = n * 16 + (lane & 15);
    int col = ks * 32 + (lane >> 4) * 8;
    unsigned short o[8];
#pragma unroll
    for (int j = 0; j < 8; ++j) {
        int k = col + j;
        float v = (row < Nh) ? Wa[k * Nh + row] : Wb[k * Nh + (row - Nh)];
        o[j] = f2bf(v);
    }
    *(uint4*)(Wt + (size_t)c * 8) = *(const uint4*)o;
}

// ---- fused prep: blocks [0,24) pack weights; blocks [24, 24+PB) count buckets

__global__ __launch_bounds__(256) void k_prep(const float* __restrict__ Wl1,
                                              const float* __restrict__ Wr1,
                                              const float* __restrict__ Wl2,
                                              const float* __restrict__ Wr2,
                                              unsigned short* __restrict__ Wt1,
                                              unsigned short* __restrict__ Wt2,
                                              const int* __restrict__ dst,
                                              int* __restrict__ C,
                                              int nE, int nbk, int epb) {
    if (blockIdx.x < 24) {
        int c = blockIdx.x * 256 + threadIdx.x;
        if (c < 4096)        wtfrag_katk(Wl1, Wr1, Wt1, 128, 256, 128, c);
        else if (c < WTCH)   wtfrag_natn(Wl2, Wr2, Wt2, 128, 64, c - 4096);
        return;
    }
    __shared__ int h[512];
    int b = blockIdx.x - 24;
    for (int i = threadIdx.x; i < nbk; i += 256) h[i] = 0;
    __syncthreads();
    int e0 = b * epb;
    int e1 = min(e0 + epb, nE);
    for (int i = e0 + threadIdx.x; i < e1; i += 256)
        atomicAdd(&h[dst[i] >> 8], 1);
    __syncthreads();
    for (int i = threadIdx.x; i < nbk; i += 256)
        C[b * nbk + i] = h[i];
}

// ---- graph build: bucket partition + per-bucket counting sort ---------------

__global__ __launch_bounds__(256) void k_colscan(int* __restrict__ C,
                                                 int* __restrict__ tot, int nbk) {
    __shared__ int sm[256];
    int k = blockIdx.x, t = threadIdx.x;
    int v = C[t * nbk + k];
    sm[t] = v;
    __syncthreads();
    for (int o = 1; o < 256; o <<= 1) {
        int u = (t >= o) ? sm[t - o] : 0;
        __syncthreads();
        sm[t] += u;
        __syncthreads();
    }
    C[t * nbk + k] = sm[t] - v;
    if (t == 255) tot[k] = sm[255];
}

// single-block exclusive scan (n <= 1024); writes grand total at offs[n]
__global__ __launch_bounds__(256) void k_scan_a(const int* __restrict__ cnt,
                                                int* __restrict__ offs, int n) {
    __shared__ int sm[256];
    int t = threadIdx.x;
    int base = t * 4;
    int v0 = 0, v1 = 0, v2 = 0, v3 = 0;
    if (base + 3 < n) {
        int4 q = *(const int4*)(cnt + base);
        v0 = q.x; v1 = q.y; v2 = q.z; v3 = q.w;
    } else {
        if (base < n)     v0 = cnt[base];
        if (base + 1 < n) v1 = cnt[base + 1];
        if (base + 2 < n) v2 = cnt[base + 2];
    }
    int s = v0 + v1 + v2 + v3;
    sm[t] = s;
    __syncthreads();
    for (int o = 1; o < 256; o <<= 1) {
        int u = (t >= o) ? sm[t - o] : 0;
        __syncthreads();
        sm[t] += u;
        __syncthreads();
    }
    int excl = sm[t] - s;
    if (base < n)     offs[base]     = excl;
    if (base + 1 < n) offs[base + 1] = excl + v0;
    if (base + 2 < n) offs[base + 2] = excl + v0 + v1;
    if (base + 3 < n) offs[base + 3] = excl + v0 + v1 + v2;
    if (t == 255) offs[n] = sm[255];
}

__global__ __launch_bounds__(256) void k_p1fill(const int* __restrict__ src,
                                                const int* __restrict__ dst,
                                                const int* __restrict__ bstart,
                                                const int* __restrict__ C,
                                                unsigned* __restrict__ ebuf,
                                                int nE, int nbk, int epb) {
    __shared__ int cur[512];
    int b = blockIdx.x;
    for (int i = threadIdx.x; i < nbk; i += 256)
        cur[i] = bstart[i] + C[b * nbk + i];
    __syncthreads();
    int e0 = b * epb;
    int e1 = min(e0 + epb, nE);
    for (int i = e0 + threadIdx.x; i < e1; i += 256) {
        int d = dst[i];
        unsigned s = (unsigned)src[i];
        int p = atomicAdd(&cur[d >> 8], 1);
        ebuf[p] = (s << 8) | (unsigned)(d & 255);
    }
}

__global__ __launch_bounds__(256) void k_p2fill(const unsigned* __restrict__ ebuf,
                                                const int* __restrict__ bstart,
                                                int* __restrict__ offs,
                                                int* __restrict__ csr,
                                                int nN, int nE) {
    __shared__ int h[256], sm[256], cur[256];
    int k = blockIdx.x, t = threadIdx.x;
    int base = bstart[k], end = bstart[k + 1];
    h[t] = 0;
    __syncthreads();
    for (int i = base + t; i < end; i += 256)
        atomicAdd(&h[ebuf[i] & 255u], 1);
    __syncthreads();
    int v = h[t];
    sm[t] = v;
    __syncthreads();
    for (int o = 1; o < 256; o <<= 1) {
        int u = (t >= o) ? sm[t - o] : 0;
        __syncthreads();
        sm[t] += u;
        __syncthreads();
    }
    int excl = sm[t] - v;
    int node = (k << 8) + t;
    if (node < nN) offs[node] = base + excl;
    cur[t] = base + excl;
    if (k == 0 && t == 0) offs[nN] = nE;
    __syncthreads();
    for (int i = base + t; i < end; i += 256) {
        unsigned e = ebuf[i];
        int p = atomicAdd(&cur[e & 255u], 1);
        csr[p] = (int)(e >> 8);
    }
}

// ---- fused layer 0: mean via 16-lane shfl butterfly + MLP --------------------
// 16 threads per node; lane j gathers edges lo+j, lo+j+16, ...; butterfly
// reduce gives all 16 lanes the 6-dim sum; then each lane computes 8 outputs.

__global__ __launch_bounds__(256) void k_l0f(const float* __restrict__ x,
                                             const int* __restrict__ offs,
                                             const int* __restrict__ csr,
                                             const float* __restrict__ Wl,
                                             const float* __restrict__ bl,
                                             const float* __restrict__ Wr,
                                             unsigned short* __restrict__ out,
                                             unsigned char* __restrict__ out8, int nN) {
    int idx = blockIdx.x * 256 + threadIdx.x;
    int node = idx >> 4;
    int j = threadIdx.x & 15;
    if (node >= nN) return;       // whole 16-lane group exits together
    int lo = offs[node], hi = offs[node + 1];
    float a0 = 0, a1 = 0, a2 = 0, a3 = 0, a4 = 0, a5 = 0;
    for (int e = lo + j; e < hi; e += 16) {
        int s = csr[e];
        const float* r = x + (size_t)s * 10 + 4;
        float2 v0 = *(const float2*)(r);
        float2 v1 = *(const float2*)(r + 2);
        float2 v2 = *(const float2*)(r + 4);
        a0 += v0.x; a1 += v0.y; a2 += v1.x; a3 += v1.y; a4 += v2.x; a5 += v2.y;
    }
#pragma unroll
    for (int mask = 1; mask < 16; mask <<= 1) {
        a0 += __shfl_xor(a0, mask); a1 += __shfl_xor(a1, mask);
        a2 += __shfl_xor(a2, mask); a3 += __shfl_xor(a3, mask);
        a4 += __shfl_xor(a4, mask); a5 += __shfl_xor(a5, mask);
    }
    float inv = 1.0f / (float)imax(hi - lo, 1);
    float m[6] = {a0 * inv, a1 * inv, a2 * inv, a3 * inv, a4 * inv, a5 * inv};
    const float* hp = x + (size_t)node * 10 + 4;
    float2 h01 = *(const float2*)hp, h23 = *(const float2*)(hp + 2), h45 = *(const float2*)(hp + 4);
    float h[6] = {h01.x, h01.y, h23.x, h23.y, h45.x, h45.y};
    int j0 = j * 8;
    float4 b0 = *(const float4*)(bl + j0);
    float4 b1 = *(const float4*)(bl + j0 + 4);
    float v[8] = {b0.x, b0.y, b0.z, b0.w, b1.x, b1.y, b1.z, b1.w};
#pragma unroll
    for (int k = 0; k < 6; ++k) {
        float4 w0 = *(const float4*)(Wl + k * 128 + j0);
        float4 w1 = *(const float4*)(Wl + k * 128 + j0 + 4);
        v[0] = fmaf(m[k], w0.x, v[0]); v[1] = fmaf(m[k], w0.y, v[1]);
        v[2] = fmaf(m[k], w0.z, v[2]); v[3] = fmaf(m[k], w0.w, v[3]);
        v[4] = fmaf(m[k], w1.x, v[4]); v[5] = fmaf(m[k], w1.y, v[5]);
        v[6] = fmaf(m[k], w1.z, v[6]); v[7] = fmaf(m[k], w1.w, v[7]);
    }
#pragma unroll
    for (int k = 0; k < 6; ++k) {
        float4 w0 = *(const float4*)(Wr + k * 128 + j0);
        float4 w1 = *(const float4*)(Wr + k * 128 + j0 + 4);
        v[0] = fmaf(h[k], w0.x, v[0]); v[1] = fmaf(h[k], w0.y, v[1]);
        v[2] = fmaf(h[k], w0.z, v[2]); v[3] = fmaf(h[k], w0.w, v[3]);
        v[4] = fmaf(h[k], w1.x, v[4]); v[5] = fmaf(h[k], w1.y, v[5]);
        v[6] = fmaf(h[k], w1.z, v[6]); v[7] = fmaf(h[k], w1.w, v[7]);
    }
#pragma unroll
    for (int t = 0; t < 8; ++t) v[t] = fmaxf(v[t], 0.f);
    unsigned ob[4];
#pragma unroll
    for (int t = 0; t < 4; ++t) ob[t] = pack2bf(v[2 * t], v[2 * t + 1]);
    *(uint4*)(out + (size_t)node * 128 + j0) = *(const uint4*)ob;
    int d0 = __builtin_amdgcn_cvt_pk_fp8_f32(v[0] * F8SCALE, v[1] * F8SCALE, 0, false);
    d0     = __builtin_amdgcn_cvt_pk_fp8_f32(v[2] * F8SCALE, v[3] * F8SCALE, d0, true);
    int d1 = __builtin_amdgcn_cvt_pk_fp8_f32(v[4] * F8SCALE, v[5] * F8SCALE, 0, false);
    d1     = __builtin_amdgcn_cvt_pk_fp8_f32(v[6] * F8SCALE, v[7] * F8SCALE, d1, true);
    uint2 o8; o8.x = (unsigned)d0; o8.y = (unsigned)d1;
    *(uint2*)(out8 + (size_t)node * 128 + j0) = o8;
}

// ---- aggregation -----------------------------------------------------------

// 128-dim fp8 mean -> bf16: thread per (node, 16B chunk), 8x-unrolled edges.
__global__ __launch_bounds__(256) void k_agg128f8(const unsigned char* __restrict__ X,
                                                  const int* __restrict__ offs,
                                                  const int* __restrict__ csr,
                                                  unsigned short* __restrict__ M, int nN) {
    int idx = blockIdx.x * 256 + threadIdx.x;
    int node = idx >> 3;
    int fl = idx & 7;             // features fl*16 .. fl*16+15
    if (node >= nN) return;
    int lo = offs[node], hi = offs[node + 1];
    float a[16];
#pragma unroll
    for (int j = 0; j < 16; ++j) a[j] = 0.f;
    int e = lo;
    for (; e + 8 <= hi; e += 8) {
        uint4 v0 = *(const uint4*)(X + (size_t)csr[e + 0] * 128 + fl * 16);
        uint4 v1 = *(const uint4*)(X + (size_t)csr[e + 1] * 128 + fl * 16);
        uint4 v2 = *(const uint4*)(X + (size_t)csr[e + 2] * 128 + fl * 16);
        uint4 v3 = *(const uint4*)(X + (size_t)csr[e + 3] * 128 + fl * 16);
        uint4 v4 = *(const uint4*)(X + (size_t)csr[e + 4] * 128 + fl * 16);
        uint4 v5 = *(const uint4*)(X + (size_t)csr[e + 5] * 128 + fl * 16);
        uint4 v6 = *(const uint4*)(X + (size_t)csr[e + 6] * 128 + fl * 16);
        uint4 v7 = *(const uint4*)(X + (size_t)csr[e + 7] * 128 + fl * 16);
        acc_f8x4(v0.x, a + 0); acc_f8x4(v0.y, a + 4); acc_f8x4(v0.z, a + 8); acc_f8x4(v0.w, a + 12);
        acc_f8x4(v1.x, a + 0); acc_f8x4(v1.y, a + 4); acc_f8x4(v1.z, a + 8); acc_f8x4(v1.w, a + 12);
        acc_f8x4(v2.x, a + 0); acc_f8x4(v2.y, a + 4); acc_f8x4(v2.z, a + 8); acc_f8x4(v2.w, a + 12);
        acc_f8x4(v3.x, a + 0); acc_f8x4(v3.y, a + 4); acc_f8x4(v3.z, a + 8); acc_f8x4(v3.w, a + 12);
        acc_f8x4(v4.x, a + 0); acc_f8x4(v4.y, a + 4); acc_f8x4(v4.z, a + 8); acc_f8x4(v4.w, a + 12);
        acc_f8x4(v5.x, a + 0); acc_f8x4(v5.y, a + 4); acc_f8x4(v5.z, a + 8); acc_f8x4(v5.w, a + 12);
        acc_f8x4(v6.x, a + 0); acc_f8x4(v6.y, a + 4); acc_f8x4(v6.z, a + 8); acc_f8x4(v6.w, a + 12);
        acc_f8x4(v7.x, a + 0); acc_f8x4(v7.y, a + 4); acc_f8x4(v7.z, a + 8); acc_f8x4(v7.w, a + 12);
    }
    for (; e + 4 <= hi; e += 4) {
        uint4 v0 = *(const uint4*)(X + (size_t)csr[e + 0] * 128 + fl * 16);
        uint4 v1 = *(const uint4*)(X + (size_t)csr[e + 1] * 128 + fl * 16);
        uint4 v2 = *(const uint4*)(X + (size_t)csr[e + 2] * 128 + fl * 16);
        uint4 v3 = *(const uint4*)(X + (size_t)csr[e + 3] * 128 + fl * 16);
        acc_f8x4(v0.x, a + 0); acc_f8x4(v0.y, a + 4); acc_f8x4(v0.z, a + 8); acc_f8x4(v0.w, a + 12);
        acc_f8x4(v1.x, a + 0); acc_f8x4(v1.y, a + 4); acc_f8x4(v1.z, a + 8); acc_f8x4(v1.w, a + 12);
        acc_f8x4(v2.x, a + 0); acc_f8x4(v2.y, a + 4); acc_f8x4(v2.z, a + 8); acc_f8x4(v2.w, a + 12);
        acc_f8x4(v3.x, a + 0); acc_f8x4(v3.y, a + 4); acc_f8x4(v3.z, a + 8); acc_f8x4(v3.w, a + 12);
    }
    for (; e < hi; ++e) {
        uint4 v = *(const uint4*)(X + (size_t)csr[e] * 128 + fl * 16);
        acc_f8x4(v.x, a + 0); acc_f8x4(v.y, a + 4); acc_f8x4(v.z, a + 8); acc_f8x4(v.w, a + 12);
    }
    float inv = 1.0f / (F8SCALE * (float)imax(hi - lo, 1));
    unsigned o[8];
#pragma unroll
    for (int j = 0; j < 8; ++j) o[j] = pack2bf(a[2 * j] * inv, a[2 * j + 1] * inv);
    unsigned short* mp = M + (size_t)node * 128 + fl * 16;
    *(uint4*)(mp)     = *(const uint4*)(o);
    *(uint4*)(mp + 8) = *(const uint4*)(o + 4);
}

// 64-dim bf16 mean + FUSED layer-2 epilogue: out = relu(mean + y2 + bl2)
__global__ __launch_bounds__(256) void k_agg64f(const unsigned short* __restrict__ X,
                                                const int* __restrict__ offs,
                                                const int* __restrict__ csr,
                                                const float* __restrict__ y2,
                                                const float* __restrict__ bl2,
                                                float* __restrict__ out, int nN) {
    int idx = blockIdx.x * 256 + threadIdx.x;
    int node = idx >> 3;
    int fl = idx & 7;             // features fl*8 .. fl*8+7
    if (node >= nN) return;
    int lo = offs[node], hi = offs[node + 1];
    float a[8] = {0, 0, 0, 0, 0, 0, 0, 0};
    int e = lo;
    for (; e + 8 <= hi; e += 8) {
        uint4 v0 = *(const uint4*)(X + (size_t)csr[e + 0] * 64 + fl * 8);
        uint4 v1 = *(const uint4*)(X + (size_t)csr[e + 1] * 64 + fl * 8);
        uint4 v2 = *(const uint4*)(X + (size_t)csr[e + 2] * 64 + fl * 8);
        uint4 v3 = *(const uint4*)(X + (size_t)csr[e + 3] * 64 + fl * 8);
        uint4 v4 = *(const uint4*)(X + (size_t)csr[e + 4] * 64 + fl * 8);
        uint4 v5 = *(const uint4*)(X + (size_t)csr[e + 5] * 64 + fl * 8);
        uint4 v6 = *(const uint4*)(X + (size_t)csr[e + 6] * 64 + fl * 8);
        uint4 v7 = *(const uint4*)(X + (size_t)csr[e + 7] * 64 + fl * 8);
        acc_bf8(v0, a); acc_bf8(v1, a); acc_bf8(v2, a); acc_bf8(v3, a);
        acc_bf8(v4, a); acc_bf8(v5, a); acc_bf8(v6, a); acc_bf8(v7, a);
    }
    for (; e + 4 <= hi; e += 4) {
        uint4 v0 = *(const uint4*)(X + (size_t)csr[e + 0] * 64 + fl * 8);
        uint4 v1 = *(const uint4*)(X + (size_t)csr[e + 1] * 64 + fl * 8);
        uint4 v2 = *(const uint4*)(X + (size_t)csr[e + 2] * 64 + fl * 8);
        uint4 v3 = *(const uint4*)(X + (size_t)csr[e + 3] * 64 + fl * 8);
        acc_bf8(v0, a); acc_bf8(v1, a); acc_bf8(v2, a); acc_bf8(v3, a);
    }
    for (; e < hi; ++e) {
        uint4 v = *(const uint4*)(X + (size_t)csr[e] * 64 + fl * 8);
        acc_bf8(v, a);
    }
    float inv = 1.0f / (float)imax(hi - lo, 1);
    const float* yp = y2 + (size_t)node * 64 + fl * 8;
    float4 ya = *(const float4*)yp;
    float4 yb = *(const float4*)(yp + 4);
    float4 ba = *(const float4*)(bl2 + fl * 8);
    float4 bb = *(const float4*)(bl2 + fl * 8 + 4);
    float* o = out + (size_t)node * 64 + fl * 8;
    *(float4*)(o) = make_float4(fmaxf(fmaf(a[0], inv, ya.x + ba.x), 0.f),
                                fmaxf(fmaf(a[1], inv, ya.y + ba.y), 0.f),
                                fmaxf(fmaf(a[2], inv, ya.z + ba.z), 0.f),
                                fmaxf(fmaf(a[3], inv, ya.w + ba.w), 0.f));
    *(float4*)(o + 4) = make_float4(fmaxf(fmaf(a[4], inv, yb.x + bb.x), 0.f),
                                    fmaxf(fmaf(a[5], inv, yb.y + bb.y), 0.f),
                                    fmaxf(fmaf(a[6], inv, yb.z + bb.z), 0.f),
                                    fmaxf(fmaf(a[7], inv, yb.w + bb.w), 0.f));
}

// ---- MFMA GEMM (layer 1): C = relu( [A0|A1] @ W^T + bias ) ------------------
// Wt fragment-linear. Double-buffered register prefetch across k-steps.

template <int KA, int KB, int N>
__global__ __launch_bounds__(256) void k_mfma(const unsigned short* __restrict__ A0,
                                              const unsigned short* __restrict__ A1,
                                              const unsigned short* __restrict__ Wt,
                                              const float* __restrict__ bias,
                                              unsigned short* __restrict__ Cout, int nN) {
    constexpr int K = KA + KB;
    constexpr int NSTEP = K / 32;
    constexpr int NB = N / 16;
    const int tid = threadIdx.x;
    const int wave = (blockIdx.x * 256 + tid) >> 6;
    const int m0 = wave * 32;
    if (m0 >= nN) return;
    const int lane = tid & 63;
    const int lr = lane & 15;
    const int lk = lane >> 4;

    f32x4 acc[2][NB];
#pragma unroll
    for (int g = 0; g < 2; ++g)
#pragma unroll
        for (int n = 0; n < NB; ++n) acc[g][n] = (f32x4){0.f, 0.f, 0.f, 0.f};

    auto loadA = [&](int kk, bf16x8& a0, bf16x8& a1) {
        const unsigned short* Ap;
        int lda, krel;
        if (KB > 0 && kk >= KA) { Ap = A1; lda = KB; krel = kk - KA; }
        else                    { Ap = A0; lda = KA; krel = kk; }
        a0 = *(const bf16x8*)(Ap + (size_t)(m0 + lr) * lda + krel + lk * 8);
        a1 = *(const bf16x8*)(Ap + (size_t)(m0 + 16 + lr) * lda + krel + lk * 8);
    };
    auto loadB = [&](int ks, bf16x8* b) {
        const unsigned short* Wk = Wt + (((size_t)ks * NB) << 6) * 8 + lane * 8;
#pragma unroll
        for (int n = 0; n < NB; ++n)
            b[n] = *(const bf16x8*)(Wk + ((size_t)n << 6) * 8);
    };

    bf16x8 a0c, a1c, a0n, a1n;
    bf16x8 bc[NB], bn[NB];
    loadA(0, a0c, a1c);
    loadB(0, bc);

#pragma unroll
    for (int ks = 0; ks < NSTEP; ++ks) {
        if (ks + 1 < NSTEP) {
            loadA((ks + 1) * 32, a0n, a1n);
            loadB(ks + 1, bn);
        }
#pragma unroll
        for (int n = 0; n < NB; ++n) {
            acc[0][n] = __builtin_amdgcn_mfma_f32_16x16x32_bf16(a0c, bc[n], acc[0][n], 0, 0, 0);
            acc[1][n] = __builtin_amdgcn_mfma_f32_16x16x32_bf16(a1c, bc[n], acc[1][n], 0, 0, 0);
        }
        if (ks + 1 < NSTEP) {
            a0c = a0n; a1c = a1n;
#pragma unroll
            for (int n = 0; n < NB; ++n) bc[n] = bn[n];
        }
    }

#pragma unroll
    for (int g = 0; g < 2; ++g) {
#pragma unroll
        for (int r = 0; r < 4; ++r) {
            int gm = m0 + g * 16 + lk * 4 + r;
#pragma unroll
            for (int n = 0; n < NB; ++n) {
                float v = fmaxf(acc[g][n][r] + bias[n * 16 + lr], 0.f);
                Cout[(size_t)gm * N + n * 16 + lr] = f2bf(v);
            }
        }
    }
}

// ---- MFMA GEMM (layer 2, merged): z2 = A@Wl2 (bf16), y2 = A@Wr2 (f32) -------
// Wt2 fragment-linear with N-concat cols [Wl2 | Wr2]; K=128, N=128.

__global__ __launch_bounds__(256) void k_mfma_l2(const unsigned short* __restrict__ A0,
                                                 const unsigned short* __restrict__ Wt,
                                                 unsigned short* __restrict__ z2,
                                                 float* __restrict__ y2, int nN) {
    constexpr int K = 128, NSTEP = 4, NB = 8;
    const int tid = threadIdx.x;
    const int wave = (blockIdx.x * 256 + tid) >> 6;
    const int m0 = wave * 32;
    if (m0 >= nN) return;
    const int lane = tid & 63;
    const int lr = lane & 15;
    const int lk = lane >> 4;

    f32x4 acc[2][NB];
#pragma unroll
    for (int g = 0; g < 2; ++g)
#pragma unroll
        for (int n = 0; n < NB; ++n) acc[g][n] = (f32x4){0.f, 0.f, 0.f, 0.f};

    auto loadA = [&](int kk, bf16x8& a0, bf16x8& a1) {
        a0 = *(const bf16x8*)(A0 + (size_t)(m0 + lr) * K + kk + lk * 8);
        a1 = *(const bf16x8*)(A0 + (size_t)(m0 + 16 + lr) * K + kk + lk * 8);
    };
    auto loadB = [&](int ks, bf16x8* b) {
        const unsigned short* Wk = Wt + (((size_t)ks * NB) << 6) * 8 + lane * 8;
#pragma unroll
        for (int n = 0; n < NB; ++n)
            b[n] = *(const bf16x8*)(Wk + ((size_t)n << 6) * 8);
    };

    bf16x8 a0c, a1c, a0n, a1n;
    bf16x8 bc[NB], bn[NB];
    loadA(0, a0c, a1c);
    loadB(0, bc);

#pragma unroll
    for (int ks = 0; ks < NSTEP; ++ks) {
        if (ks + 1 < NSTEP) {
            loadA((ks + 1) * 32, a0n, a1n);
            loadB(ks + 1, bn);
        }
#pragma unroll
        for (int n = 0; n < NB; ++n) {
            acc[0][n] = __builtin_amdgcn_mfma_f32_16x16x32_bf16(a0c, bc[n], acc[0][n], 0, 0, 0);
            acc[1][n] = __builtin_amdgcn_mfma_f32_16x16x32_bf16(a1c, bc[n], acc[1][n], 0, 0, 0);
        }
        if (ks + 1 < NSTEP) {
            a0c = a0n; a1c = a1n;
#pragma unroll
            for (int n = 0; n < NB; ++n) bc[n] = bn[n];
        }
    }

#pragma unroll
    for (int g = 0; g < 2; ++g) {
#pragma unroll
        for (int r = 0; r < 4; ++r) {
            int gm = m0 + g * 16 + lk * 4 + r;
#pragma unroll
            for (int n = 0; n < 4; ++n)
                z2[(size_t)gm * 64 + n * 16 + lr] = f2bf(acc[g][n][r]);
#pragma unroll
            for (int n = 4; n < 8; ++n)
                y2[(size_t)gm * 64 + (n - 4) * 16 + lr] = acc[g][n][r];
        }
    }
}

// ---------------------------------------------------------------------------

extern "C" void kernel_launch(void* const* d_in, const int* in_sizes, int n_in,
                              void* d_out, int out_size, void* d_ws, size_t ws_size,
                              hipStream_t stream) {
    const float* x   = (const float*)d_in[0];
    const int*   ei  = (const int*)d_in[1];
    const float* Wl0 = (const float*)d_in[2];
    const float* bl0 = (const float*)d_in[3];
    const float* Wr0 = (const float*)d_in[4];
    const float* Wl1 = (const float*)d_in[5];
    const float* bl1 = (const float*)d_in[6];
    const float* Wr1 = (const float*)d_in[7];
    const float* Wl2 = (const float*)d_in[8];
    const float* bl2 = (const float*)d_in[9];
    const float* Wr2 = (const float*)d_in[10];

    const int nN = in_sizes[0] / 10;
    const int nE = in_sizes[1] / 2;
    const int* src = ei;
    const int* dst = ei + nE;
    const int nbk = (nN + 255) >> 8;            // 391 buckets (<=512 for LDS)
    const int epb = (nE + PB - 1) / PB;         // edges per partition block

    char* ws = (char*)d_ws;
    size_t off = 0;
    auto alloc = [&](size_t bytes) -> char* {
        char* p = ws + off;
        off = (off + bytes + 255) & ~(size_t)255;
        return p;
    };
    unsigned short* out0   = (unsigned short*)alloc((size_t)nN * 128 * 2); // reused as z2 (nN x 64)
    unsigned char*  out0f8 = (unsigned char*)alloc((size_t)nN * 128);
    unsigned short* mean1  = (unsigned short*)alloc((size_t)nN * 128 * 2); // reused as y2 (f32 nN x 64)
    unsigned short* out1   = (unsigned short*)alloc((size_t)nN * 128 * 2);
    unsigned short* Wt1 = (unsigned short*)alloc((size_t)128 * 256 * 2);
    unsigned short* Wt2 = (unsigned short*)alloc((size_t)128 * 128 * 2);
    int* C      = (int*)alloc((size_t)PB * nbk * 4);
    int* tot    = (int*)alloc((size_t)nbk * 4);
    int* bstart = (int*)alloc(((size_t)nbk + 1) * 4);
    int* offs   = (int*)alloc(((size_t)nN + 1) * 4);
    int* csr    = (int*)alloc((size_t)nE * 4);
    unsigned* ebuf = (unsigned*)alloc((size_t)nE * 4);

    unsigned short* z2 = out0;            // out0 dead after layer-1 GEMM
    float*          y2 = (float*)mean1;   // mean1 dead after layer-1 GEMM

    // prep: weight packing (blocks 0..23) + bucket counting (blocks 24..279)
    k_prep<<<24 + PB, 256, 0, stream>>>(Wl1, Wr1, Wl2, Wr2, Wt1, Wt2, dst, C, nE, nbk, epb);
    k_colscan<<<nbk, 256, 0, stream>>>(C, tot, nbk);
    k_scan_a<<<1, 256, 0, stream>>>(tot, bstart, nbk);
    k_p1fill<<<PB, 256, 0, stream>>>(src, dst, bstart, C, ebuf, nE, nbk, epb);
    k_p2fill<<<nbk, 256, 0, stream>>>(ebuf, bstart, offs, csr, nN, nE);

    // layer 0 fused (mean via shfl butterfly + K=6 MLP) -> out0 bf16 + out0f8
    k_l0f<<<((size_t)nN * 16 + 255) / 256, 256, 0, stream>>>(
        x, offs, csr, Wl0, bl0, Wr0, out0, out0f8, nN);

    const int gemm_grid = (nN / 32 + 3) / 4 + 1;   // 4 waves/block, 32 rows/wave

    // layer 1: mean1 = agg(out0f8); out1 = relu([mean1|out0] @ W1 + bl1)
    k_agg128f8<<<((size_t)nN * 8 + 255) / 256, 256, 0, stream>>>(out0f8, offs, csr, mean1, nN);
    k_mfma<128, 128, 128><<<gemm_grid, 256, 0, stream>>>(mean1, out0, Wt1, bl1, out1, nN);

    // layer 2 (merged): {z2, y2} = out1 @ [Wl2|Wr2]; out = relu(agg(z2) + y2 + bl2)
    k_mfma_l2<<<gemm_grid, 256, 0, stream>>>(out1, Wt2, z2, y2, nN);
    k_agg64f<<<((size_t)nN * 8 + 255) / 256, 256, 0, stream>>>(
        z2, offs, csr, y2, bl2, (float*)d_out, nN);
}